// Round 2
// baseline (780.619 us; speedup 1.0000x reference)
//
#include <hip/hip_runtime.h>
#include <hip/hip_bf16.h>

typedef __hip_bfloat16 bf16;

__device__ __forceinline__ float toF(bf16 v) { return __bfloat162float(v); }

// dual-dtype load: dt=1 -> underlying memory is fp32; dt=0 -> bf16
__device__ __forceinline__ float ldf(const void* p, size_t i, int dt) {
  return dt ? ((const float*)p)[i] : __bfloat162float(((const bf16*)p)[i]);
}

// ---------------- dtype detection ----------------
// If memory holds fp32 but we read it as bf16, half the "elements" are fp32
// mantissa bits -> random exponent -> huge magnitudes. True bf16 N(0,1) data
// never exceeds ~1e1. Check first `n` elements.
__global__ void detect_dtype(const void* x, int n, int* flag) {
  __shared__ int s;
  if (threadIdx.x == 0) s = 0;
  __syncthreads();
  const bf16* xb = (const bf16*)x;
  int bad = 0;
  for (int i = threadIdx.x; i < n; i += 256) {
    float v = __bfloat162float(xb[i]);
    if (!(fabsf(v) < 1e6f)) bad = 1;  // catches inf/nan too
  }
  if (bad) atomicOr(&s, 1);
  __syncthreads();
  if (threadIdx.x == 0) flag[0] = s;
}

// ---------------- CSR build ----------------
__global__ void count_edges(const int* __restrict__ ei, int N, int E, int* __restrict__ cnt) {
  int e = blockIdx.x * blockDim.x + threadIdx.x;
  int Etot = E + N;
  if (e >= Etot) return;
  int d = (e < E) ? ei[E + e] : (e - E);
  atomicAdd(&cnt[d], 1);
}

// single block, 1024 threads: exclusive scan of cnt[0..n) -> rowstart, cursor; rowstart[n]=total
__global__ void scan_kernel(const int* __restrict__ cnt, int* __restrict__ rowstart,
                            int* __restrict__ cursor, int n) {
  __shared__ int wsum[16];
  __shared__ int carry_s;
  int t = threadIdx.x, lane = t & 63, w = t >> 6;
  if (t == 0) carry_s = 0;
  __syncthreads();
  for (int base = 0; base < n; base += 1024) {
    int i = base + t;
    int v = (i < n) ? cnt[i] : 0;
    int x = v;
#pragma unroll
    for (int off = 1; off < 64; off <<= 1) {
      int y = __shfl_up(x, off, 64);
      if (lane >= off) x += y;
    }
    if (lane == 63) wsum[w] = x;
    __syncthreads();
    if (t < 16) {
      int s = wsum[t];
#pragma unroll
      for (int off = 1; off < 16; off <<= 1) {
        int y = __shfl_up(s, off, 64);
        if (t >= off) s += y;
      }
      wsum[t] = s;
    }
    __syncthreads();
    int woff = (w > 0) ? wsum[w - 1] : 0;
    int incl = x + woff;
    int carry = carry_s;
    if (i < n) {
      int excl = carry + incl - v;
      rowstart[i] = excl;
      cursor[i] = excl;
    }
    __syncthreads();
    if (t == 1023) carry_s = carry + wsum[15];
    __syncthreads();
  }
  if (threadIdx.x == 0) rowstart[n] = carry_s;
}

__global__ void scatter_edges(const int* __restrict__ ei, int N, int E,
                              int* __restrict__ cursor, int* __restrict__ adj) {
  int e = blockIdx.x * blockDim.x + threadIdx.x;
  int Etot = E + N;
  if (e >= Etot) return;
  int d, s;
  if (e < E) { s = ei[e]; d = ei[E + e]; } else { s = e - E; d = s; }
  int pos = atomicAdd(&cursor[d], 1);
  adj[pos] = s;
}

// ---------------- GEMM: C[nrows,128] = A[nrows,K] @ W[K,128], bf16 out, fp32 acc --------
// DUALA: A comes from d_in (dtype per flag). Otherwise A is our bf16 buffer.
template <bool DUALA>
__global__ __launch_bounds__(256) void gemm_tile(const void* __restrict__ A, const void* __restrict__ W,
                                                 bf16* __restrict__ C, int nrows, int K,
                                                 const int* __restrict__ dtflag) {
  const int BM = 64, BK = 16;
  __shared__ float At[BK][BM + 4];   // transposed A tile
  __shared__ float Wt[BK][128];
  int dt = dtflag[0];
  int tid = threadIdx.x;
  int row0 = blockIdx.x * BM;
  int tr = tid >> 2;            // 0..63 row for A load
  int tk4 = (tid & 3) << 2;     // k offset 0/4/8/12 for A load
  int col4 = (tid & 31) << 2;   // output col group
  int rrow = (tid >> 5) << 3;   // output row group (8 rows)
  float acc[8][4];
#pragma unroll
  for (int m = 0; m < 8; m++)
#pragma unroll
    for (int j = 0; j < 4; j++) acc[m][j] = 0.f;

  for (int k0 = 0; k0 < K; k0 += BK) {
    float av[4];
    int arow = row0 + tr;
#pragma unroll
    for (int i = 0; i < 4; i++) {
      int k = k0 + tk4 + i;
      bool ok = (arow < nrows && k < K);
      size_t idx = (size_t)arow * K + k;
      if (DUALA)
        av[i] = ok ? ldf(A, idx, dt) : 0.f;
      else
        av[i] = ok ? toF(((const bf16*)A)[idx]) : 0.f;
    }
    __syncthreads();
#pragma unroll
    for (int i = 0; i < 4; i++) At[tk4 + i][tr] = av[i];
#pragma unroll
    for (int i = 0; i < 8; i++) {
      int flat = tid + 256 * i;
      int kk = flat >> 7, c = flat & 127;
      int k = k0 + kk;
      Wt[kk][c] = (k < K) ? ldf(W, (size_t)k * 128 + c, dt) : 0.f;
    }
    __syncthreads();
#pragma unroll
    for (int kk = 0; kk < BK; kk++) {
      float w4[4], a8[8];
#pragma unroll
      for (int j = 0; j < 4; j++) w4[j] = Wt[kk][col4 + j];
#pragma unroll
      for (int m = 0; m < 8; m++) a8[m] = At[kk][rrow + m];
#pragma unroll
      for (int m = 0; m < 8; m++)
#pragma unroll
        for (int j = 0; j < 4; j++) acc[m][j] += a8[m] * w4[j];
    }
  }
#pragma unroll
  for (int m = 0; m < 8; m++) {
    int r = row0 + rrow + m;
    if (r < nrows) {
#pragma unroll
      for (int j = 0; j < 4; j++) C[(size_t)r * 128 + col4 + j] = __float2bfloat16(acc[m][j]);
    }
  }
}

// ---------------- per-node attention logits ----------------
__global__ __launch_bounds__(256) void alphas_kernel(const bf16* __restrict__ xw,
                                                     const void* __restrict__ aS, const void* __restrict__ aD,
                                                     float* __restrict__ as_, float* __restrict__ ad_, int N,
                                                     const int* __restrict__ dtflag) {
  int dt = dtflag[0];
  int wid = (blockIdx.x * blockDim.x + threadIdx.x) >> 6;
  int lane = threadIdx.x & 63;
  if (wid >= N) return;
  float v0 = toF(xw[(size_t)wid * 128 + lane]);
  float v1 = toF(xw[(size_t)wid * 128 + 64 + lane]);
  float s0 = v0 * ldf(aS, lane, dt);
  float s1 = v1 * ldf(aS, 64 + lane, dt);
  float t0 = v0 * ldf(aD, lane, dt);
  float t1 = v1 * ldf(aD, 64 + lane, dt);
#pragma unroll
  for (int off = 32; off > 0; off >>= 1) {
    s0 += __shfl_down(s0, off, 64);
    s1 += __shfl_down(s1, off, 64);
    t0 += __shfl_down(t0, off, 64);
    t1 += __shfl_down(t1, off, 64);
  }
  if (lane == 0) {
    as_[2 * wid] = s0; as_[2 * wid + 1] = s1;
    ad_[2 * wid] = t0; ad_[2 * wid + 1] = t1;
  }
}

// ---------------- GAT aggregate: one wave per dst node ----------------
__global__ __launch_bounds__(256) void gat_agg(const bf16* __restrict__ xw,
                                               const float* __restrict__ as_, const float* __restrict__ ad_,
                                               const int* __restrict__ rowstart, const int* __restrict__ adj,
                                               const void* __restrict__ bias, bf16* __restrict__ out, int N,
                                               const int* __restrict__ dtflag) {
  int dt = dtflag[0];
  int n = (blockIdx.x * blockDim.x + threadIdx.x) >> 6;
  int lane = threadIdx.x & 63;
  if (n >= N) return;
  int r0 = rowstart[n], r1 = rowstart[n + 1];
  float adv0 = ad_[2 * n], adv1 = ad_[2 * n + 1];
  // pass 1: segment max
  float m0 = -1e30f, m1 = -1e30f;
  for (int i = r0 + lane; i < r1; i += 64) {
    int s = adj[i];
    float e0 = as_[2 * s] + adv0; e0 = (e0 > 0.f) ? e0 : 0.2f * e0;
    float e1 = as_[2 * s + 1] + adv1; e1 = (e1 > 0.f) ? e1 : 0.2f * e1;
    m0 = fmaxf(m0, e0); m1 = fmaxf(m1, e1);
  }
#pragma unroll
  for (int off = 32; off > 0; off >>= 1) {
    m0 = fmaxf(m0, __shfl_down(m0, off, 64));
    m1 = fmaxf(m1, __shfl_down(m1, off, 64));
  }
  m0 = __shfl(m0, 0, 64); m1 = __shfl(m1, 0, 64);
  // pass 2: denom
  float d0 = 0.f, d1 = 0.f;
  for (int i = r0 + lane; i < r1; i += 64) {
    int s = adj[i];
    float e0 = as_[2 * s] + adv0; e0 = (e0 > 0.f) ? e0 : 0.2f * e0;
    float e1 = as_[2 * s + 1] + adv1; e1 = (e1 > 0.f) ? e1 : 0.2f * e1;
    d0 += __expf(e0 - m0); d1 += __expf(e1 - m1);
  }
#pragma unroll
  for (int off = 32; off > 0; off >>= 1) {
    d0 += __shfl_down(d0, off, 64);
    d1 += __shfl_down(d1, off, 64);
  }
  d0 = __shfl(d0, 0, 64); d1 = __shfl(d1, 0, 64);
  float inv0 = 1.f / (d0 + 1e-16f), inv1 = 1.f / (d1 + 1e-16f);
  // pass 3: weighted accumulate (whole wave per edge; lane = feature dim)
  float acc0 = 0.f, acc1 = 0.f;
  for (int i = r0; i < r1; i++) {
    int s = adj[i];
    float e0 = as_[2 * s] + adv0; e0 = (e0 > 0.f) ? e0 : 0.2f * e0;
    float e1 = as_[2 * s + 1] + adv1; e1 = (e1 > 0.f) ? e1 : 0.2f * e1;
    float w0 = __expf(e0 - m0), w1 = __expf(e1 - m1);
    acc0 += w0 * toF(xw[(size_t)s * 128 + lane]);
    acc1 += w1 * toF(xw[(size_t)s * 128 + 64 + lane]);
  }
  float o0 = acc0 * inv0 + ldf(bias, lane, dt);
  float o1 = acc1 * inv1 + ldf(bias, 64 + lane, dt);
  out[(size_t)n * 128 + lane] = __float2bfloat16(o0 > 0.f ? o0 : 0.f);
  out[(size_t)n * 128 + 64 + lane] = __float2bfloat16(o1 > 0.f ? o1 : 0.f);
}

// ---------------- head: mean-pool + readout + news + concat + sigmoid ----------------
__global__ __launch_bounds__(512) void head_kernel(
    const bf16* __restrict__ h, const void* __restrict__ x, const int* __restrict__ batch,
    const void* __restrict__ Wr, const void* __restrict__ br,
    const void* __restrict__ Wn, const void* __restrict__ bn,
    const void* __restrict__ Wc, const void* __restrict__ bc,
    void* __restrict__ out, int N, int IN, const int* __restrict__ dtflag) {
  int dt = dtflag[0];
  int b = blockIdx.x;
  int t = threadIdx.x;
  int c = t & 127, grp = t >> 7;  // 4 groups of 128
  __shared__ int sr0, sr1;
  if (t == 0) {
    int lo = 0, hi = N;
    while (lo < hi) { int mid = (lo + hi) >> 1; if (batch[mid] < b) lo = mid + 1; else hi = mid; }
    sr0 = lo;
    lo = 0; hi = N;
    int b1 = b + 1;
    while (lo < hi) { int mid = (lo + hi) >> 1; if (batch[mid] < b1) lo = mid + 1; else hi = mid; }
    sr1 = lo;
  }
  __syncthreads();
  int r0 = sr0, r1 = sr1;
  float sum = 0.f;
  for (int n = r0 + grp; n < r1; n += 4) sum += toF(h[(size_t)n * 128 + c]);
  __shared__ float pl[4][128];
  __shared__ float pooled_s[128];
  __shared__ float gred[128];
  pl[grp][c] = sum;
  __syncthreads();
  if (t < 128) {
    pooled_s[t] = (pl[0][t] + pl[1][t] + pl[2][t] + pl[3][t]) / (float)(r1 - r0);
  }
  __syncthreads();
  if (t < 128) {
    float gacc = 0.f;
    for (int k = 0; k < 128; k++) gacc += pooled_s[k] * ldf(Wr, k * 128 + t, dt);
    gacc += ldf(br, t, dt);
    float g = gacc > 0.f ? gacc : 0.f;
    float nacc = 0.f;
    for (int k = 0; k < IN; k++) nacc += ldf(x, (size_t)r0 * IN + k, dt) * ldf(Wn, k * 128 + t, dt);
    nacc += ldf(bn, t, dt);
    float nw = nacc > 0.f ? nacc : 0.f;
    gred[t] = g * ldf(Wc, t, dt) + nw * ldf(Wc, 128 + t, dt);
  }
  __syncthreads();
  for (int s = 64; s > 0; s >>= 1) {
    if (t < s) gred[t] += gred[t + s];
    __syncthreads();
  }
  if (t == 0) {
    float z = gred[0] + ldf(bc, 0, dt);
    float r = 1.f / (1.f + __expf(-z));
    if (dt) ((float*)out)[b] = r;
    else ((bf16*)out)[b] = __float2bfloat16(r);
  }
}

extern "C" void kernel_launch(void* const* d_in, const int* in_sizes, int n_in,
                              void* d_out, int out_size, void* d_ws, size_t ws_size,
                              hipStream_t stream) {
  const void* x   = d_in[0];
  const void* W0  = d_in[1];
  const void* aS0 = d_in[2];
  const void* aD0 = d_in[3];
  const void* b0  = d_in[4];
  const void* W1  = d_in[5];
  const void* aS1 = d_in[6];
  const void* aD1 = d_in[7];
  const void* b1  = d_in[8];
  const void* Wn  = d_in[9];
  const void* bn  = d_in[10];
  const void* Wr  = d_in[11];
  const void* br  = d_in[12];
  const void* Wc  = d_in[13];
  const void* bc  = d_in[14];
  const int* ei    = (const int*)d_in[15];
  const int* batch = (const int*)d_in[16];

  const int N = in_sizes[16];
  const int IN = in_sizes[0] / N;
  const int E = in_sizes[15] / 2;
  const int B = out_size;
  const int Etot = E + N;

  // workspace layout (all 256B aligned), total ~30.5 MB
  char* w = (char*)d_ws;
  size_t off = 0;
  int* flag = (int*)(w + off);            off += 256;
  bf16* bufA = (bf16*)(w + off);          off += ((size_t)N * 128 * 2 + 255) / 256 * 256;
  bf16* bufB = (bf16*)(w + off);          off += ((size_t)N * 128 * 2 + 255) / 256 * 256;
  float* as_ = (float*)(w + off);         off += ((size_t)N * 2 * 4 + 255) / 256 * 256;
  float* ad_ = (float*)(w + off);         off += ((size_t)N * 2 * 4 + 255) / 256 * 256;
  int* cnt = (int*)(w + off);             off += ((size_t)N * 4 + 255) / 256 * 256;
  int* rowstart = (int*)(w + off);        off += ((size_t)(N + 1) * 4 + 255) / 256 * 256;
  int* cursor = (int*)(w + off);          off += ((size_t)N * 4 + 255) / 256 * 256;
  int* adj = (int*)(w + off);             off += ((size_t)Etot * 4 + 255) / 256 * 256;

  int ndet = in_sizes[0] < 4096 ? in_sizes[0] : 4096;
  detect_dtype<<<1, 256, 0, stream>>>(x, ndet, flag);

  hipMemsetAsync(cnt, 0, sizeof(int) * N, stream);
  const int tb = 256;
  count_edges<<<(Etot + tb - 1) / tb, tb, 0, stream>>>(ei, N, E, cnt);
  scan_kernel<<<1, 1024, 0, stream>>>(cnt, rowstart, cursor, N);
  scatter_edges<<<(Etot + tb - 1) / tb, tb, 0, stream>>>(ei, N, E, cursor, adj);

  int gemm_grid = (N + 63) / 64;
  int wgrid = ((N * 64) + 255) / 256;  // one wave per node

  // Layer 0
  gemm_tile<true><<<gemm_grid, 256, 0, stream>>>(x, W0, bufA, N, IN, flag);
  alphas_kernel<<<wgrid, 256, 0, stream>>>(bufA, aS0, aD0, as_, ad_, N, flag);
  gat_agg<<<wgrid, 256, 0, stream>>>(bufA, as_, ad_, rowstart, adj, b0, bufB, N, flag);

  // Layer 1
  gemm_tile<false><<<gemm_grid, 256, 0, stream>>>(bufB, W1, bufA, N, 128, flag);
  alphas_kernel<<<wgrid, 256, 0, stream>>>(bufA, aS1, aD1, as_, ad_, N, flag);
  gat_agg<<<wgrid, 256, 0, stream>>>(bufA, as_, ad_, rowstart, adj, b1, bufB, N, flag);

  // Head
  head_kernel<<<B, 512, 0, stream>>>(bufB, x, batch, Wr, br, Wn, bn, Wc, bc, (void*)d_out, N, IN, flag);
}

// Round 3
// 620.499 us; speedup vs baseline: 1.2581x; 1.2581x over previous
//
#include <hip/hip_runtime.h>
#include <hip/hip_bf16.h>

typedef __hip_bfloat16 bf16;
typedef __attribute__((ext_vector_type(8))) __bf16 bf16x8;
typedef __attribute__((ext_vector_type(4))) float f32x4;

__device__ __forceinline__ float toF(bf16 v) { return __bfloat162float(v); }

// dual-dtype load: dt=1 -> underlying memory is fp32; dt=0 -> bf16
__device__ __forceinline__ float ldf(const void* p, size_t i, int dt) {
  return dt ? ((const float*)p)[i] : __bfloat162float(((const bf16*)p)[i]);
}
__device__ __forceinline__ ushort toBF(float f) {
  union { bf16 b; ushort u; } cv; cv.b = __float2bfloat16(f); return cv.u;
}

// ---------------- dtype detection ----------------
__global__ void detect_dtype(const void* x, int n, int* flag) {
  __shared__ int s;
  if (threadIdx.x == 0) s = 0;
  __syncthreads();
  const bf16* xb = (const bf16*)x;
  int bad = 0;
  for (int i = threadIdx.x; i < n; i += 256) {
    float v = __bfloat162float(xb[i]);
    if (!(fabsf(v) < 1e6f)) bad = 1;
  }
  if (bad) atomicOr(&s, 1);
  __syncthreads();
  if (threadIdx.x == 0) flag[0] = s;
}

// ---------------- CSR build ----------------
__global__ void count_edges(const int* __restrict__ ei, int N, int E, int* __restrict__ cnt) {
  int e = blockIdx.x * blockDim.x + threadIdx.x;
  int Etot = E + N;
  if (e >= Etot) return;
  int d = (e < E) ? ei[E + e] : (e - E);
  atomicAdd(&cnt[d], 1);
}

// phase A: per-1024-chunk sums
__global__ __launch_bounds__(256) void scan_reduce(const int* __restrict__ cnt, int n, int* __restrict__ csum) {
  int base = blockIdx.x * 1024;
  int t = threadIdx.x;
  int s = 0;
#pragma unroll
  for (int j = 0; j < 4; j++) {
    int i = base + t * 4 + j;
    if (i < n) s += cnt[i];
  }
#pragma unroll
  for (int off = 32; off > 0; off >>= 1) s += __shfl_down(s, off, 64);
  __shared__ int ws[4];
  if ((t & 63) == 0) ws[t >> 6] = s;
  __syncthreads();
  if (t == 0) csum[blockIdx.x] = ws[0] + ws[1] + ws[2] + ws[3];
}

// phase B: single block scans up to 256 chunk sums in place (csum -> exclusive), writes total
__global__ __launch_bounds__(256) void scan_top(int* __restrict__ csum, int nb, int* __restrict__ rowstart, int n) {
  __shared__ int sc[256];
  int t = threadIdx.x;
  int v0 = (t < nb) ? csum[t] : 0;
  sc[t] = v0;
  for (int off = 1; off < 256; off <<= 1) {
    __syncthreads();
    int v = (t >= off) ? sc[t - off] : 0;
    __syncthreads();
    sc[t] += v;
  }
  __syncthreads();
  if (t < nb) csum[t] = sc[t] - v0;  // exclusive
  if (t == 0) rowstart[n] = sc[255]; // total
}

// phase C: downsweep — element-wise exclusive scan within each chunk + chunk offset
__global__ __launch_bounds__(256) void scan_down(const int* __restrict__ cnt, int n,
                                                 const int* __restrict__ csum,
                                                 int* __restrict__ rowstart, int* __restrict__ cursor) {
  int base = blockIdx.x * 1024;
  int t = threadIdx.x, lane = t & 63, w = t >> 6;
  int v[4];
#pragma unroll
  for (int j = 0; j < 4; j++) {
    int i = base + t * 4 + j;
    v[j] = (i < n) ? cnt[i] : 0;
  }
  int s1 = v[0], s2 = s1 + v[1], s3 = s2 + v[2], s4 = s3 + v[3];
  // wave inclusive scan of thread totals
  int x = s4;
#pragma unroll
  for (int off = 1; off < 64; off <<= 1) {
    int y = __shfl_up(x, off, 64);
    if (lane >= off) x += y;
  }
  int texcl = x - s4;
  __shared__ int ws[4];
  if (lane == 63) ws[w] = x;
  __syncthreads();
  int woff = 0;
  for (int i = 0; i < 4; i++) if (i < w) woff += ws[i];
  int b0 = csum[blockIdx.x] + woff + texcl;
  int e0 = b0, e1 = b0 + s1, e2 = b0 + s2, e3 = b0 + s3;
  int i0 = base + t * 4;
  if (i0 + 0 < n) { rowstart[i0 + 0] = e0; cursor[i0 + 0] = e0; }
  if (i0 + 1 < n) { rowstart[i0 + 1] = e1; cursor[i0 + 1] = e1; }
  if (i0 + 2 < n) { rowstart[i0 + 2] = e2; cursor[i0 + 2] = e2; }
  if (i0 + 3 < n) { rowstart[i0 + 3] = e3; cursor[i0 + 3] = e3; }
}

__global__ void scatter_edges(const int* __restrict__ ei, int N, int E,
                              int* __restrict__ cursor, int* __restrict__ adj) {
  int e = blockIdx.x * blockDim.x + threadIdx.x;
  int Etot = E + N;
  if (e >= Etot) return;
  int d, s;
  if (e < E) { s = ei[e]; d = ei[E + e]; } else { s = e - E; d = s; }
  int pos = atomicAdd(&cursor[d], 1);
  adj[pos] = s;
}

// ---------------- weight pre-transpose (+K pad to mult of 32), bf16 out -------------
// Wt[c][k] = W[k][c], k in [0,Kpad), zero for k >= K
__global__ void pack_wt(const void* __restrict__ W, ushort* __restrict__ Wt, int K, int Kpad,
                        const int* __restrict__ dtflag) {
  int dt = dtflag[0];
  int c = blockIdx.x;           // 0..127
  int k = threadIdx.x;          // 0..Kpad-1 (blockDim = Kpad)
  float v = (k < K) ? ldf(W, (size_t)k * 128 + c, dt) : 0.f;
  Wt[(size_t)c * Kpad + k] = toBF(v);
}

// ---------------- MFMA GEMM: C[nrows,128] = A[nrows,K] @ W[K,128] ----------------
// Wt is pre-transposed [128][Kpad] bf16. Block tile 128x128, BK=32, 256 threads (4 waves).
// DUALA: A is a d_in tensor (dtype per flag), scalar-staged. else: A is bf16 [nrows][K], K%32==0, vector-staged.
template <bool DUALA>
__global__ __launch_bounds__(256) void mfma_gemm(const void* __restrict__ A, const ushort* __restrict__ Wt,
                                                 bf16* __restrict__ C, int nrows, int K, int Kpad,
                                                 const int* __restrict__ dtflag) {
  __shared__ __align__(16) ushort As[128 * 32];
  __shared__ __align__(16) ushort Ws[128 * 32];
  int dt = DUALA ? dtflag[0] : 0;
  int tid = threadIdx.x;
  int wave = tid >> 6, lane = tid & 63;
  int m = lane & 15, q = lane >> 4;
  int row0 = blockIdx.x * 128;

  f32x4 acc[2][8];
#pragma unroll
  for (int p = 0; p < 2; p++)
#pragma unroll
    for (int ct = 0; ct < 8; ct++) acc[p][ct] = (f32x4){0.f, 0.f, 0.f, 0.f};

  for (int k0 = 0; k0 < Kpad; k0 += 32) {
    // stage A tile [128][32]
    if (DUALA) {
#pragma unroll
      for (int i = 0; i < 16; i++) {
        int e = tid + i * 256;
        int row = e >> 5, kk = e & 31;
        int gr = row0 + row, gk = k0 + kk;
        float v = (gr < nrows && gk < K) ? ldf(A, (size_t)gr * K + gk, dt) : 0.f;
        As[row * 32 + kk] = toBF(v);
      }
    } else {
#pragma unroll
      for (int i = 0; i < 2; i++) {
        int e = tid + i * 256;
        int row = e >> 2, kc = (e & 3) * 8;
        int gr = row0 + row;
        uint4 v = (gr < nrows) ? *(const uint4*)((const ushort*)A + (size_t)gr * K + k0 + kc)
                               : (uint4){0u, 0u, 0u, 0u};
        *(uint4*)&As[row * 32 + kc] = v;
      }
    }
    // stage W tile [128][32] (already transposed: Wt[c][k])
#pragma unroll
    for (int i = 0; i < 2; i++) {
      int e = tid + i * 256;
      int col = e >> 2, kc = (e & 3) * 8;
      *(uint4*)&Ws[col * 32 + kc] = *(const uint4*)&Wt[(size_t)col * Kpad + k0 + kc];
    }
    __syncthreads();
    bf16x8 af[2];
#pragma unroll
    for (int p = 0; p < 2; p++)
      af[p] = *(const bf16x8*)&As[((wave * 2 + p) * 16 + m) * 32 + q * 8];
#pragma unroll
    for (int ct = 0; ct < 8; ct++) {
      bf16x8 bf_ = *(const bf16x8*)&Ws[(ct * 16 + m) * 32 + q * 8];
#pragma unroll
      for (int p = 0; p < 2; p++)
        acc[p][ct] = __builtin_amdgcn_mfma_f32_16x16x32_bf16(af[p], bf_, acc[p][ct], 0, 0, 0);
    }
    __syncthreads();
  }
#pragma unroll
  for (int p = 0; p < 2; p++) {
#pragma unroll
    for (int ct = 0; ct < 8; ct++) {
#pragma unroll
      for (int r = 0; r < 4; r++) {
        int grow = row0 + (wave * 2 + p) * 16 + q * 4 + r;
        if (grow < nrows) C[(size_t)grow * 128 + ct * 16 + m] = __float2bfloat16(acc[p][ct][r]);
      }
    }
  }
}

// ---------------- per-node attention logits ----------------
__global__ __launch_bounds__(256) void alphas_kernel(const bf16* __restrict__ xw,
                                                     const void* __restrict__ aS, const void* __restrict__ aD,
                                                     float* __restrict__ as_, float* __restrict__ ad_, int N,
                                                     const int* __restrict__ dtflag) {
  int dt = dtflag[0];
  int wid = (blockIdx.x * blockDim.x + threadIdx.x) >> 6;
  int lane = threadIdx.x & 63;
  if (wid >= N) return;
  float v0 = toF(xw[(size_t)wid * 128 + lane]);
  float v1 = toF(xw[(size_t)wid * 128 + 64 + lane]);
  float s0 = v0 * ldf(aS, lane, dt);
  float s1 = v1 * ldf(aS, 64 + lane, dt);
  float t0 = v0 * ldf(aD, lane, dt);
  float t1 = v1 * ldf(aD, 64 + lane, dt);
#pragma unroll
  for (int off = 32; off > 0; off >>= 1) {
    s0 += __shfl_down(s0, off, 64);
    s1 += __shfl_down(s1, off, 64);
    t0 += __shfl_down(t0, off, 64);
    t1 += __shfl_down(t1, off, 64);
  }
  if (lane == 0) {
    as_[2 * wid] = s0; as_[2 * wid + 1] = s1;
    ad_[2 * wid] = t0; ad_[2 * wid + 1] = t1;
  }
}

// ---------------- GAT aggregate: one wave per dst node ----------------
__global__ __launch_bounds__(256) void gat_agg(const bf16* __restrict__ xw,
                                               const float* __restrict__ as_, const float* __restrict__ ad_,
                                               const int* __restrict__ rowstart, const int* __restrict__ adj,
                                               const void* __restrict__ bias, bf16* __restrict__ out, int N,
                                               const int* __restrict__ dtflag) {
  int dt = dtflag[0];
  int n = (blockIdx.x * blockDim.x + threadIdx.x) >> 6;
  int lane = threadIdx.x & 63;
  if (n >= N) return;
  int r0 = rowstart[n], r1 = rowstart[n + 1];
  float adv0 = ad_[2 * n], adv1 = ad_[2 * n + 1];
  float m0 = -1e30f, m1 = -1e30f;
  for (int i = r0 + lane; i < r1; i += 64) {
    int s = adj[i];
    float e0 = as_[2 * s] + adv0; e0 = (e0 > 0.f) ? e0 : 0.2f * e0;
    float e1 = as_[2 * s + 1] + adv1; e1 = (e1 > 0.f) ? e1 : 0.2f * e1;
    m0 = fmaxf(m0, e0); m1 = fmaxf(m1, e1);
  }
#pragma unroll
  for (int off = 32; off > 0; off >>= 1) {
    m0 = fmaxf(m0, __shfl_down(m0, off, 64));
    m1 = fmaxf(m1, __shfl_down(m1, off, 64));
  }
  m0 = __shfl(m0, 0, 64); m1 = __shfl(m1, 0, 64);
  float d0 = 0.f, d1 = 0.f;
  for (int i = r0 + lane; i < r1; i += 64) {
    int s = adj[i];
    float e0 = as_[2 * s] + adv0; e0 = (e0 > 0.f) ? e0 : 0.2f * e0;
    float e1 = as_[2 * s + 1] + adv1; e1 = (e1 > 0.f) ? e1 : 0.2f * e1;
    d0 += __expf(e0 - m0); d1 += __expf(e1 - m1);
  }
#pragma unroll
  for (int off = 32; off > 0; off >>= 1) {
    d0 += __shfl_down(d0, off, 64);
    d1 += __shfl_down(d1, off, 64);
  }
  d0 = __shfl(d0, 0, 64); d1 = __shfl(d1, 0, 64);
  float inv0 = 1.f / (d0 + 1e-16f), inv1 = 1.f / (d1 + 1e-16f);
  float acc0 = 0.f, acc1 = 0.f;
  for (int i = r0; i < r1; i++) {
    int s = adj[i];
    float e0 = as_[2 * s] + adv0; e0 = (e0 > 0.f) ? e0 : 0.2f * e0;
    float e1 = as_[2 * s + 1] + adv1; e1 = (e1 > 0.f) ? e1 : 0.2f * e1;
    float w0 = __expf(e0 - m0), w1 = __expf(e1 - m1);
    acc0 += w0 * toF(xw[(size_t)s * 128 + lane]);
    acc1 += w1 * toF(xw[(size_t)s * 128 + 64 + lane]);
  }
  float o0 = acc0 * inv0 + ldf(bias, lane, dt);
  float o1 = acc1 * inv1 + ldf(bias, 64 + lane, dt);
  out[(size_t)n * 128 + lane] = __float2bfloat16(o0 > 0.f ? o0 : 0.f);
  out[(size_t)n * 128 + 64 + lane] = __float2bfloat16(o1 > 0.f ? o1 : 0.f);
}

// ---------------- parallel mean-pool (unnormalized sums; contiguous batch) ----------------
__global__ __launch_bounds__(256) void pool_kernel(const bf16* __restrict__ h, const int* __restrict__ batch,
                                                   float* __restrict__ pooled, int N) {
  int n0 = blockIdx.x * 128;
  int nEnd = n0 + 128 < N ? n0 + 128 : N;
  int col = threadIdx.x & 127, half = threadIdx.x >> 7;
  float acc = 0.f;
  int cur = -1;
  for (int n = n0 + half; n < nEnd; n += 2) {
    int g = batch[n];
    if (g != cur) {
      if (cur >= 0) atomicAdd(&pooled[(size_t)cur * 128 + col], acc);
      acc = 0.f; cur = g;
    }
    acc += toF(h[(size_t)n * 128 + col]);
  }
  if (cur >= 0) atomicAdd(&pooled[(size_t)cur * 128 + col], acc);
}

// ---------------- head: readout + news + concat + sigmoid ----------------
__global__ __launch_bounds__(128) void head2_kernel(
    const float* __restrict__ pooled, const void* __restrict__ x, const int* __restrict__ batch,
    const void* __restrict__ Wr, const void* __restrict__ br,
    const void* __restrict__ Wn, const void* __restrict__ bn,
    const void* __restrict__ Wc, const void* __restrict__ bc,
    void* __restrict__ out, int N, int IN, const int* __restrict__ dtflag) {
  int dt = dtflag[0];
  int b = blockIdx.x;
  int t = threadIdx.x;
  __shared__ int sr0, sr1;
  if (t == 0) {
    int lo = 0, hi = N;
    while (lo < hi) { int mid = (lo + hi) >> 1; if (batch[mid] < b) lo = mid + 1; else hi = mid; }
    sr0 = lo;
    lo = 0; hi = N;
    int b1 = b + 1;
    while (lo < hi) { int mid = (lo + hi) >> 1; if (batch[mid] < b1) lo = mid + 1; else hi = mid; }
    sr1 = lo;
  }
  __syncthreads();
  int r0 = sr0, r1 = sr1;
  float inv_cnt = 1.f / (float)(r1 - r0);
  __shared__ float pl[128];
  __shared__ float xs[512];
  __shared__ float red[128];
  pl[t] = pooled[(size_t)b * 128 + t] * inv_cnt;
  for (int k = t; k < IN; k += 128) xs[k] = ldf(x, (size_t)r0 * IN + k, dt);
  __syncthreads();
  float gacc = 0.f;
  for (int k = 0; k < 128; k++) gacc += pl[k] * ldf(Wr, (size_t)k * 128 + t, dt);
  gacc += ldf(br, t, dt);
  float g = gacc > 0.f ? gacc : 0.f;
  float nacc = 0.f;
  for (int k = 0; k < IN; k++) nacc += xs[k] * ldf(Wn, (size_t)k * 128 + t, dt);
  nacc += ldf(bn, t, dt);
  float nw = nacc > 0.f ? nacc : 0.f;
  red[t] = g * ldf(Wc, t, dt) + nw * ldf(Wc, 128 + t, dt);
  __syncthreads();
  for (int s = 64; s > 0; s >>= 1) {
    if (t < s) red[t] += red[t + s];
    __syncthreads();
  }
  if (t == 0) {
    float z = red[0] + ldf(bc, 0, dt);
    float r = 1.f / (1.f + __expf(-z));
    if (dt) ((float*)out)[b] = r;
    else ((bf16*)out)[b] = __float2bfloat16(r);
  }
}

extern "C" void kernel_launch(void* const* d_in, const int* in_sizes, int n_in,
                              void* d_out, int out_size, void* d_ws, size_t ws_size,
                              hipStream_t stream) {
  const void* x   = d_in[0];
  const void* W0  = d_in[1];
  const void* aS0 = d_in[2];
  const void* aD0 = d_in[3];
  const void* b0  = d_in[4];
  const void* W1  = d_in[5];
  const void* aS1 = d_in[6];
  const void* aD1 = d_in[7];
  const void* b1  = d_in[8];
  const void* Wn  = d_in[9];
  const void* bn  = d_in[10];
  const void* Wr  = d_in[11];
  const void* br  = d_in[12];
  const void* Wc  = d_in[13];
  const void* bc  = d_in[14];
  const int* ei    = (const int*)d_in[15];
  const int* batch = (const int*)d_in[16];

  const int N = in_sizes[16];
  const int IN = in_sizes[0] / N;
  const int E = in_sizes[15] / 2;
  const int B = out_size;
  const int Etot = E + N;
  const int Kpad0 = (IN + 31) / 32 * 32;   // 320

  // workspace layout
  char* w = (char*)d_ws;
  size_t off = 0;
  auto alloc = [&](size_t bytes) { void* p = w + off; off += (bytes + 255) / 256 * 256; return p; };
  int* flag      = (int*)alloc(256);
  bf16* bufA     = (bf16*)alloc((size_t)N * 128 * 2);     // xw (both layers)
  bf16* bufB     = (bf16*)alloc((size_t)N * 128 * 2);     // h0 then h1
  float* as_     = (float*)alloc((size_t)N * 2 * 4);
  float* ad_     = (float*)alloc((size_t)N * 2 * 4);
  int* cnt       = (int*)alloc((size_t)N * 4);
  int* rowstart  = (int*)alloc((size_t)(N + 1) * 4);
  int* cursor    = (int*)alloc((size_t)N * 4);
  int* adj       = (int*)alloc((size_t)Etot * 4);
  int* csum      = (int*)alloc(1024);                     // chunk sums (<=256)
  ushort* Wt0    = (ushort*)alloc((size_t)128 * Kpad0 * 2);
  ushort* Wt1    = (ushort*)alloc((size_t)128 * 128 * 2);
  float* pooled  = (float*)alloc((size_t)B * 128 * 4);

  int ndet = in_sizes[0] < 4096 ? in_sizes[0] : 4096;
  detect_dtype<<<1, 256, 0, stream>>>(x, ndet, flag);

  hipMemsetAsync(cnt, 0, sizeof(int) * N, stream);
  hipMemsetAsync(pooled, 0, sizeof(float) * (size_t)B * 128, stream);

  const int tb = 256;
  count_edges<<<(Etot + tb - 1) / tb, tb, 0, stream>>>(ei, N, E, cnt);
  int nb = (N + 1023) / 1024;
  scan_reduce<<<nb, 256, 0, stream>>>(cnt, N, csum);
  scan_top<<<1, 256, 0, stream>>>(csum, nb, rowstart, N);
  scan_down<<<nb, 256, 0, stream>>>(cnt, N, csum, rowstart, cursor);
  scatter_edges<<<(Etot + tb - 1) / tb, tb, 0, stream>>>(ei, N, E, cursor, adj);

  pack_wt<<<128, Kpad0, 0, stream>>>(W0, Wt0, IN, Kpad0, flag);
  pack_wt<<<128, 128, 0, stream>>>(W1, Wt1, 128, 128, flag);

  int ggrid = (N + 127) / 128;
  int wgrid = ((N * 64) + 255) / 256;

  // Layer 0
  mfma_gemm<true><<<ggrid, 256, 0, stream>>>(x, Wt0, bufA, N, IN, Kpad0, flag);
  alphas_kernel<<<wgrid, 256, 0, stream>>>(bufA, aS0, aD0, as_, ad_, N, flag);
  gat_agg<<<wgrid, 256, 0, stream>>>(bufA, as_, ad_, rowstart, adj, b0, bufB, N, flag);

  // Layer 1
  mfma_gemm<false><<<ggrid, 256, 0, stream>>>(bufB, Wt1, bufA, N, 128, 128, flag);
  alphas_kernel<<<wgrid, 256, 0, stream>>>(bufA, aS1, aD1, as_, ad_, N, flag);
  gat_agg<<<wgrid, 256, 0, stream>>>(bufA, as_, ad_, rowstart, adj, b1, bufB, N, flag);

  // Head
  pool_kernel<<<ggrid, 256, 0, stream>>>(bufB, batch, pooled, N);
  head2_kernel<<<B, 128, 0, stream>>>(pooled, x, batch, Wr, br, Wn, bn, Wc, bc,
                                      (void*)d_out, N, IN, flag);
}

// Round 4
// 482.386 us; speedup vs baseline: 1.6182x; 1.2863x over previous
//
#include <hip/hip_runtime.h>
#include <hip/hip_bf16.h>

typedef __hip_bfloat16 bf16;
typedef __attribute__((ext_vector_type(8))) __bf16 bf16x8;
typedef __attribute__((ext_vector_type(4))) float f32x4;

__device__ __forceinline__ float toF(bf16 v) { return __bfloat162float(v); }

// dual-dtype load: dt=1 -> underlying memory is fp32; dt=0 -> bf16
__device__ __forceinline__ float ldf(const void* p, size_t i, int dt) {
  return dt ? ((const float*)p)[i] : __bfloat162float(((const bf16*)p)[i]);
}
__device__ __forceinline__ ushort toBF(float f) {
  union { bf16 b; ushort u; } cv; cv.b = __float2bfloat16(f); return cv.u;
}

// ---------------- dtype detection ----------------
__global__ void detect_dtype(const void* x, int n, int* flag) {
  __shared__ int s;
  if (threadIdx.x == 0) s = 0;
  __syncthreads();
  const bf16* xb = (const bf16*)x;
  int bad = 0;
  for (int i = threadIdx.x; i < n; i += 256) {
    float v = __bfloat162float(xb[i]);
    if (!(fabsf(v) < 1e6f)) bad = 1;
  }
  if (bad) atomicOr(&s, 1);
  __syncthreads();
  if (threadIdx.x == 0) flag[0] = s;
}

// ---------------- CSR build ----------------
__global__ void count_edges(const int* __restrict__ ei, int N, int E, int* __restrict__ cnt) {
  int e = blockIdx.x * blockDim.x + threadIdx.x;
  int Etot = E + N;
  if (e >= Etot) return;
  int d = (e < E) ? ei[E + e] : (e - E);
  atomicAdd(&cnt[d], 1);
}

__global__ __launch_bounds__(256) void scan_reduce(const int* __restrict__ cnt, int n, int* __restrict__ csum) {
  int base = blockIdx.x * 1024;
  int t = threadIdx.x;
  int s = 0;
#pragma unroll
  for (int j = 0; j < 4; j++) {
    int i = base + t * 4 + j;
    if (i < n) s += cnt[i];
  }
#pragma unroll
  for (int off = 32; off > 0; off >>= 1) s += __shfl_down(s, off, 64);
  __shared__ int ws[4];
  if ((t & 63) == 0) ws[t >> 6] = s;
  __syncthreads();
  if (t == 0) csum[blockIdx.x] = ws[0] + ws[1] + ws[2] + ws[3];
}

__global__ __launch_bounds__(256) void scan_top(int* __restrict__ csum, int nb, int* __restrict__ rowstart, int n) {
  __shared__ int sc[256];
  int t = threadIdx.x;
  int v0 = (t < nb) ? csum[t] : 0;
  sc[t] = v0;
  for (int off = 1; off < 256; off <<= 1) {
    __syncthreads();
    int v = (t >= off) ? sc[t - off] : 0;
    __syncthreads();
    sc[t] += v;
  }
  __syncthreads();
  if (t < nb) csum[t] = sc[t] - v0;  // exclusive
  if (t == 0) rowstart[n] = sc[255]; // total
}

__global__ __launch_bounds__(256) void scan_down(const int* __restrict__ cnt, int n,
                                                 const int* __restrict__ csum,
                                                 int* __restrict__ rowstart, int* __restrict__ cursor) {
  int base = blockIdx.x * 1024;
  int t = threadIdx.x, lane = t & 63, w = t >> 6;
  int v[4];
#pragma unroll
  for (int j = 0; j < 4; j++) {
    int i = base + t * 4 + j;
    v[j] = (i < n) ? cnt[i] : 0;
  }
  int s1 = v[0], s2 = s1 + v[1], s3 = s2 + v[2], s4 = s3 + v[3];
  int x = s4;
#pragma unroll
  for (int off = 1; off < 64; off <<= 1) {
    int y = __shfl_up(x, off, 64);
    if (lane >= off) x += y;
  }
  int texcl = x - s4;
  __shared__ int ws[4];
  if (lane == 63) ws[w] = x;
  __syncthreads();
  int woff = 0;
  for (int i = 0; i < 4; i++) if (i < w) woff += ws[i];
  int b0 = csum[blockIdx.x] + woff + texcl;
  int e0 = b0, e1 = b0 + s1, e2 = b0 + s2, e3 = b0 + s3;
  int i0 = base + t * 4;
  if (i0 + 0 < n) { rowstart[i0 + 0] = e0; cursor[i0 + 0] = e0; }
  if (i0 + 1 < n) { rowstart[i0 + 1] = e1; cursor[i0 + 1] = e1; }
  if (i0 + 2 < n) { rowstart[i0 + 2] = e2; cursor[i0 + 2] = e2; }
  if (i0 + 3 < n) { rowstart[i0 + 3] = e3; cursor[i0 + 3] = e3; }
}

__global__ void scatter_edges(const int* __restrict__ ei, int N, int E,
                              int* __restrict__ cursor, int* __restrict__ adj) {
  int e = blockIdx.x * blockDim.x + threadIdx.x;
  int Etot = E + N;
  if (e >= Etot) return;
  int d, s;
  if (e < E) { s = ei[e]; d = ei[E + e]; } else { s = e - E; d = s; }
  int pos = atomicAdd(&cursor[d], 1);
  adj[pos] = s;
}

// ---------------- weight pre-transpose: Wt[c][k] = W[k][c], bf16 ----------------
__global__ void pack_wt(const void* __restrict__ W, ushort* __restrict__ Wt, int K, int Kpad,
                        const int* __restrict__ dtflag) {
  int dt = dtflag[0];
  int c = blockIdx.x;
  int k = threadIdx.x;
  if (k >= Kpad) return;
  float v = (k < K) ? ldf(W, (size_t)k * 128 + c, dt) : 0.f;
  Wt[(size_t)c * Kpad + k] = toBF(v);
}

// ---------------- MFMA GEMM + fused attention logits ----------------
// C[nrows,128] = A[nrows,K] @ W[K,128]; also as2[n]={alpha_src_h0,h1}, ad2[n]={alpha_dst_h0,h1}
// computed from the fp32 accumulator (dot with aS/aD + cross-lane reduce).
// Block tile 128x128, BK=32, 256 threads (4 waves).
template <bool DUALA>
__global__ __launch_bounds__(256) void mfma_gemm(const void* __restrict__ A, const ushort* __restrict__ Wt,
                                                 bf16* __restrict__ C,
                                                 float2* __restrict__ as2, float2* __restrict__ ad2,
                                                 const void* __restrict__ aS, const void* __restrict__ aD,
                                                 int nrows, int K, int Kpad,
                                                 const int* __restrict__ dtflag) {
  __shared__ __align__(16) ushort As[128 * 32];
  __shared__ __align__(16) ushort Ws[128 * 32];
  int dtg = dtflag[0];
  int tid = threadIdx.x;
  int wave = tid >> 6, lane = tid & 63;
  int m = lane & 15, q = lane >> 4;
  int row0 = blockIdx.x * 128;

  f32x4 acc[2][8];
#pragma unroll
  for (int p = 0; p < 2; p++)
#pragma unroll
    for (int ct = 0; ct < 8; ct++) acc[p][ct] = (f32x4){0.f, 0.f, 0.f, 0.f};

  for (int k0 = 0; k0 < Kpad; k0 += 32) {
    // ---- stage A tile [128][32] ----
    if (DUALA) {
      if (dtg == 0) {
        // bf16 source, rows 4B-aligned (stride K*2, K may be odd*2... 620B: 4B aligned)
        const unsigned char* Ab = (const unsigned char*)A;
#pragma unroll
        for (int i = 0; i < 8; i++) {
          int e = tid + i * 256;
          int row = e >> 4, kk = (e & 15) * 2;
          int gr = row0 + row, gk = k0 + kk;
          uint pv = 0;
          if (gr < nrows) {
            if (gk + 1 < K) pv = *(const uint*)(Ab + (size_t)gr * (K * 2) + (size_t)gk * 2);
            else if (gk < K) pv = *(const ushort*)(Ab + (size_t)gr * (K * 2) + (size_t)gk * 2);
          }
          *(uint*)&As[row * 32 + kk] = pv;
        }
      } else {
        const float* Af = (const float*)A;
#pragma unroll
        for (int i = 0; i < 16; i++) {
          int e = tid + i * 256;
          int row = e >> 5, kk = e & 31;
          int gr = row0 + row, gk = k0 + kk;
          float v = (gr < nrows && gk < K) ? Af[(size_t)gr * K + gk] : 0.f;
          As[row * 32 + kk] = toBF(v);
        }
      }
    } else {
#pragma unroll
      for (int i = 0; i < 2; i++) {
        int e = tid + i * 256;
        int row = e >> 2, kc = (e & 3) * 8;
        int gr = row0 + row;
        uint4 v = (gr < nrows) ? *(const uint4*)((const ushort*)A + (size_t)gr * K + k0 + kc)
                               : (uint4){0u, 0u, 0u, 0u};
        *(uint4*)&As[row * 32 + kc] = v;
      }
    }
    // ---- stage W tile [128][32] ----
#pragma unroll
    for (int i = 0; i < 2; i++) {
      int e = tid + i * 256;
      int col = e >> 2, kc = (e & 3) * 8;
      *(uint4*)&Ws[col * 32 + kc] = *(const uint4*)&Wt[(size_t)col * Kpad + k0 + kc];
    }
    __syncthreads();
    bf16x8 af[2];
#pragma unroll
    for (int p = 0; p < 2; p++)
      af[p] = *(const bf16x8*)&As[((wave * 2 + p) * 16 + m) * 32 + q * 8];
#pragma unroll
    for (int ct = 0; ct < 8; ct++) {
      bf16x8 bf_ = *(const bf16x8*)&Ws[(ct * 16 + m) * 32 + q * 8];
#pragma unroll
      for (int p = 0; p < 2; p++)
        acc[p][ct] = __builtin_amdgcn_mfma_f32_16x16x32_bf16(af[p], bf_, acc[p][ct], 0, 0, 0);
    }
    __syncthreads();
  }

  // ---- C writeback ----
#pragma unroll
  for (int p = 0; p < 2; p++) {
#pragma unroll
    for (int ct = 0; ct < 8; ct++) {
#pragma unroll
      for (int r = 0; r < 4; r++) {
        int grow = row0 + (wave * 2 + p) * 16 + q * 4 + r;
        if (grow < nrows) C[(size_t)grow * 128 + ct * 16 + m] = __float2bfloat16(acc[p][ct][r]);
      }
    }
  }

  // ---- fused attention logits ----
  // row R (held by 16 lanes with fixed q, m=0..15): cols ct*16+m. Head0 = ct<4, head1 = ct>=4.
  float aSv[8], aDv[8];
#pragma unroll
  for (int ct = 0; ct < 8; ct++) {
    aSv[ct] = ldf(aS, ct * 16 + m, dtg);
    aDv[ct] = ldf(aD, ct * 16 + m, dtg);
  }
#pragma unroll
  for (int p = 0; p < 2; p++) {
#pragma unroll
    for (int r = 0; r < 4; r++) {
      float s0 = 0.f, s1 = 0.f, d0 = 0.f, d1 = 0.f;
#pragma unroll
      for (int ct = 0; ct < 4; ct++) {
        float v = acc[p][ct][r];
        s0 += v * aSv[ct]; d0 += v * aDv[ct];
      }
#pragma unroll
      for (int ct = 4; ct < 8; ct++) {
        float v = acc[p][ct][r];
        s1 += v * aSv[ct]; d1 += v * aDv[ct];
      }
#pragma unroll
      for (int off = 1; off < 16; off <<= 1) {
        s0 += __shfl_xor(s0, off, 64);
        s1 += __shfl_xor(s1, off, 64);
        d0 += __shfl_xor(d0, off, 64);
        d1 += __shfl_xor(d1, off, 64);
      }
      int grow = row0 + (wave * 2 + p) * 16 + q * 4 + r;
      if (m == 0 && grow < nrows) {
        as2[grow] = make_float2(s0, s1);
        ad2[grow] = make_float2(d0, d1);
      }
    }
  }
}

// ---------------- GAT aggregate v2: one wave per dst, LDS-cached softmax weights -------
#define GCAP 128
__global__ __launch_bounds__(256) void gat_agg2(const bf16* __restrict__ xw,
                                                const float2* __restrict__ as2, const float2* __restrict__ ad2,
                                                const int* __restrict__ rowstart, const int* __restrict__ adj,
                                                const void* __restrict__ bias, bf16* __restrict__ out, int N,
                                                const int* __restrict__ dtflag) {
  __shared__ float sW0[4][GCAP];
  __shared__ float sW1[4][GCAP];
  __shared__ int sS[4][GCAP];
  int dt = dtflag[0];
  int wslot = threadIdx.x >> 6;
  int lane = threadIdx.x & 63;
  int n = (blockIdx.x * blockDim.x + threadIdx.x) >> 6;
  bool act = n < N;
  int r0 = 0, r1 = 0;
  float2 adv = make_float2(0.f, 0.f);
  if (act) { r0 = rowstart[n]; r1 = rowstart[n + 1]; adv = ad2[n]; }
  int deg = r1 - r0;

  // loop 1: logits into regs (<=2 per lane), running max
  float e0a[2], e1a[2];
  int sa[2];
  float m0 = -1e30f, m1 = -1e30f;
#pragma unroll
  for (int j = 0; j < 2; j++) {
    int i = r0 + lane + 64 * j;
    bool v = act && i < r1;
    int s = v ? adj[i] : 0;
    sa[j] = s;
    float e0 = -1e30f, e1 = -1e30f;
    if (v) {
      float2 asv = as2[s];
      e0 = asv.x + adv.x; e0 = (e0 > 0.f) ? e0 : 0.2f * e0;
      e1 = asv.y + adv.y; e1 = (e1 > 0.f) ? e1 : 0.2f * e1;
    }
    e0a[j] = e0; e1a[j] = e1;
    m0 = fmaxf(m0, e0); m1 = fmaxf(m1, e1);
  }
  for (int i = r0 + GCAP + lane; i < r1; i += 64) {  // overflow tail (rare)
    int s = adj[i];
    float2 asv = as2[s];
    float e0 = asv.x + adv.x; e0 = (e0 > 0.f) ? e0 : 0.2f * e0;
    float e1 = asv.y + adv.y; e1 = (e1 > 0.f) ? e1 : 0.2f * e1;
    m0 = fmaxf(m0, e0); m1 = fmaxf(m1, e1);
  }
#pragma unroll
  for (int off = 32; off > 0; off >>= 1) {
    m0 = fmaxf(m0, __shfl_xor(m0, off, 64));
    m1 = fmaxf(m1, __shfl_xor(m1, off, 64));
  }

  // loop 2: weights, LDS cache, denom
  float den0 = 0.f, den1 = 0.f;
#pragma unroll
  for (int j = 0; j < 2; j++) {
    int i = r0 + lane + 64 * j;
    bool v = act && i < r1;
    float w0 = v ? __expf(e0a[j] - m0) : 0.f;
    float w1 = v ? __expf(e1a[j] - m1) : 0.f;
    sW0[wslot][lane + 64 * j] = w0;
    sW1[wslot][lane + 64 * j] = w1;
    sS[wslot][lane + 64 * j] = sa[j];
    den0 += w0; den1 += w1;
  }
  for (int i = r0 + GCAP + lane; i < r1; i += 64) {
    int s = adj[i];
    float2 asv = as2[s];
    float e0 = asv.x + adv.x; e0 = (e0 > 0.f) ? e0 : 0.2f * e0;
    float e1 = asv.y + adv.y; e1 = (e1 > 0.f) ? e1 : 0.2f * e1;
    den0 += __expf(e0 - m0); den1 += __expf(e1 - m1);
  }
#pragma unroll
  for (int off = 32; off > 0; off >>= 1) {
    den0 += __shfl_xor(den0, off, 64);
    den1 += __shfl_xor(den1, off, 64);
  }
  float inv0 = 1.f / (den0 + 1e-16f), inv1 = 1.f / (den1 + 1e-16f);
  __syncthreads();  // LDS visibility (uniform: all threads reach)

  // pass 3: tight gather-accumulate; lane covers cols 2*lane, 2*lane+1
  float a0 = 0.f, a1 = 0.f;
  const uint* xw32 = (const uint*)xw;
  int cap = deg < GCAP ? deg : GCAP;
#pragma unroll 2
  for (int i = 0; i < cap; i++) {
    int s = sS[wslot][i];
    float w0 = sW0[wslot][i], w1 = sW1[wslot][i];
    uint pv = xw32[((size_t)s << 6) + lane];
    float xlo = __uint_as_float(pv << 16);
    float xhi = __uint_as_float(pv & 0xffff0000u);
    float ws = (lane < 32) ? w0 : w1;
    a0 += ws * xlo; a1 += ws * xhi;
  }
  for (int i = cap; i < deg; i++) {  // overflow tail: recompute weight (uniform)
    int s = adj[r0 + i];
    float2 asv = as2[s];
    float e0 = asv.x + adv.x; e0 = (e0 > 0.f) ? e0 : 0.2f * e0;
    float e1 = asv.y + adv.y; e1 = (e1 > 0.f) ? e1 : 0.2f * e1;
    float w0 = __expf(e0 - m0), w1 = __expf(e1 - m1);
    uint pv = xw32[((size_t)s << 6) + lane];
    float xlo = __uint_as_float(pv << 16);
    float xhi = __uint_as_float(pv & 0xffff0000u);
    float ws = (lane < 32) ? w0 : w1;
    a0 += ws * xlo; a1 += ws * xhi;
  }
  if (act) {
    int c0 = 2 * lane;
    float invs = (lane < 32) ? inv0 : inv1;
    float o0 = a0 * invs + ldf(bias, c0, dt);
    float o1 = a1 * invs + ldf(bias, c0 + 1, dt);
    o0 = o0 > 0.f ? o0 : 0.f;
    o1 = o1 > 0.f ? o1 : 0.f;
    uint pk = (uint)toBF(o0) | ((uint)toBF(o1) << 16);
    ((uint*)out)[(size_t)n * 64 + lane] = pk;
  }
}

// ---------------- parallel mean-pool (unnormalized sums; contiguous batch) ----------------
__global__ __launch_bounds__(256) void pool_kernel(const bf16* __restrict__ h, const int* __restrict__ batch,
                                                   float* __restrict__ pooled, int N) {
  int n0 = blockIdx.x * 128;
  int nEnd = n0 + 128 < N ? n0 + 128 : N;
  int col = threadIdx.x & 127, half = threadIdx.x >> 7;
  float acc = 0.f;
  int cur = -1;
  for (int n = n0 + half; n < nEnd; n += 2) {
    int g = batch[n];
    if (g != cur) {
      if (cur >= 0) atomicAdd(&pooled[(size_t)cur * 128 + col], acc);
      acc = 0.f; cur = g;
    }
    acc += toF(h[(size_t)n * 128 + col]);
  }
  if (cur >= 0) atomicAdd(&pooled[(size_t)cur * 128 + col], acc);
}

// ---------------- head: readout + news + concat + sigmoid ----------------
__global__ __launch_bounds__(128) void head2_kernel(
    const float* __restrict__ pooled, const void* __restrict__ x, const int* __restrict__ batch,
    const void* __restrict__ Wr, const void* __restrict__ br,
    const void* __restrict__ Wn, const void* __restrict__ bn,
    const void* __restrict__ Wc, const void* __restrict__ bc,
    void* __restrict__ out, int N, int IN, const int* __restrict__ dtflag) {
  int dt = dtflag[0];
  int b = blockIdx.x;
  int t = threadIdx.x;
  __shared__ int sr0, sr1;
  if (t == 0) {
    int lo = 0, hi = N;
    while (lo < hi) { int mid = (lo + hi) >> 1; if (batch[mid] < b) lo = mid + 1; else hi = mid; }
    sr0 = lo;
    lo = 0; hi = N;
    int b1 = b + 1;
    while (lo < hi) { int mid = (lo + hi) >> 1; if (batch[mid] < b1) lo = mid + 1; else hi = mid; }
    sr1 = lo;
  }
  __syncthreads();
  int r0 = sr0, r1 = sr1;
  float inv_cnt = 1.f / (float)(r1 - r0);
  __shared__ float pl[128];
  __shared__ float xs[512];
  __shared__ float red[128];
  pl[t] = pooled[(size_t)b * 128 + t] * inv_cnt;
  for (int k = t; k < IN; k += 128) xs[k] = ldf(x, (size_t)r0 * IN + k, dt);
  __syncthreads();
  float gacc = 0.f;
  for (int k = 0; k < 128; k++) gacc += pl[k] * ldf(Wr, (size_t)k * 128 + t, dt);
  gacc += ldf(br, t, dt);
  float g = gacc > 0.f ? gacc : 0.f;
  float nacc = 0.f;
  for (int k = 0; k < IN; k++) nacc += xs[k] * ldf(Wn, (size_t)k * 128 + t, dt);
  nacc += ldf(bn, t, dt);
  float nw = nacc > 0.f ? nacc : 0.f;
  red[t] = g * ldf(Wc, t, dt) + nw * ldf(Wc, 128 + t, dt);
  __syncthreads();
  for (int s = 64; s > 0; s >>= 1) {
    if (t < s) red[t] += red[t + s];
    __syncthreads();
  }
  if (t == 0) {
    float z = red[0] + ldf(bc, 0, dt);
    float r = 1.f / (1.f + __expf(-z));
    if (dt) ((float*)out)[b] = r;
    else ((bf16*)out)[b] = __float2bfloat16(r);
  }
}

extern "C" void kernel_launch(void* const* d_in, const int* in_sizes, int n_in,
                              void* d_out, int out_size, void* d_ws, size_t ws_size,
                              hipStream_t stream) {
  const void* x   = d_in[0];
  const void* W0  = d_in[1];
  const void* aS0 = d_in[2];
  const void* aD0 = d_in[3];
  const void* b0  = d_in[4];
  const void* W1  = d_in[5];
  const void* aS1 = d_in[6];
  const void* aD1 = d_in[7];
  const void* b1  = d_in[8];
  const void* Wn  = d_in[9];
  const void* bn  = d_in[10];
  const void* Wr  = d_in[11];
  const void* br  = d_in[12];
  const void* Wc  = d_in[13];
  const void* bc  = d_in[14];
  const int* ei    = (const int*)d_in[15];
  const int* batch = (const int*)d_in[16];

  const int N = in_sizes[16];
  const int IN = in_sizes[0] / N;
  const int E = in_sizes[15] / 2;
  const int B = out_size;
  const int Etot = E + N;
  const int Kpad0 = (IN + 31) / 32 * 32;   // 320

  // workspace layout
  char* w = (char*)d_ws;
  size_t off = 0;
  auto alloc = [&](size_t bytes) { void* p = w + off; off += (bytes + 255) / 256 * 256; return p; };
  int* flag      = (int*)alloc(256);
  bf16* bufA     = (bf16*)alloc((size_t)N * 128 * 2);     // xw (both layers)
  bf16* bufB     = (bf16*)alloc((size_t)N * 128 * 2);     // h0 then h1
  float2* as2    = (float2*)alloc((size_t)N * 8);
  float2* ad2    = (float2*)alloc((size_t)N * 8);
  int* cnt       = (int*)alloc((size_t)N * 4);
  int* rowstart  = (int*)alloc((size_t)(N + 1) * 4);
  int* cursor    = (int*)alloc((size_t)N * 4);
  int* adj       = (int*)alloc((size_t)Etot * 4);
  int* csum      = (int*)alloc(1024);
  ushort* Wt0    = (ushort*)alloc((size_t)128 * Kpad0 * 2);
  ushort* Wt1    = (ushort*)alloc((size_t)128 * 128 * 2);
  float* pooled  = (float*)alloc((size_t)B * 128 * 4);

  int ndet = in_sizes[0] < 4096 ? in_sizes[0] : 4096;
  detect_dtype<<<1, 256, 0, stream>>>(x, ndet, flag);

  hipMemsetAsync(cnt, 0, sizeof(int) * N, stream);
  hipMemsetAsync(pooled, 0, sizeof(float) * (size_t)B * 128, stream);

  const int tb = 256;
  count_edges<<<(Etot + tb - 1) / tb, tb, 0, stream>>>(ei, N, E, cnt);
  int nb = (N + 1023) / 1024;
  scan_reduce<<<nb, 256, 0, stream>>>(cnt, N, csum);
  scan_top<<<1, 256, 0, stream>>>(csum, nb, rowstart, N);
  scan_down<<<nb, 256, 0, stream>>>(cnt, N, csum, rowstart, cursor);
  scatter_edges<<<(Etot + tb - 1) / tb, tb, 0, stream>>>(ei, N, E, cursor, adj);

  pack_wt<<<128, Kpad0, 0, stream>>>(W0, Wt0, IN, Kpad0, flag);
  pack_wt<<<128, 128, 0, stream>>>(W1, Wt1, 128, 128, flag);

  int ggrid = (N + 127) / 128;
  int wgrid = ((N * 64) + 255) / 256;

  // Layer 0
  mfma_gemm<true><<<ggrid, 256, 0, stream>>>(x, Wt0, bufA, as2, ad2, aS0, aD0, N, IN, Kpad0, flag);
  gat_agg2<<<wgrid, 256, 0, stream>>>(bufA, as2, ad2, rowstart, adj, b0, bufB, N, flag);

  // Layer 1
  mfma_gemm<false><<<ggrid, 256, 0, stream>>>(bufB, Wt1, bufA, as2, ad2, aS1, aD1, N, 128, 128, flag);
  gat_agg2<<<wgrid, 256, 0, stream>>>(bufA, as2, ad2, rowstart, adj, b1, bufB, N, flag);

  // Head
  pool_kernel<<<ggrid, 256, 0, stream>>>(bufB, batch, pooled, N);
  head2_kernel<<<B, 128, 0, stream>>>(pooled, x, batch, Wr, br, Wn, bn, Wc, bc,
                                      (void*)d_out, N, IN, flag);
}

// Round 5
// 443.735 us; speedup vs baseline: 1.7592x; 1.0871x over previous
//
#include <hip/hip_runtime.h>
#include <hip/hip_bf16.h>

typedef __hip_bfloat16 bf16;
typedef __attribute__((ext_vector_type(8))) __bf16 bf16x8;
typedef __attribute__((ext_vector_type(4))) float f32x4;

__device__ __forceinline__ float toF(bf16 v) { return __bfloat162float(v); }

// dual-dtype load: dt=1 -> underlying memory is fp32; dt=0 -> bf16
__device__ __forceinline__ float ldf(const void* p, size_t i, int dt) {
  return dt ? ((const float*)p)[i] : __bfloat162float(((const bf16*)p)[i]);
}
__device__ __forceinline__ ushort toBF(float f) {
  union { bf16 b; ushort u; } cv; cv.b = __float2bfloat16(f); return cv.u;
}

// ---------------- dtype detection ----------------
__global__ void detect_dtype(const void* x, int n, int* flag) {
  __shared__ int s;
  if (threadIdx.x == 0) s = 0;
  __syncthreads();
  const bf16* xb = (const bf16*)x;
  int bad = 0;
  for (int i = threadIdx.x; i < n; i += 256) {
    float v = __bfloat162float(xb[i]);
    if (!(fabsf(v) < 1e6f)) bad = 1;
  }
  if (bad) atomicOr(&s, 1);
  __syncthreads();
  if (threadIdx.x == 0) flag[0] = s;
}

// ---------------- CSR build ----------------
__global__ void count_edges(const int* __restrict__ ei, int N, int E, int* __restrict__ cnt) {
  int e = blockIdx.x * blockDim.x + threadIdx.x;
  int Etot = E + N;
  if (e >= Etot) return;
  int d = (e < E) ? ei[E + e] : (e - E);
  atomicAdd(&cnt[d], 1);
}

__global__ __launch_bounds__(256) void scan_reduce(const int* __restrict__ cnt, int n, int* __restrict__ csum) {
  int base = blockIdx.x * 1024;
  int t = threadIdx.x;
  int s = 0;
#pragma unroll
  for (int j = 0; j < 4; j++) {
    int i = base + t * 4 + j;
    if (i < n) s += cnt[i];
  }
#pragma unroll
  for (int off = 32; off > 0; off >>= 1) s += __shfl_down(s, off, 64);
  __shared__ int ws[4];
  if ((t & 63) == 0) ws[t >> 6] = s;
  __syncthreads();
  if (t == 0) csum[blockIdx.x] = ws[0] + ws[1] + ws[2] + ws[3];
}

__global__ __launch_bounds__(256) void scan_top(int* __restrict__ csum, int nb, int* __restrict__ rowstart, int n) {
  __shared__ int sc[256];
  int t = threadIdx.x;
  int v0 = (t < nb) ? csum[t] : 0;
  sc[t] = v0;
  for (int off = 1; off < 256; off <<= 1) {
    __syncthreads();
    int v = (t >= off) ? sc[t - off] : 0;
    __syncthreads();
    sc[t] += v;
  }
  __syncthreads();
  if (t < nb) csum[t] = sc[t] - v0;  // exclusive
  if (t == 0) rowstart[n] = sc[255]; // total
}

__global__ __launch_bounds__(256) void scan_down(const int* __restrict__ cnt, int n,
                                                 const int* __restrict__ csum,
                                                 int* __restrict__ rowstart, int* __restrict__ cursor) {
  int base = blockIdx.x * 1024;
  int t = threadIdx.x, lane = t & 63, w = t >> 6;
  int v[4];
#pragma unroll
  for (int j = 0; j < 4; j++) {
    int i = base + t * 4 + j;
    v[j] = (i < n) ? cnt[i] : 0;
  }
  int s1 = v[0], s2 = s1 + v[1], s3 = s2 + v[2], s4 = s3 + v[3];
  int x = s4;
#pragma unroll
  for (int off = 1; off < 64; off <<= 1) {
    int y = __shfl_up(x, off, 64);
    if (lane >= off) x += y;
  }
  int texcl = x - s4;
  __shared__ int ws[4];
  if (lane == 63) ws[w] = x;
  __syncthreads();
  int woff = 0;
  for (int i = 0; i < 4; i++) if (i < w) woff += ws[i];
  int b0 = csum[blockIdx.x] + woff + texcl;
  int e0 = b0, e1 = b0 + s1, e2 = b0 + s2, e3 = b0 + s3;
  int i0 = base + t * 4;
  if (i0 + 0 < n) { rowstart[i0 + 0] = e0; cursor[i0 + 0] = e0; }
  if (i0 + 1 < n) { rowstart[i0 + 1] = e1; cursor[i0 + 1] = e1; }
  if (i0 + 2 < n) { rowstart[i0 + 2] = e2; cursor[i0 + 2] = e2; }
  if (i0 + 3 < n) { rowstart[i0 + 3] = e3; cursor[i0 + 3] = e3; }
}

__global__ void scatter_edges(const int* __restrict__ ei, int N, int E,
                              int* __restrict__ cursor, int* __restrict__ adj) {
  int e = blockIdx.x * blockDim.x + threadIdx.x;
  int Etot = E + N;
  if (e >= Etot) return;
  int d, s;
  if (e < E) { s = ei[e]; d = ei[E + e]; } else { s = e - E; d = s; }
  int pos = atomicAdd(&cursor[d], 1);
  adj[pos] = s;
}

// ---------------- weight pre-transpose: Wt[c][k] = W[k][c], bf16 ----------------
__global__ void pack_wt(const void* __restrict__ W, ushort* __restrict__ Wt, int K, int Kpad,
                        const int* __restrict__ dtflag) {
  int dt = dtflag[0];
  int c = blockIdx.x;
  int k = threadIdx.x;
  if (k >= Kpad) return;
  float v = (k < K) ? ldf(W, (size_t)k * 128 + c, dt) : 0.f;
  Wt[(size_t)c * Kpad + k] = toBF(v);
}

// ---------------- MFMA GEMM + fused attention logits ----------------
// C[nrows,128] = A[nrows,K] @ W[K,128]; also as2/ad2 attention logits per node.
// Block tile 64x128, BK=32, 256 threads (4 waves; wave handles 16 rows).
// Register-prefetch pipeline: loads for tile k+1 issued before MFMA phase of tile k,
// consumed (waitcnt) only at the next LDS-store — one latency exposure per tile,
// overlapped with MFMA + barrier of the previous tile.
template <bool DUALA>
__global__ __launch_bounds__(256) void mfma_gemm(const void* __restrict__ A, const ushort* __restrict__ Wt,
                                                 bf16* __restrict__ C,
                                                 float2* __restrict__ as2, float2* __restrict__ ad2,
                                                 const void* __restrict__ aS, const void* __restrict__ aD,
                                                 int nrows, int K, int Kpad,
                                                 const int* __restrict__ dtflag) {
  __shared__ __align__(16) ushort As[64 * 32];
  __shared__ __align__(16) ushort Ws[128 * 32];
  int dtg = dtflag[0];
  int tid = threadIdx.x;
  int wave = tid >> 6, lane = tid & 63;
  int m = lane & 15, q = lane >> 4;
  int row0 = blockIdx.x * 64;

  f32x4 acc[8];
#pragma unroll
  for (int ct = 0; ct < 8; ct++) acc[ct] = (f32x4){0.f, 0.f, 0.f, 0.f};

  // staging registers
  uint stA[4];     // DUALA, bf16 source
  float stAf[8];   // DUALA, fp32 source
  uint4 stA16;     // !DUALA (bf16 buffer, K%32==0, 16B-aligned rows)
  uint4 stW[2];

  auto loadA = [&](int k0) {
    if (DUALA) {
      if (dtg == 0) {
        const unsigned char* Ab = (const unsigned char*)A;
#pragma unroll
        for (int i = 0; i < 4; i++) {
          int e = tid + i * 256;
          int row = e >> 4, kk = (e & 15) * 2;
          int gr = row0 + row, gk = k0 + kk;
          uint pv = 0;
          if (gr < nrows) {
            if (gk + 1 < K) pv = *(const uint*)(Ab + (size_t)gr * ((size_t)K * 2) + (size_t)gk * 2);
            else if (gk < K) pv = *(const ushort*)(Ab + (size_t)gr * ((size_t)K * 2) + (size_t)gk * 2);
          }
          stA[i] = pv;
        }
      } else {
        const float* Af = (const float*)A;
#pragma unroll
        for (int i = 0; i < 8; i++) {
          int e = tid + i * 256;
          int row = e >> 5, kk = e & 31;
          int gr = row0 + row, gk = k0 + kk;
          stAf[i] = (gr < nrows && gk < K) ? Af[(size_t)gr * K + gk] : 0.f;
        }
      }
    } else {
      int row = tid >> 2, kc = (tid & 3) * 8;
      int gr = row0 + row;
      stA16 = (gr < nrows) ? *(const uint4*)((const ushort*)A + (size_t)gr * K + k0 + kc)
                           : (uint4){0u, 0u, 0u, 0u};
    }
  };
  auto loadW = [&](int k0) {
#pragma unroll
    for (int i = 0; i < 2; i++) {
      int e = tid + i * 256;
      int col = e >> 2, kc = (e & 3) * 8;
      stW[i] = *(const uint4*)&Wt[(size_t)col * Kpad + k0 + kc];
    }
  };
  auto storeLDS = [&]() {
    if (DUALA) {
      if (dtg == 0) {
#pragma unroll
        for (int i = 0; i < 4; i++) {
          int e = tid + i * 256;
          int row = e >> 4, kk = (e & 15) * 2;
          *(uint*)&As[row * 32 + kk] = stA[i];
        }
      } else {
#pragma unroll
        for (int i = 0; i < 8; i++) {
          int e = tid + i * 256;
          int row = e >> 5, kk = e & 31;
          As[row * 32 + kk] = toBF(stAf[i]);
        }
      }
    } else {
      int row = tid >> 2, kc = (tid & 3) * 8;
      *(uint4*)&As[row * 32 + kc] = stA16;
    }
#pragma unroll
    for (int i = 0; i < 2; i++) {
      int e = tid + i * 256;
      int col = e >> 2, kc = (e & 3) * 8;
      *(uint4*)&Ws[col * 32 + kc] = stW[i];
    }
  };

  loadA(0);
  loadW(0);
  for (int k0 = 0; k0 < Kpad; k0 += 32) {
    storeLDS();           // waitcnt for the in-flight loads lands here
    __syncthreads();
    int kn = k0 + 32;
    if (kn < Kpad) { loadA(kn); loadW(kn); }  // issue async; consumed next iter
    bf16x8 af = *(const bf16x8*)&As[(wave * 16 + m) * 32 + q * 8];
#pragma unroll
    for (int ct = 0; ct < 8; ct++) {
      bf16x8 bf_ = *(const bf16x8*)&Ws[(ct * 16 + m) * 32 + q * 8];
      acc[ct] = __builtin_amdgcn_mfma_f32_16x16x32_bf16(af, bf_, acc[ct], 0, 0, 0);
    }
    __syncthreads();      // all reads done before next tile's LDS store
  }

  // ---- C writeback ----
#pragma unroll
  for (int ct = 0; ct < 8; ct++) {
#pragma unroll
    for (int r = 0; r < 4; r++) {
      int grow = row0 + wave * 16 + q * 4 + r;
      if (grow < nrows) C[(size_t)grow * 128 + ct * 16 + m] = __float2bfloat16(acc[ct][r]);
    }
  }

  // ---- fused attention logits ----
  float aSv[8], aDv[8];
#pragma unroll
  for (int ct = 0; ct < 8; ct++) {
    aSv[ct] = ldf(aS, ct * 16 + m, dtg);
    aDv[ct] = ldf(aD, ct * 16 + m, dtg);
  }
#pragma unroll
  for (int r = 0; r < 4; r++) {
    float s0 = 0.f, s1 = 0.f, d0 = 0.f, d1 = 0.f;
#pragma unroll
    for (int ct = 0; ct < 4; ct++) {
      float v = acc[ct][r];
      s0 += v * aSv[ct]; d0 += v * aDv[ct];
    }
#pragma unroll
    for (int ct = 4; ct < 8; ct++) {
      float v = acc[ct][r];
      s1 += v * aSv[ct]; d1 += v * aDv[ct];
    }
#pragma unroll
    for (int off = 1; off < 16; off <<= 1) {
      s0 += __shfl_xor(s0, off, 64);
      s1 += __shfl_xor(s1, off, 64);
      d0 += __shfl_xor(d0, off, 64);
      d1 += __shfl_xor(d1, off, 64);
    }
    int grow = row0 + wave * 16 + q * 4 + r;
    if (m == 0 && grow < nrows) {
      as2[grow] = make_float2(s0, s1);
      ad2[grow] = make_float2(d0, d1);
    }
  }
}

// ---------------- GAT aggregate v2: one wave per dst, LDS-cached softmax weights -------
#define GCAP 128
__global__ __launch_bounds__(256) void gat_agg2(const bf16* __restrict__ xw,
                                                const float2* __restrict__ as2, const float2* __restrict__ ad2,
                                                const int* __restrict__ rowstart, const int* __restrict__ adj,
                                                const void* __restrict__ bias, bf16* __restrict__ out, int N,
                                                const int* __restrict__ dtflag) {
  __shared__ float sW0[4][GCAP];
  __shared__ float sW1[4][GCAP];
  __shared__ int sS[4][GCAP];
  int dt = dtflag[0];
  int wslot = threadIdx.x >> 6;
  int lane = threadIdx.x & 63;
  int n = (blockIdx.x * blockDim.x + threadIdx.x) >> 6;
  bool act = n < N;
  int r0 = 0, r1 = 0;
  float2 adv = make_float2(0.f, 0.f);
  if (act) { r0 = rowstart[n]; r1 = rowstart[n + 1]; adv = ad2[n]; }
  int deg = r1 - r0;

  float e0a[2], e1a[2];
  int sa[2];
  float m0 = -1e30f, m1 = -1e30f;
#pragma unroll
  for (int j = 0; j < 2; j++) {
    int i = r0 + lane + 64 * j;
    bool v = act && i < r1;
    int s = v ? adj[i] : 0;
    sa[j] = s;
    float e0 = -1e30f, e1 = -1e30f;
    if (v) {
      float2 asv = as2[s];
      e0 = asv.x + adv.x; e0 = (e0 > 0.f) ? e0 : 0.2f * e0;
      e1 = asv.y + adv.y; e1 = (e1 > 0.f) ? e1 : 0.2f * e1;
    }
    e0a[j] = e0; e1a[j] = e1;
    m0 = fmaxf(m0, e0); m1 = fmaxf(m1, e1);
  }
  for (int i = r0 + GCAP + lane; i < r1; i += 64) {
    int s = adj[i];
    float2 asv = as2[s];
    float e0 = asv.x + adv.x; e0 = (e0 > 0.f) ? e0 : 0.2f * e0;
    float e1 = asv.y + adv.y; e1 = (e1 > 0.f) ? e1 : 0.2f * e1;
    m0 = fmaxf(m0, e0); m1 = fmaxf(m1, e1);
  }
#pragma unroll
  for (int off = 32; off > 0; off >>= 1) {
    m0 = fmaxf(m0, __shfl_xor(m0, off, 64));
    m1 = fmaxf(m1, __shfl_xor(m1, off, 64));
  }

  float den0 = 0.f, den1 = 0.f;
#pragma unroll
  for (int j = 0; j < 2; j++) {
    int i = r0 + lane + 64 * j;
    bool v = act && i < r1;
    float w0 = v ? __expf(e0a[j] - m0) : 0.f;
    float w1 = v ? __expf(e1a[j] - m1) : 0.f;
    sW0[wslot][lane + 64 * j] = w0;
    sW1[wslot][lane + 64 * j] = w1;
    sS[wslot][lane + 64 * j] = sa[j];
    den0 += w0; den1 += w1;
  }
  for (int i = r0 + GCAP + lane; i < r1; i += 64) {
    int s = adj[i];
    float2 asv = as2[s];
    float e0 = asv.x + adv.x; e0 = (e0 > 0.f) ? e0 : 0.2f * e0;
    float e1 = asv.y + adv.y; e1 = (e1 > 0.f) ? e1 : 0.2f * e1;
    den0 += __expf(e0 - m0); den1 += __expf(e1 - m1);
  }
#pragma unroll
  for (int off = 32; off > 0; off >>= 1) {
    den0 += __shfl_xor(den0, off, 64);
    den1 += __shfl_xor(den1, off, 64);
  }
  float inv0 = 1.f / (den0 + 1e-16f), inv1 = 1.f / (den1 + 1e-16f);
  __syncthreads();

  float a0 = 0.f, a1 = 0.f;
  const uint* xw32 = (const uint*)xw;
  int cap = deg < GCAP ? deg : GCAP;
#pragma unroll 2
  for (int i = 0; i < cap; i++) {
    int s = sS[wslot][i];
    float w0 = sW0[wslot][i], w1 = sW1[wslot][i];
    uint pv = xw32[((size_t)s << 6) + lane];
    float xlo = __uint_as_float(pv << 16);
    float xhi = __uint_as_float(pv & 0xffff0000u);
    float ws = (lane < 32) ? w0 : w1;
    a0 += ws * xlo; a1 += ws * xhi;
  }
  for (int i = cap; i < deg; i++) {
    int s = adj[r0 + i];
    float2 asv = as2[s];
    float e0 = asv.x + adv.x; e0 = (e0 > 0.f) ? e0 : 0.2f * e0;
    float e1 = asv.y + adv.y; e1 = (e1 > 0.f) ? e1 : 0.2f * e1;
    float w0 = __expf(e0 - m0), w1 = __expf(e1 - m1);
    uint pv = xw32[((size_t)s << 6) + lane];
    float xlo = __uint_as_float(pv << 16);
    float xhi = __uint_as_float(pv & 0xffff0000u);
    float ws = (lane < 32) ? w0 : w1;
    a0 += ws * xlo; a1 += ws * xhi;
  }
  if (act) {
    int c0 = 2 * lane;
    float invs = (lane < 32) ? inv0 : inv1;
    float o0 = a0 * invs + ldf(bias, c0, dt);
    float o1 = a1 * invs + ldf(bias, c0 + 1, dt);
    o0 = o0 > 0.f ? o0 : 0.f;
    o1 = o1 > 0.f ? o1 : 0.f;
    uint pk = (uint)toBF(o0) | ((uint)toBF(o1) << 16);
    ((uint*)out)[(size_t)n * 64 + lane] = pk;
  }
}

// ---------------- parallel mean-pool (unnormalized sums; contiguous batch) ----------------
__global__ __launch_bounds__(256) void pool_kernel(const bf16* __restrict__ h, const int* __restrict__ batch,
                                                   float* __restrict__ pooled, int N) {
  int n0 = blockIdx.x * 128;
  int nEnd = n0 + 128 < N ? n0 + 128 : N;
  int col = threadIdx.x & 127, half = threadIdx.x >> 7;
  float acc = 0.f;
  int cur = -1;
  for (int n = n0 + half; n < nEnd; n += 2) {
    int g = batch[n];
    if (g != cur) {
      if (cur >= 0) atomicAdd(&pooled[(size_t)cur * 128 + col], acc);
      acc = 0.f; cur = g;
    }
    acc += toF(h[(size_t)n * 128 + col]);
  }
  if (cur >= 0) atomicAdd(&pooled[(size_t)cur * 128 + col], acc);
}

// ---------------- head: readout + news + concat + sigmoid ----------------
__global__ __launch_bounds__(128) void head2_kernel(
    const float* __restrict__ pooled, const void* __restrict__ x, const int* __restrict__ batch,
    const void* __restrict__ Wr, const void* __restrict__ br,
    const void* __restrict__ Wn, const void* __restrict__ bn,
    const void* __restrict__ Wc, const void* __restrict__ bc,
    void* __restrict__ out, int N, int IN, const int* __restrict__ dtflag) {
  int dt = dtflag[0];
  int b = blockIdx.x;
  int t = threadIdx.x;
  __shared__ int sr0, sr1;
  if (t == 0) {
    int lo = 0, hi = N;
    while (lo < hi) { int mid = (lo + hi) >> 1; if (batch[mid] < b) lo = mid + 1; else hi = mid; }
    sr0 = lo;
    lo = 0; hi = N;
    int b1 = b + 1;
    while (lo < hi) { int mid = (lo + hi) >> 1; if (batch[mid] < b1) lo = mid + 1; else hi = mid; }
    sr1 = lo;
  }
  __syncthreads();
  int r0 = sr0, r1 = sr1;
  float inv_cnt = 1.f / (float)(r1 - r0);
  __shared__ float pl[128];
  __shared__ float xs[512];
  __shared__ float red[128];
  pl[t] = pooled[(size_t)b * 128 + t] * inv_cnt;
  for (int k = t; k < IN; k += 128) xs[k] = ldf(x, (size_t)r0 * IN + k, dt);
  __syncthreads();
  float gacc = 0.f;
  for (int k = 0; k < 128; k++) gacc += pl[k] * ldf(Wr, (size_t)k * 128 + t, dt);
  gacc += ldf(br, t, dt);
  float g = gacc > 0.f ? gacc : 0.f;
  float nacc = 0.f;
  for (int k = 0; k < IN; k++) nacc += xs[k] * ldf(Wn, (size_t)k * 128 + t, dt);
  nacc += ldf(bn, t, dt);
  float nw = nacc > 0.f ? nacc : 0.f;
  red[t] = g * ldf(Wc, t, dt) + nw * ldf(Wc, 128 + t, dt);
  __syncthreads();
  for (int s = 64; s > 0; s >>= 1) {
    if (t < s) red[t] += red[t + s];
    __syncthreads();
  }
  if (t == 0) {
    float z = red[0] + ldf(bc, 0, dt);
    float r = 1.f / (1.f + __expf(-z));
    if (dt) ((float*)out)[b] = r;
    else ((bf16*)out)[b] = __float2bfloat16(r);
  }
}

extern "C" void kernel_launch(void* const* d_in, const int* in_sizes, int n_in,
                              void* d_out, int out_size, void* d_ws, size_t ws_size,
                              hipStream_t stream) {
  const void* x   = d_in[0];
  const void* W0  = d_in[1];
  const void* aS0 = d_in[2];
  const void* aD0 = d_in[3];
  const void* b0  = d_in[4];
  const void* W1  = d_in[5];
  const void* aS1 = d_in[6];
  const void* aD1 = d_in[7];
  const void* b1  = d_in[8];
  const void* Wn  = d_in[9];
  const void* bn  = d_in[10];
  const void* Wr  = d_in[11];
  const void* br  = d_in[12];
  const void* Wc  = d_in[13];
  const void* bc  = d_in[14];
  const int* ei    = (const int*)d_in[15];
  const int* batch = (const int*)d_in[16];

  const int N = in_sizes[16];
  const int IN = in_sizes[0] / N;
  const int E = in_sizes[15] / 2;
  const int B = out_size;
  const int Etot = E + N;
  const int Kpad0 = (IN + 31) / 32 * 32;   // 320

  // workspace layout
  char* w = (char*)d_ws;
  size_t off = 0;
  auto alloc = [&](size_t bytes) { void* p = w + off; off += (bytes + 255) / 256 * 256; return p; };
  int* flag      = (int*)alloc(256);
  bf16* bufA     = (bf16*)alloc((size_t)N * 128 * 2);     // xw (both layers)
  bf16* bufB     = (bf16*)alloc((size_t)N * 128 * 2);     // h0 then h1
  float2* as2    = (float2*)alloc((size_t)N * 8);
  float2* ad2    = (float2*)alloc((size_t)N * 8);
  int* cnt       = (int*)alloc((size_t)N * 4);
  int* rowstart  = (int*)alloc((size_t)(N + 1) * 4);
  int* cursor    = (int*)alloc((size_t)N * 4);
  int* adj       = (int*)alloc((size_t)Etot * 4);
  int* csum      = (int*)alloc(1024);
  ushort* Wt0    = (ushort*)alloc((size_t)128 * Kpad0 * 2);
  ushort* Wt1    = (ushort*)alloc((size_t)128 * 128 * 2);
  float* pooled  = (float*)alloc((size_t)B * 128 * 4);

  int ndet = in_sizes[0] < 4096 ? in_sizes[0] : 4096;
  detect_dtype<<<1, 256, 0, stream>>>(x, ndet, flag);

  hipMemsetAsync(cnt, 0, sizeof(int) * N, stream);
  hipMemsetAsync(pooled, 0, sizeof(float) * (size_t)B * 128, stream);

  const int tb = 256;
  count_edges<<<(Etot + tb - 1) / tb, tb, 0, stream>>>(ei, N, E, cnt);
  int nb = (N + 1023) / 1024;
  scan_reduce<<<nb, 256, 0, stream>>>(cnt, N, csum);
  scan_top<<<1, 256, 0, stream>>>(csum, nb, rowstart, N);
  scan_down<<<nb, 256, 0, stream>>>(cnt, N, csum, rowstart, cursor);
  scatter_edges<<<(Etot + tb - 1) / tb, tb, 0, stream>>>(ei, N, E, cursor, adj);

  pack_wt<<<128, Kpad0, 0, stream>>>(W0, Wt0, IN, Kpad0, flag);
  pack_wt<<<128, 128, 0, stream>>>(W1, Wt1, 128, 128, flag);

  int ggrid = (N + 63) / 64;       // mfma_gemm: 64-row tiles
  int pgrid = (N + 127) / 128;     // pool: 128-node chunks
  int wgrid = ((N * 64) + 255) / 256;

  // Layer 0
  mfma_gemm<true><<<ggrid, 256, 0, stream>>>(x, Wt0, bufA, as2, ad2, aS0, aD0, N, IN, Kpad0, flag);
  gat_agg2<<<wgrid, 256, 0, stream>>>(bufA, as2, ad2, rowstart, adj, b0, bufB, N, flag);

  // Layer 1
  mfma_gemm<false><<<ggrid, 256, 0, stream>>>(bufB, Wt1, bufA, as2, ad2, aS1, aD1, N, 128, 128, flag);
  gat_agg2<<<wgrid, 256, 0, stream>>>(bufA, as2, ad2, rowstart, adj, b1, bufB, N, flag);

  // Head
  pool_kernel<<<pgrid, 256, 0, stream>>>(bufB, batch, pooled, N);
  head2_kernel<<<B, 128, 0, stream>>>(pooled, x, batch, Wr, br, Wn, bn, Wc, bc,
                                      (void*)d_out, N, IN, flag);
}

// Round 6
// 439.788 us; speedup vs baseline: 1.7750x; 1.0090x over previous
//
#include <hip/hip_runtime.h>
#include <hip/hip_bf16.h>

typedef __hip_bfloat16 bf16;
typedef __attribute__((ext_vector_type(8))) __bf16 bf16x8;
typedef __attribute__((ext_vector_type(4))) float f32x4;

__device__ __forceinline__ float toF(bf16 v) { return __bfloat162float(v); }

// dual-dtype load: dt=1 -> underlying memory is fp32; dt=0 -> bf16
__device__ __forceinline__ float ldf(const void* p, size_t i, int dt) {
  return dt ? ((const float*)p)[i] : __bfloat162float(((const bf16*)p)[i]);
}
__device__ __forceinline__ ushort toBF(float f) {
  union { bf16 b; ushort u; } cv; cv.b = __float2bfloat16(f); return cv.u;
}

// ---------------- dtype detection ----------------
__global__ void detect_dtype(const void* x, int n, int* flag) {
  __shared__ int s;
  if (threadIdx.x == 0) s = 0;
  __syncthreads();
  const bf16* xb = (const bf16*)x;
  int bad = 0;
  for (int i = threadIdx.x; i < n; i += 256) {
    float v = __bfloat162float(xb[i]);
    if (!(fabsf(v) < 1e6f)) bad = 1;
  }
  if (bad) atomicOr(&s, 1);
  __syncthreads();
  if (threadIdx.x == 0) flag[0] = s;
}

// ---------------- CSR build ----------------
__global__ void count_edges(const int* __restrict__ ei, int N, int E, int* __restrict__ cnt) {
  int e = blockIdx.x * blockDim.x + threadIdx.x;
  int Etot = E + N;
  if (e >= Etot) return;
  int d = (e < E) ? ei[E + e] : (e - E);
  atomicAdd(&cnt[d], 1);
}

__global__ __launch_bounds__(256) void scan_reduce(const int* __restrict__ cnt, int n, int* __restrict__ csum) {
  int base = blockIdx.x * 1024;
  int t = threadIdx.x;
  int s = 0;
#pragma unroll
  for (int j = 0; j < 4; j++) {
    int i = base + t * 4 + j;
    if (i < n) s += cnt[i];
  }
#pragma unroll
  for (int off = 32; off > 0; off >>= 1) s += __shfl_down(s, off, 64);
  __shared__ int ws[4];
  if ((t & 63) == 0) ws[t >> 6] = s;
  __syncthreads();
  if (t == 0) csum[blockIdx.x] = ws[0] + ws[1] + ws[2] + ws[3];
}

__global__ __launch_bounds__(256) void scan_top(int* __restrict__ csum, int nb, int* __restrict__ rowstart, int n) {
  __shared__ int sc[256];
  int t = threadIdx.x;
  int v0 = (t < nb) ? csum[t] : 0;
  sc[t] = v0;
  for (int off = 1; off < 256; off <<= 1) {
    __syncthreads();
    int v = (t >= off) ? sc[t - off] : 0;
    __syncthreads();
    sc[t] += v;
  }
  __syncthreads();
  if (t < nb) csum[t] = sc[t] - v0;  // exclusive
  if (t == 0) rowstart[n] = sc[255]; // total
}

__global__ __launch_bounds__(256) void scan_down(const int* __restrict__ cnt, int n,
                                                 const int* __restrict__ csum,
                                                 int* __restrict__ rowstart, int* __restrict__ cursor) {
  int base = blockIdx.x * 1024;
  int t = threadIdx.x, lane = t & 63, w = t >> 6;
  int v[4];
#pragma unroll
  for (int j = 0; j < 4; j++) {
    int i = base + t * 4 + j;
    v[j] = (i < n) ? cnt[i] : 0;
  }
  int s1 = v[0], s2 = s1 + v[1], s3 = s2 + v[2], s4 = s3 + v[3];
  int x = s4;
#pragma unroll
  for (int off = 1; off < 64; off <<= 1) {
    int y = __shfl_up(x, off, 64);
    if (lane >= off) x += y;
  }
  int texcl = x - s4;
  __shared__ int ws[4];
  if (lane == 63) ws[w] = x;
  __syncthreads();
  int woff = 0;
  for (int i = 0; i < 4; i++) if (i < w) woff += ws[i];
  int b0 = csum[blockIdx.x] + woff + texcl;
  int e0 = b0, e1 = b0 + s1, e2 = b0 + s2, e3 = b0 + s3;
  int i0 = base + t * 4;
  if (i0 + 0 < n) { rowstart[i0 + 0] = e0; cursor[i0 + 0] = e0; }
  if (i0 + 1 < n) { rowstart[i0 + 1] = e1; cursor[i0 + 1] = e1; }
  if (i0 + 2 < n) { rowstart[i0 + 2] = e2; cursor[i0 + 2] = e2; }
  if (i0 + 3 < n) { rowstart[i0 + 3] = e3; cursor[i0 + 3] = e3; }
}

__global__ void scatter_edges(const int* __restrict__ ei, int N, int E,
                              int* __restrict__ cursor, int* __restrict__ adj) {
  int e = blockIdx.x * blockDim.x + threadIdx.x;
  int Etot = E + N;
  if (e >= Etot) return;
  int d, s;
  if (e < E) { s = ei[e]; d = ei[E + e]; } else { s = e - E; d = s; }
  int pos = atomicAdd(&cursor[d], 1);
  adj[pos] = s;
}

// ---------------- weight pre-transpose: Wt[c][k] = W[k][c], bf16 ----------------
__global__ void pack_wt(const void* __restrict__ W, ushort* __restrict__ Wt, int K, int Kpad,
                        const int* __restrict__ dtflag) {
  int dt = dtflag[0];
  int c = blockIdx.x;
  int k = threadIdx.x;
  if (k >= Kpad) return;
  float v = (k < K) ? ldf(W, (size_t)k * 128 + c, dt) : 0.f;
  Wt[(size_t)c * Kpad + k] = toBF(v);
}

// ---------------- MFMA GEMM + fused attention logits ----------------
// C[nrows,128] = A[nrows,K] @ W[K,128]; also as2/ad2 attention logits per node.
// Block tile 64x128, BK=32, 256 threads (4 waves; wave handles 16 rows).
template <bool DUALA>
__global__ __launch_bounds__(256) void mfma_gemm(const void* __restrict__ A, const ushort* __restrict__ Wt,
                                                 bf16* __restrict__ C,
                                                 float2* __restrict__ as2, float2* __restrict__ ad2,
                                                 const void* __restrict__ aS, const void* __restrict__ aD,
                                                 int nrows, int K, int Kpad,
                                                 const int* __restrict__ dtflag) {
  __shared__ __align__(16) ushort As[64 * 32];
  __shared__ __align__(16) ushort Ws[128 * 32];
  int dtg = dtflag[0];
  int tid = threadIdx.x;
  int wave = tid >> 6, lane = tid & 63;
  int m = lane & 15, q = lane >> 4;
  int row0 = blockIdx.x * 64;

  f32x4 acc[8];
#pragma unroll
  for (int ct = 0; ct < 8; ct++) acc[ct] = (f32x4){0.f, 0.f, 0.f, 0.f};

  uint stA[4];
  float stAf[8];
  uint4 stA16;
  uint4 stW[2];

  auto loadA = [&](int k0) {
    if (DUALA) {
      if (dtg == 0) {
        const unsigned char* Ab = (const unsigned char*)A;
#pragma unroll
        for (int i = 0; i < 4; i++) {
          int e = tid + i * 256;
          int row = e >> 4, kk = (e & 15) * 2;
          int gr = row0 + row, gk = k0 + kk;
          uint pv = 0;
          if (gr < nrows) {
            if (gk + 1 < K) pv = *(const uint*)(Ab + (size_t)gr * ((size_t)K * 2) + (size_t)gk * 2);
            else if (gk < K) pv = *(const ushort*)(Ab + (size_t)gr * ((size_t)K * 2) + (size_t)gk * 2);
          }
          stA[i] = pv;
        }
      } else {
        const float* Af = (const float*)A;
#pragma unroll
        for (int i = 0; i < 8; i++) {
          int e = tid + i * 256;
          int row = e >> 5, kk = e & 31;
          int gr = row0 + row, gk = k0 + kk;
          stAf[i] = (gr < nrows && gk < K) ? Af[(size_t)gr * K + gk] : 0.f;
        }
      }
    } else {
      int row = tid >> 2, kc = (tid & 3) * 8;
      int gr = row0 + row;
      stA16 = (gr < nrows) ? *(const uint4*)((const ushort*)A + (size_t)gr * K + k0 + kc)
                           : (uint4){0u, 0u, 0u, 0u};
    }
  };
  auto loadW = [&](int k0) {
#pragma unroll
    for (int i = 0; i < 2; i++) {
      int e = tid + i * 256;
      int col = e >> 2, kc = (e & 3) * 8;
      stW[i] = *(const uint4*)&Wt[(size_t)col * Kpad + k0 + kc];
    }
  };
  auto storeLDS = [&]() {
    if (DUALA) {
      if (dtg == 0) {
#pragma unroll
        for (int i = 0; i < 4; i++) {
          int e = tid + i * 256;
          int row = e >> 4, kk = (e & 15) * 2;
          *(uint*)&As[row * 32 + kk] = stA[i];
        }
      } else {
#pragma unroll
        for (int i = 0; i < 8; i++) {
          int e = tid + i * 256;
          int row = e >> 5, kk = e & 31;
          As[row * 32 + kk] = toBF(stAf[i]);
        }
      }
    } else {
      int row = tid >> 2, kc = (tid & 3) * 8;
      *(uint4*)&As[row * 32 + kc] = stA16;
    }
#pragma unroll
    for (int i = 0; i < 2; i++) {
      int e = tid + i * 256;
      int col = e >> 2, kc = (e & 3) * 8;
      *(uint4*)&Ws[col * 32 + kc] = stW[i];
    }
  };

  loadA(0);
  loadW(0);
  for (int k0 = 0; k0 < Kpad; k0 += 32) {
    storeLDS();
    __syncthreads();
    int kn = k0 + 32;
    if (kn < Kpad) { loadA(kn); loadW(kn); }
    bf16x8 af = *(const bf16x8*)&As[(wave * 16 + m) * 32 + q * 8];
#pragma unroll
    for (int ct = 0; ct < 8; ct++) {
      bf16x8 bf_ = *(const bf16x8*)&Ws[(ct * 16 + m) * 32 + q * 8];
      acc[ct] = __builtin_amdgcn_mfma_f32_16x16x32_bf16(af, bf_, acc[ct], 0, 0, 0);
    }
    __syncthreads();
  }

#pragma unroll
  for (int ct = 0; ct < 8; ct++) {
#pragma unroll
    for (int r = 0; r < 4; r++) {
      int grow = row0 + wave * 16 + q * 4 + r;
      if (grow < nrows) C[(size_t)grow * 128 + ct * 16 + m] = __float2bfloat16(acc[ct][r]);
    }
  }

  float aSv[8], aDv[8];
#pragma unroll
  for (int ct = 0; ct < 8; ct++) {
    aSv[ct] = ldf(aS, ct * 16 + m, dtg);
    aDv[ct] = ldf(aD, ct * 16 + m, dtg);
  }
#pragma unroll
  for (int r = 0; r < 4; r++) {
    float s0 = 0.f, s1 = 0.f, d0 = 0.f, d1 = 0.f;
#pragma unroll
    for (int ct = 0; ct < 4; ct++) {
      float v = acc[ct][r];
      s0 += v * aSv[ct]; d0 += v * aDv[ct];
    }
#pragma unroll
    for (int ct = 4; ct < 8; ct++) {
      float v = acc[ct][r];
      s1 += v * aSv[ct]; d1 += v * aDv[ct];
    }
#pragma unroll
    for (int off = 1; off < 16; off <<= 1) {
      s0 += __shfl_xor(s0, off, 64);
      s1 += __shfl_xor(s1, off, 64);
      d0 += __shfl_xor(d0, off, 64);
      d1 += __shfl_xor(d1, off, 64);
    }
    int grow = row0 + wave * 16 + q * 4 + r;
    if (m == 0 && grow < nrows) {
      as2[grow] = make_float2(s0, s1);
      ad2[grow] = make_float2(d0, d1);
    }
  }
}

// ---------------- GAT aggregate v2: one wave per dst, LDS-cached softmax weights -------
#define GCAP 128
__global__ __launch_bounds__(256) void gat_agg2(const bf16* __restrict__ xw,
                                                const float2* __restrict__ as2, const float2* __restrict__ ad2,
                                                const int* __restrict__ rowstart, const int* __restrict__ adj,
                                                const void* __restrict__ bias, bf16* __restrict__ out, int N,
                                                const int* __restrict__ dtflag) {
  __shared__ float sW0[4][GCAP];
  __shared__ float sW1[4][GCAP];
  __shared__ int sS[4][GCAP];
  int dt = dtflag[0];
  int wslot = threadIdx.x >> 6;
  int lane = threadIdx.x & 63;
  int n = (blockIdx.x * blockDim.x + threadIdx.x) >> 6;
  bool act = n < N;
  int r0 = 0, r1 = 0;
  float2 adv = make_float2(0.f, 0.f);
  if (act) { r0 = rowstart[n]; r1 = rowstart[n + 1]; adv = ad2[n]; }
  int deg = r1 - r0;

  float e0a[2], e1a[2];
  int sa[2];
  float m0 = -1e30f, m1 = -1e30f;
#pragma unroll
  for (int j = 0; j < 2; j++) {
    int i = r0 + lane + 64 * j;
    bool v = act && i < r1;
    int s = v ? adj[i] : 0;
    sa[j] = s;
    float e0 = -1e30f, e1 = -1e30f;
    if (v) {
      float2 asv = as2[s];
      e0 = asv.x + adv.x; e0 = (e0 > 0.f) ? e0 : 0.2f * e0;
      e1 = asv.y + adv.y; e1 = (e1 > 0.f) ? e1 : 0.2f * e1;
    }
    e0a[j] = e0; e1a[j] = e1;
    m0 = fmaxf(m0, e0); m1 = fmaxf(m1, e1);
  }
  for (int i = r0 + GCAP + lane; i < r1; i += 64) {
    int s = adj[i];
    float2 asv = as2[s];
    float e0 = asv.x + adv.x; e0 = (e0 > 0.f) ? e0 : 0.2f * e0;
    float e1 = asv.y + adv.y; e1 = (e1 > 0.f) ? e1 : 0.2f * e1;
    m0 = fmaxf(m0, e0); m1 = fmaxf(m1, e1);
  }
#pragma unroll
  for (int off = 32; off > 0; off >>= 1) {
    m0 = fmaxf(m0, __shfl_xor(m0, off, 64));
    m1 = fmaxf(m1, __shfl_xor(m1, off, 64));
  }

  float den0 = 0.f, den1 = 0.f;
#pragma unroll
  for (int j = 0; j < 2; j++) {
    int i = r0 + lane + 64 * j;
    bool v = act && i < r1;
    float w0 = v ? __expf(e0a[j] - m0) : 0.f;
    float w1 = v ? __expf(e1a[j] - m1) : 0.f;
    sW0[wslot][lane + 64 * j] = w0;
    sW1[wslot][lane + 64 * j] = w1;
    sS[wslot][lane + 64 * j] = sa[j];
    den0 += w0; den1 += w1;
  }
  for (int i = r0 + GCAP + lane; i < r1; i += 64) {
    int s = adj[i];
    float2 asv = as2[s];
    float e0 = asv.x + adv.x; e0 = (e0 > 0.f) ? e0 : 0.2f * e0;
    float e1 = asv.y + adv.y; e1 = (e1 > 0.f) ? e1 : 0.2f * e1;
    den0 += __expf(e0 - m0); den1 += __expf(e1 - m1);
  }
#pragma unroll
  for (int off = 32; off > 0; off >>= 1) {
    den0 += __shfl_xor(den0, off, 64);
    den1 += __shfl_xor(den1, off, 64);
  }
  float inv0 = 1.f / (den0 + 1e-16f), inv1 = 1.f / (den1 + 1e-16f);
  __syncthreads();

  float a0 = 0.f, a1 = 0.f;
  const uint* xw32 = (const uint*)xw;
  int cap = deg < GCAP ? deg : GCAP;
#pragma unroll 2
  for (int i = 0; i < cap; i++) {
    int s = sS[wslot][i];
    float w0 = sW0[wslot][i], w1 = sW1[wslot][i];
    uint pv = xw32[((size_t)s << 6) + lane];
    float xlo = __uint_as_float(pv << 16);
    float xhi = __uint_as_float(pv & 0xffff0000u);
    float ws = (lane < 32) ? w0 : w1;
    a0 += ws * xlo; a1 += ws * xhi;
  }
  for (int i = cap; i < deg; i++) {
    int s = adj[r0 + i];
    float2 asv = as2[s];
    float e0 = asv.x + adv.x; e0 = (e0 > 0.f) ? e0 : 0.2f * e0;
    float e1 = asv.y + adv.y; e1 = (e1 > 0.f) ? e1 : 0.2f * e1;
    float w0 = __expf(e0 - m0), w1 = __expf(e1 - m1);
    uint pv = xw32[((size_t)s << 6) + lane];
    float xlo = __uint_as_float(pv << 16);
    float xhi = __uint_as_float(pv & 0xffff0000u);
    float ws = (lane < 32) ? w0 : w1;
    a0 += ws * xlo; a1 += ws * xhi;
  }
  if (act) {
    int c0 = 2 * lane;
    float invs = (lane < 32) ? inv0 : inv1;
    float o0 = a0 * invs + ldf(bias, c0, dt);
    float o1 = a1 * invs + ldf(bias, c0 + 1, dt);
    o0 = o0 > 0.f ? o0 : 0.f;
    o1 = o1 > 0.f ? o1 : 0.f;
    uint pk = (uint)toBF(o0) | ((uint)toBF(o1) << 16);
    ((uint*)out)[(size_t)n * 64 + lane] = pk;
  }
}

// ---------------- parallel mean-pool (unnormalized sums; contiguous batch) ----------------
__global__ __launch_bounds__(256) void pool_kernel(const bf16* __restrict__ h, const int* __restrict__ batch,
                                                   float* __restrict__ pooled, int N) {
  int n0 = blockIdx.x * 128;
  int nEnd = n0 + 128 < N ? n0 + 128 : N;
  int col = threadIdx.x & 127, half = threadIdx.x >> 7;
  float acc = 0.f;
  int cur = -1;
  for (int n = n0 + half; n < nEnd; n += 2) {
    int g = batch[n];
    if (g != cur) {
      if (cur >= 0) atomicAdd(&pooled[(size_t)cur * 128 + col], acc);
      acc = 0.f; cur = g;
    }
    acc += toF(h[(size_t)n * 128 + col]);
  }
  if (cur >= 0) atomicAdd(&pooled[(size_t)cur * 128 + col], acc);
}

// ---------------- head v3: 512 threads, 4-way k-split, ILP accumulators ----------------
__global__ __launch_bounds__(512) void head3_kernel(
    const float* __restrict__ pooled, const void* __restrict__ x, const int* __restrict__ batch,
    const void* __restrict__ Wr, const void* __restrict__ br,
    const void* __restrict__ Wn, const void* __restrict__ bn,
    const void* __restrict__ Wc, const void* __restrict__ bc,
    void* __restrict__ out, int N, int IN, const int* __restrict__ dtflag) {
  int dt = dtflag[0];
  int b = blockIdx.x;
  int tid = threadIdx.x;
  int t = tid & 127, g = tid >> 7;  // g in 0..3
  __shared__ int sr0, sr1;
  __shared__ float xs[512];
  __shared__ float pl[128];
  __shared__ float pn[4][128];
  __shared__ float pg[4][128];
  __shared__ float red[128];
  if (tid == 0) {
    int lo = 0, hi = N;
    while (lo < hi) { int mid = (lo + hi) >> 1; if (batch[mid] < b) lo = mid + 1; else hi = mid; }
    sr0 = lo;
  }
  if (tid == 1) {
    int lo = 0, hi = N, b1 = b + 1;
    while (lo < hi) { int mid = (lo + hi) >> 1; if (batch[mid] < b1) lo = mid + 1; else hi = mid; }
    sr1 = lo;
  }
  __syncthreads();
  int r0 = sr0;
  float inv_cnt = 1.f / (float)(sr1 - r0);
  if (tid < 128) pl[tid] = pooled[(size_t)b * 128 + tid] * inv_cnt;
  for (int k = tid; k < IN; k += 512) xs[k] = ldf(x, (size_t)r0 * IN + k, dt);
  __syncthreads();

  // news matvec: k ≡ g (mod 4), 4 independent accumulators for ILP
  float n0 = 0.f, n1 = 0.f, n2 = 0.f, n3 = 0.f;
  {
    int k = g;
    for (; k + 12 < IN; k += 16) {
      n0 += xs[k]      * ldf(Wn, (size_t)k * 128 + t, dt);
      n1 += xs[k + 4]  * ldf(Wn, (size_t)(k + 4) * 128 + t, dt);
      n2 += xs[k + 8]  * ldf(Wn, (size_t)(k + 8) * 128 + t, dt);
      n3 += xs[k + 12] * ldf(Wn, (size_t)(k + 12) * 128 + t, dt);
    }
    for (; k < IN; k += 4) n0 += xs[k] * ldf(Wn, (size_t)k * 128 + t, dt);
  }
  // readout matvec: 128 k's, 2 accumulators
  float g0 = 0.f, g1 = 0.f;
  {
    int k = g;
    for (; k + 4 < 128; k += 8) {
      g0 += pl[k]     * ldf(Wr, (size_t)k * 128 + t, dt);
      g1 += pl[k + 4] * ldf(Wr, (size_t)(k + 4) * 128 + t, dt);
    }
    for (; k < 128; k += 4) g0 += pl[k] * ldf(Wr, (size_t)k * 128 + t, dt);
  }
  pn[g][t] = (n0 + n1) + (n2 + n3);
  pg[g][t] = g0 + g1;
  __syncthreads();
  if (tid < 128) {
    float nw = pn[0][t] + pn[1][t] + pn[2][t] + pn[3][t] + ldf(bn, t, dt);
    nw = nw > 0.f ? nw : 0.f;
    float gg = pg[0][t] + pg[1][t] + pg[2][t] + pg[3][t] + ldf(br, t, dt);
    gg = gg > 0.f ? gg : 0.f;
    red[t] = gg * ldf(Wc, t, dt) + nw * ldf(Wc, 128 + t, dt);
  }
  __syncthreads();
  for (int s = 64; s > 0; s >>= 1) {
    if (tid < s) red[tid] += red[tid + s];
    __syncthreads();
  }
  if (tid == 0) {
    float z = red[0] + ldf(bc, 0, dt);
    float r = 1.f / (1.f + __expf(-z));
    if (dt) ((float*)out)[b] = r;
    else ((bf16*)out)[b] = __float2bfloat16(r);
  }
}

extern "C" void kernel_launch(void* const* d_in, const int* in_sizes, int n_in,
                              void* d_out, int out_size, void* d_ws, size_t ws_size,
                              hipStream_t stream) {
  const void* x   = d_in[0];
  const void* W0  = d_in[1];
  const void* aS0 = d_in[2];
  const void* aD0 = d_in[3];
  const void* b0  = d_in[4];
  const void* W1  = d_in[5];
  const void* aS1 = d_in[6];
  const void* aD1 = d_in[7];
  const void* b1  = d_in[8];
  const void* Wn  = d_in[9];
  const void* bn  = d_in[10];
  const void* Wr  = d_in[11];
  const void* br  = d_in[12];
  const void* Wc  = d_in[13];
  const void* bc  = d_in[14];
  const int* ei    = (const int*)d_in[15];
  const int* batch = (const int*)d_in[16];

  const int N = in_sizes[16];
  const int IN = in_sizes[0] / N;
  const int E = in_sizes[15] / 2;
  const int B = out_size;
  const int Etot = E + N;
  const int Kpad0 = (IN + 31) / 32 * 32;   // 320

  char* w = (char*)d_ws;
  size_t off = 0;
  auto alloc = [&](size_t bytes) { void* p = w + off; off += (bytes + 255) / 256 * 256; return p; };
  int* flag      = (int*)alloc(256);
  bf16* bufA     = (bf16*)alloc((size_t)N * 128 * 2);
  bf16* bufB     = (bf16*)alloc((size_t)N * 128 * 2);
  float2* as2    = (float2*)alloc((size_t)N * 8);
  float2* ad2    = (float2*)alloc((size_t)N * 8);
  int* cnt       = (int*)alloc((size_t)N * 4);
  int* rowstart  = (int*)alloc((size_t)(N + 1) * 4);
  int* cursor    = (int*)alloc((size_t)N * 4);
  int* adj       = (int*)alloc((size_t)Etot * 4);
  int* csum      = (int*)alloc(1024);
  ushort* Wt0    = (ushort*)alloc((size_t)128 * Kpad0 * 2);
  ushort* Wt1    = (ushort*)alloc((size_t)128 * 128 * 2);
  float* pooled  = (float*)alloc((size_t)B * 128 * 4);

  int ndet = in_sizes[0] < 4096 ? in_sizes[0] : 4096;
  detect_dtype<<<1, 256, 0, stream>>>(x, ndet, flag);

  hipMemsetAsync(cnt, 0, sizeof(int) * N, stream);
  hipMemsetAsync(pooled, 0, sizeof(float) * (size_t)B * 128, stream);

  const int tb = 256;
  count_edges<<<(Etot + tb - 1) / tb, tb, 0, stream>>>(ei, N, E, cnt);
  int nb = (N + 1023) / 1024;
  scan_reduce<<<nb, 256, 0, stream>>>(cnt, N, csum);
  scan_top<<<1, 256, 0, stream>>>(csum, nb, rowstart, N);
  scan_down<<<nb, 256, 0, stream>>>(cnt, N, csum, rowstart, cursor);
  scatter_edges<<<(Etot + tb - 1) / tb, tb, 0, stream>>>(ei, N, E, cursor, adj);

  pack_wt<<<128, Kpad0, 0, stream>>>(W0, Wt0, IN, Kpad0, flag);
  pack_wt<<<128, 128, 0, stream>>>(W1, Wt1, 128, 128, flag);

  int ggrid = (N + 63) / 64;
  int pgrid = (N + 127) / 128;
  int wgrid = ((N * 64) + 255) / 256;

  // Layer 0
  mfma_gemm<true><<<ggrid, 256, 0, stream>>>(x, Wt0, bufA, as2, ad2, aS0, aD0, N, IN, Kpad0, flag);
  gat_agg2<<<wgrid, 256, 0, stream>>>(bufA, as2, ad2, rowstart, adj, b0, bufB, N, flag);

  // Layer 1
  mfma_gemm<false><<<ggrid, 256, 0, stream>>>(bufB, Wt1, bufA, as2, ad2, aS1, aD1, N, 128, 128, flag);
  gat_agg2<<<wgrid, 256, 0, stream>>>(bufA, as2, ad2, rowstart, adj, b1, bufB, N, flag);

  // Head
  pool_kernel<<<pgrid, 256, 0, stream>>>(bufB, batch, pooled, N);
  head3_kernel<<<B, 512, 0, stream>>>(pooled, x, batch, Wr, br, Wn, bn, Wc, bc,
                                      (void*)d_out, N, IN, flag);
}

// Round 7
// 363.581 us; speedup vs baseline: 2.1470x; 1.2096x over previous
//
#include <hip/hip_runtime.h>
#include <hip/hip_bf16.h>

typedef __hip_bfloat16 bf16;
typedef __attribute__((ext_vector_type(8))) __bf16 bf16x8;
typedef __attribute__((ext_vector_type(4))) float f32x4;

__device__ __forceinline__ float toF(bf16 v) { return __bfloat162float(v); }

// dual-dtype load: dt=1 -> underlying memory is fp32; dt=0 -> bf16
__device__ __forceinline__ float ldf(const void* p, size_t i, int dt) {
  return dt ? ((const float*)p)[i] : __bfloat162float(((const bf16*)p)[i]);
}
__device__ __forceinline__ ushort toBF(float f) {
  union { bf16 b; ushort u; } cv; cv.b = __float2bfloat16(f); return cv.u;
}

// ---------------- dtype detection ----------------
__global__ void detect_dtype(const void* x, int n, int* flag) {
  __shared__ int s;
  if (threadIdx.x == 0) s = 0;
  __syncthreads();
  const bf16* xb = (const bf16*)x;
  int bad = 0;
  for (int i = threadIdx.x; i < n; i += 256) {
    float v = __bfloat162float(xb[i]);
    if (!(fabsf(v) < 1e6f)) bad = 1;
  }
  if (bad) atomicOr(&s, 1);
  __syncthreads();
  if (threadIdx.x == 0) flag[0] = s;
}

// ---------------- CSR build (real edges only; self-loops handled in agg) -------------
// count + capture rank (stable within dst via atomic return)
__global__ void count_rank(const int* __restrict__ ei, int E,
                           int* __restrict__ cnt, int* __restrict__ rank) {
  int e = blockIdx.x * blockDim.x + threadIdx.x;
  if (e >= E) return;
  int d = ei[E + e];
  rank[e] = atomicAdd(&cnt[d], 1);
}

__global__ __launch_bounds__(256) void scan_reduce(const int* __restrict__ cnt, int n, int* __restrict__ csum) {
  int base = blockIdx.x * 1024;
  int t = threadIdx.x;
  int s = 0;
#pragma unroll
  for (int j = 0; j < 4; j++) {
    int i = base + t * 4 + j;
    if (i < n) s += cnt[i];
  }
#pragma unroll
  for (int off = 32; off > 0; off >>= 1) s += __shfl_down(s, off, 64);
  __shared__ int ws[4];
  if ((t & 63) == 0) ws[t >> 6] = s;
  __syncthreads();
  if (t == 0) csum[blockIdx.x] = ws[0] + ws[1] + ws[2] + ws[3];
}

__global__ __launch_bounds__(256) void scan_top(int* __restrict__ csum, int nb, int* __restrict__ rowstart, int n) {
  __shared__ int sc[256];
  int t = threadIdx.x;
  int v0 = (t < nb) ? csum[t] : 0;
  sc[t] = v0;
  for (int off = 1; off < 256; off <<= 1) {
    __syncthreads();
    int v = (t >= off) ? sc[t - off] : 0;
    __syncthreads();
    sc[t] += v;
  }
  __syncthreads();
  if (t < nb) csum[t] = sc[t] - v0;  // exclusive
  if (t == 0) rowstart[n] = sc[255]; // total
}

__global__ __launch_bounds__(256) void scan_down(const int* __restrict__ cnt, int n,
                                                 const int* __restrict__ csum,
                                                 int* __restrict__ rowstart) {
  int base = blockIdx.x * 1024;
  int t = threadIdx.x, lane = t & 63, w = t >> 6;
  int v[4];
#pragma unroll
  for (int j = 0; j < 4; j++) {
    int i = base + t * 4 + j;
    v[j] = (i < n) ? cnt[i] : 0;
  }
  int s1 = v[0], s2 = s1 + v[1], s3 = s2 + v[2], s4 = s3 + v[3];
  int x = s4;
#pragma unroll
  for (int off = 1; off < 64; off <<= 1) {
    int y = __shfl_up(x, off, 64);
    if (lane >= off) x += y;
  }
  int texcl = x - s4;
  __shared__ int ws[4];
  if (lane == 63) ws[w] = x;
  __syncthreads();
  int woff = 0;
  for (int i = 0; i < 4; i++) if (i < w) woff += ws[i];
  int b0 = csum[blockIdx.x] + woff + texcl;
  int e0 = b0, e1 = b0 + s1, e2 = b0 + s2, e3 = b0 + s3;
  int i0 = base + t * 4;
  if (i0 + 0 < n) rowstart[i0 + 0] = e0;
  if (i0 + 1 < n) rowstart[i0 + 1] = e1;
  if (i0 + 2 < n) rowstart[i0 + 2] = e2;
  if (i0 + 3 < n) rowstart[i0 + 3] = e3;
}

// atomic-free scatter using precomputed rank
__global__ void scatter2(const int* __restrict__ ei, int E,
                         const int* __restrict__ rowstart, const int* __restrict__ rank,
                         int* __restrict__ adj) {
  int e = blockIdx.x * blockDim.x + threadIdx.x;
  if (e >= E) return;
  int s = ei[e], d = ei[E + e];
  adj[rowstart[d] + rank[e]] = s;
}

// ---------------- weight pre-transpose: Wt[c][k] = W[k][c], bf16 ----------------
__global__ void pack_wt(const void* __restrict__ W, ushort* __restrict__ Wt, int K, int Kpad,
                        const int* __restrict__ dtflag) {
  int dt = dtflag[0];
  int c = blockIdx.x;
  int k = threadIdx.x;
  if (k >= Kpad) return;
  float v = (k < K) ? ldf(W, (size_t)k * 128 + c, dt) : 0.f;
  Wt[(size_t)c * Kpad + k] = toBF(v);
}

// ---------------- head-weight fp32 pack: [Wn | Wr | bn | br | Wc | bc] ----------------
__global__ void convert_head(const void* Wn, const void* Wr, const void* bn, const void* br,
                             const void* Wc, const void* bc, float* __restrict__ dst, int IN,
                             const int* __restrict__ dtflag) {
  int dt = dtflag[0];
  int i = blockIdx.x * blockDim.x + threadIdx.x;
  int s0 = IN * 128, s1 = s0 + 128 * 128, s2 = s1 + 128, s3 = s2 + 128, s4 = s3 + 256, s5 = s4 + 1;
  if (i >= s5) return;
  float v;
  if (i < s0) v = ldf(Wn, i, dt);
  else if (i < s1) v = ldf(Wr, i - s0, dt);
  else if (i < s2) v = ldf(bn, i - s1, dt);
  else if (i < s3) v = ldf(br, i - s2, dt);
  else if (i < s4) v = ldf(Wc, i - s3, dt);
  else v = ldf(bc, 0, dt);
  dst[i] = v;
}

// ---------------- MFMA GEMM + fused attention logits ----------------
template <bool DUALA>
__global__ __launch_bounds__(256) void mfma_gemm(const void* __restrict__ A, const ushort* __restrict__ Wt,
                                                 bf16* __restrict__ C,
                                                 float2* __restrict__ as2, float2* __restrict__ ad2,
                                                 const void* __restrict__ aS, const void* __restrict__ aD,
                                                 int nrows, int K, int Kpad,
                                                 const int* __restrict__ dtflag) {
  __shared__ __align__(16) ushort As[64 * 32];
  __shared__ __align__(16) ushort Ws[128 * 32];
  int dtg = dtflag[0];
  int tid = threadIdx.x;
  int wave = tid >> 6, lane = tid & 63;
  int m = lane & 15, q = lane >> 4;
  int row0 = blockIdx.x * 64;

  f32x4 acc[8];
#pragma unroll
  for (int ct = 0; ct < 8; ct++) acc[ct] = (f32x4){0.f, 0.f, 0.f, 0.f};

  uint stA[4];
  float stAf[8];
  uint4 stA16;
  uint4 stW[2];

  auto loadA = [&](int k0) {
    if (DUALA) {
      if (dtg == 0) {
        const unsigned char* Ab = (const unsigned char*)A;
#pragma unroll
        for (int i = 0; i < 4; i++) {
          int e = tid + i * 256;
          int row = e >> 4, kk = (e & 15) * 2;
          int gr = row0 + row, gk = k0 + kk;
          uint pv = 0;
          if (gr < nrows) {
            if (gk + 1 < K) pv = *(const uint*)(Ab + (size_t)gr * ((size_t)K * 2) + (size_t)gk * 2);
            else if (gk < K) pv = *(const ushort*)(Ab + (size_t)gr * ((size_t)K * 2) + (size_t)gk * 2);
          }
          stA[i] = pv;
        }
      } else {
        const float* Af = (const float*)A;
#pragma unroll
        for (int i = 0; i < 8; i++) {
          int e = tid + i * 256;
          int row = e >> 5, kk = e & 31;
          int gr = row0 + row, gk = k0 + kk;
          stAf[i] = (gr < nrows && gk < K) ? Af[(size_t)gr * K + gk] : 0.f;
        }
      }
    } else {
      int row = tid >> 2, kc = (tid & 3) * 8;
      int gr = row0 + row;
      stA16 = (gr < nrows) ? *(const uint4*)((const ushort*)A + (size_t)gr * K + k0 + kc)
                           : (uint4){0u, 0u, 0u, 0u};
    }
  };
  auto loadW = [&](int k0) {
#pragma unroll
    for (int i = 0; i < 2; i++) {
      int e = tid + i * 256;
      int col = e >> 2, kc = (e & 3) * 8;
      stW[i] = *(const uint4*)&Wt[(size_t)col * Kpad + k0 + kc];
    }
  };
  auto storeLDS = [&]() {
    if (DUALA) {
      if (dtg == 0) {
#pragma unroll
        for (int i = 0; i < 4; i++) {
          int e = tid + i * 256;
          int row = e >> 4, kk = (e & 15) * 2;
          *(uint*)&As[row * 32 + kk] = stA[i];
        }
      } else {
#pragma unroll
        for (int i = 0; i < 8; i++) {
          int e = tid + i * 256;
          int row = e >> 5, kk = e & 31;
          As[row * 32 + kk] = toBF(stAf[i]);
        }
      }
    } else {
      int row = tid >> 2, kc = (tid & 3) * 8;
      *(uint4*)&As[row * 32 + kc] = stA16;
    }
#pragma unroll
    for (int i = 0; i < 2; i++) {
      int e = tid + i * 256;
      int col = e >> 2, kc = (e & 3) * 8;
      *(uint4*)&Ws[col * 32 + kc] = stW[i];
    }
  };

  loadA(0);
  loadW(0);
  for (int k0 = 0; k0 < Kpad; k0 += 32) {
    storeLDS();
    __syncthreads();
    int kn = k0 + 32;
    if (kn < Kpad) { loadA(kn); loadW(kn); }
    bf16x8 af = *(const bf16x8*)&As[(wave * 16 + m) * 32 + q * 8];
#pragma unroll
    for (int ct = 0; ct < 8; ct++) {
      bf16x8 bf_ = *(const bf16x8*)&Ws[(ct * 16 + m) * 32 + q * 8];
      acc[ct] = __builtin_amdgcn_mfma_f32_16x16x32_bf16(af, bf_, acc[ct], 0, 0, 0);
    }
    __syncthreads();
  }

#pragma unroll
  for (int ct = 0; ct < 8; ct++) {
#pragma unroll
    for (int r = 0; r < 4; r++) {
      int grow = row0 + wave * 16 + q * 4 + r;
      if (grow < nrows) C[(size_t)grow * 128 + ct * 16 + m] = __float2bfloat16(acc[ct][r]);
    }
  }

  float aSv[8], aDv[8];
#pragma unroll
  for (int ct = 0; ct < 8; ct++) {
    aSv[ct] = ldf(aS, ct * 16 + m, dtg);
    aDv[ct] = ldf(aD, ct * 16 + m, dtg);
  }
#pragma unroll
  for (int r = 0; r < 4; r++) {
    float s0 = 0.f, s1 = 0.f, d0 = 0.f, d1 = 0.f;
#pragma unroll
    for (int ct = 0; ct < 4; ct++) {
      float v = acc[ct][r];
      s0 += v * aSv[ct]; d0 += v * aDv[ct];
    }
#pragma unroll
    for (int ct = 4; ct < 8; ct++) {
      float v = acc[ct][r];
      s1 += v * aSv[ct]; d1 += v * aDv[ct];
    }
#pragma unroll
    for (int off = 1; off < 16; off <<= 1) {
      s0 += __shfl_xor(s0, off, 64);
      s1 += __shfl_xor(s1, off, 64);
      d0 += __shfl_xor(d0, off, 64);
      d1 += __shfl_xor(d1, off, 64);
    }
    int grow = row0 + wave * 16 + q * 4 + r;
    if (m == 0 && grow < nrows) {
      as2[grow] = make_float2(s0, s1);
      ad2[grow] = make_float2(d0, d1);
    }
  }
}

// ---------------- GAT aggregate v3: no max pass (exp-arg clamped), analytic self-loop --
// Softmax without max-subtract is mathematically identical; logits are O(10) here and
// the 60.f clamp guards the pathological case. LDS caches (src, w0, w1) per edge.
#define GCAP 64
__global__ __launch_bounds__(256) void gat_agg3(const bf16* __restrict__ xw,
                                                const float2* __restrict__ as2, const float2* __restrict__ ad2,
                                                const int* __restrict__ rowstart, const int* __restrict__ adj,
                                                const void* __restrict__ bias, bf16* __restrict__ out, int N,
                                                const int* __restrict__ dtflag) {
  __shared__ float2 sW[4][GCAP];
  __shared__ int sS[4][GCAP];
  int dt = dtflag[0];
  int wslot = threadIdx.x >> 6;
  int lane = threadIdx.x & 63;
  int n = (blockIdx.x * blockDim.x + threadIdx.x) >> 6;
  bool act = n < N;
  int r0 = 0, r1 = 0;
  float2 adv = make_float2(0.f, 0.f), asn = make_float2(0.f, 0.f);
  if (act) { r0 = rowstart[n]; r1 = rowstart[n + 1]; adv = ad2[n]; asn = as2[n]; }
  int deg = r1 - r0;

  // analytic self-loop weight
  float es0 = asn.x + adv.x; es0 = es0 > 0.f ? es0 : 0.2f * es0;
  float es1 = asn.y + adv.y; es1 = es1 > 0.f ? es1 : 0.2f * es1;
  float ws0 = __expf(fminf(es0, 60.f)), ws1 = __expf(fminf(es1, 60.f));

  // edge weights -> LDS (one slot per lane), local denom
  float den0, den1;
  {
    bool v = act && lane < deg;
    int s = v ? adj[r0 + lane] : 0;
    float w0 = 0.f, w1 = 0.f;
    if (v) {
      float2 asv = as2[s];
      float e0 = asv.x + adv.x; e0 = e0 > 0.f ? e0 : 0.2f * e0;
      float e1 = asv.y + adv.y; e1 = e1 > 0.f ? e1 : 0.2f * e1;
      w0 = __expf(fminf(e0, 60.f)); w1 = __expf(fminf(e1, 60.f));
    }
    sW[wslot][lane] = make_float2(w0, w1);
    sS[wslot][lane] = s;
    den0 = w0; den1 = w1;
  }
  for (int i = r0 + GCAP + lane; i < r1; i += 64) {  // overflow tail (deg > 64, rare)
    int s = adj[i];
    float2 asv = as2[s];
    float e0 = asv.x + adv.x; e0 = e0 > 0.f ? e0 : 0.2f * e0;
    float e1 = asv.y + adv.y; e1 = e1 > 0.f ? e1 : 0.2f * e1;
    den0 += __expf(fminf(e0, 60.f)); den1 += __expf(fminf(e1, 60.f));
  }
#pragma unroll
  for (int off = 32; off > 0; off >>= 1) {
    den0 += __shfl_xor(den0, off, 64);
    den1 += __shfl_xor(den1, off, 64);
  }
  den0 += ws0; den1 += ws1;
  float inv0 = 1.f / (den0 + 1e-16f), inv1 = 1.f / (den1 + 1e-16f);
  // no barrier needed: each wave reads only its own wslot LDS slice

  // gather-accumulate; lane covers cols 2*lane, 2*lane+1 (head0 = lanes<32)
  const uint* xw32 = (const uint*)xw;
  float wsS = (lane < 32) ? ws0 : ws1;
  uint pvs = act ? xw32[((size_t)n << 6) + lane] : 0;
  float a0 = wsS * __uint_as_float(pvs << 16);
  float a1 = wsS * __uint_as_float(pvs & 0xffff0000u);
  int cap = deg < GCAP ? deg : GCAP;
#pragma unroll 4
  for (int i = 0; i < cap; i++) {
    float2 wv = sW[wslot][i];
    int s = sS[wslot][i];
    uint pv = xw32[((size_t)s << 6) + lane];
    float ws = (lane < 32) ? wv.x : wv.y;
    a0 += ws * __uint_as_float(pv << 16);
    a1 += ws * __uint_as_float(pv & 0xffff0000u);
  }
  for (int i = GCAP; i < deg; i++) {  // tail: recompute weight (wave-uniform loop)
    int s = adj[r0 + i];
    float2 asv = as2[s];
    float e0 = asv.x + adv.x; e0 = e0 > 0.f ? e0 : 0.2f * e0;
    float e1 = asv.y + adv.y; e1 = e1 > 0.f ? e1 : 0.2f * e1;
    float w0 = __expf(fminf(e0, 60.f)), w1 = __expf(fminf(e1, 60.f));
    uint pv = xw32[((size_t)s << 6) + lane];
    float ws = (lane < 32) ? w0 : w1;
    a0 += ws * __uint_as_float(pv << 16);
    a1 += ws * __uint_as_float(pv & 0xffff0000u);
  }
  if (act) {
    int c0 = 2 * lane;
    float invs = (lane < 32) ? inv0 : inv1;
    float o0 = a0 * invs + ldf(bias, c0, dt);
    float o1 = a1 * invs + ldf(bias, c0 + 1, dt);
    o0 = o0 > 0.f ? o0 : 0.f;
    o1 = o1 > 0.f ? o1 : 0.f;
    uint pk = (uint)toBF(o0) | ((uint)toBF(o1) << 16);
    ((uint*)out)[(size_t)n * 64 + lane] = pk;
  }
}

// ---------------- parallel mean-pool (unnormalized sums; contiguous batch) ----------------
__global__ __launch_bounds__(256) void pool_kernel(const bf16* __restrict__ h, const int* __restrict__ batch,
                                                   float* __restrict__ pooled, int N) {
  int n0 = blockIdx.x * 128;
  int nEnd = n0 + 128 < N ? n0 + 128 : N;
  int col = threadIdx.x & 127, half = threadIdx.x >> 7;
  float acc = 0.f;
  int cur = -1;
  for (int n = n0 + half; n < nEnd; n += 2) {
    int g = batch[n];
    if (g != cur) {
      if (cur >= 0) atomicAdd(&pooled[(size_t)cur * 128 + col], acc);
      acc = 0.f; cur = g;
    }
    acc += toF(h[(size_t)n * 128 + col]);
  }
  if (cur >= 0) atomicAdd(&pooled[(size_t)cur * 128 + col], acc);
}

// ---------------- head v4: fp32-packed weights, no per-load dtype branch ----------------
__global__ __launch_bounds__(512) void head4_kernel(
    const float* __restrict__ pooled, const void* __restrict__ x, const int* __restrict__ batch,
    const float* __restrict__ HW, void* __restrict__ out, int N, int IN,
    const int* __restrict__ dtflag) {
  const float* Wn_f = HW;
  const float* Wr_f = HW + (size_t)IN * 128;
  const float* bn_f = Wr_f + 128 * 128;
  const float* br_f = bn_f + 128;
  const float* Wc_f = br_f + 128;
  const float* bc_f = Wc_f + 256;
  int dt = dtflag[0];
  int b = blockIdx.x;
  int tid = threadIdx.x;
  int t = tid & 127, g = tid >> 7;  // g in 0..3
  __shared__ int sr0, sr1;
  __shared__ float xs[512];
  __shared__ float pl[128];
  __shared__ float pn[4][128];
  __shared__ float pg[4][128];
  __shared__ float red[128];
  if (tid == 0) {
    int lo = 0, hi = N;
    while (lo < hi) { int mid = (lo + hi) >> 1; if (batch[mid] < b) lo = mid + 1; else hi = mid; }
    sr0 = lo;
  }
  if (tid == 1) {
    int lo = 0, hi = N, b1 = b + 1;
    while (lo < hi) { int mid = (lo + hi) >> 1; if (batch[mid] < b1) lo = mid + 1; else hi = mid; }
    sr1 = lo;
  }
  __syncthreads();
  int r0 = sr0;
  float inv_cnt = 1.f / (float)(sr1 - r0);
  if (tid < 128) pl[tid] = pooled[(size_t)b * 128 + tid] * inv_cnt;
  if (dt) {
    const float* xf = (const float*)x + (size_t)r0 * IN;
    for (int k = tid; k < IN; k += 512) xs[k] = xf[k];
  } else {
    const bf16* xb = (const bf16*)x + (size_t)r0 * IN;
    for (int k = tid; k < IN; k += 512) xs[k] = toF(xb[k]);
  }
  __syncthreads();

  // news matvec: k ≡ g (mod 4), 4 independent accumulators
  float n0 = 0.f, n1 = 0.f, n2 = 0.f, n3 = 0.f;
  {
    int k = g;
    for (; k + 12 < IN; k += 16) {
      n0 += xs[k]      * Wn_f[(size_t)k * 128 + t];
      n1 += xs[k + 4]  * Wn_f[(size_t)(k + 4) * 128 + t];
      n2 += xs[k + 8]  * Wn_f[(size_t)(k + 8) * 128 + t];
      n3 += xs[k + 12] * Wn_f[(size_t)(k + 12) * 128 + t];
    }
    for (; k < IN; k += 4) n0 += xs[k] * Wn_f[(size_t)k * 128 + t];
  }
  // readout matvec
  float g0 = 0.f, g1 = 0.f;
  {
    int k = g;
    for (; k + 4 < 128; k += 8) {
      g0 += pl[k]     * Wr_f[(size_t)k * 128 + t];
      g1 += pl[k + 4] * Wr_f[(size_t)(k + 4) * 128 + t];
    }
    for (; k < 128; k += 4) g0 += pl[k] * Wr_f[(size_t)k * 128 + t];
  }
  pn[g][t] = (n0 + n1) + (n2 + n3);
  pg[g][t] = g0 + g1;
  __syncthreads();
  if (tid < 128) {
    float nw = pn[0][t] + pn[1][t] + pn[2][t] + pn[3][t] + bn_f[t];
    nw = nw > 0.f ? nw : 0.f;
    float gg = pg[0][t] + pg[1][t] + pg[2][t] + pg[3][t] + br_f[t];
    gg = gg > 0.f ? gg : 0.f;
    red[t] = gg * Wc_f[t] + nw * Wc_f[128 + t];
  }
  __syncthreads();
  for (int s = 64; s > 0; s >>= 1) {
    if (tid < s) red[tid] += red[tid + s];
    __syncthreads();
  }
  if (tid == 0) {
    float z = red[0] + bc_f[0];
    float r = 1.f / (1.f + __expf(-z));
    if (dt) ((float*)out)[b] = r;
    else ((bf16*)out)[b] = __float2bfloat16(r);
  }
}

extern "C" void kernel_launch(void* const* d_in, const int* in_sizes, int n_in,
                              void* d_out, int out_size, void* d_ws, size_t ws_size,
                              hipStream_t stream) {
  const void* x   = d_in[0];
  const void* W0  = d_in[1];
  const void* aS0 = d_in[2];
  const void* aD0 = d_in[3];
  const void* b0  = d_in[4];
  const void* W1  = d_in[5];
  const void* aS1 = d_in[6];
  const void* aD1 = d_in[7];
  const void* b1  = d_in[8];
  const void* Wn  = d_in[9];
  const void* bn  = d_in[10];
  const void* Wr  = d_in[11];
  const void* br  = d_in[12];
  const void* Wc  = d_in[13];
  const void* bc  = d_in[14];
  const int* ei    = (const int*)d_in[15];
  const int* batch = (const int*)d_in[16];

  const int N = in_sizes[16];
  const int IN = in_sizes[0] / N;
  const int E = in_sizes[15] / 2;
  const int B = out_size;
  const int Kpad0 = (IN + 31) / 32 * 32;   // 320
  const int hw_elems = IN * 128 + 128 * 128 + 128 + 128 + 256 + 1;

  char* w = (char*)d_ws;
  size_t off = 0;
  auto alloc = [&](size_t bytes) { void* p = w + off; off += (bytes + 255) / 256 * 256; return p; };
  int* flag      = (int*)alloc(256);
  bf16* bufA     = (bf16*)alloc((size_t)N * 128 * 2);
  bf16* bufB     = (bf16*)alloc((size_t)N * 128 * 2);
  float2* as2    = (float2*)alloc((size_t)N * 8);
  float2* ad2    = (float2*)alloc((size_t)N * 8);
  int* cnt       = (int*)alloc((size_t)N * 4);
  int* rowstart  = (int*)alloc((size_t)(N + 1) * 4);
  int* rank      = (int*)alloc((size_t)E * 4);
  int* adj       = (int*)alloc((size_t)E * 4);
  int* csum      = (int*)alloc(1024);
  ushort* Wt0    = (ushort*)alloc((size_t)128 * Kpad0 * 2);
  ushort* Wt1    = (ushort*)alloc((size_t)128 * 128 * 2);
  float* pooled  = (float*)alloc((size_t)B * 128 * 4);
  float* HW      = (float*)alloc((size_t)hw_elems * 4);

  int ndet = in_sizes[0] < 4096 ? in_sizes[0] : 4096;
  detect_dtype<<<1, 256, 0, stream>>>(x, ndet, flag);

  hipMemsetAsync(cnt, 0, sizeof(int) * N, stream);
  hipMemsetAsync(pooled, 0, sizeof(float) * (size_t)B * 128, stream);

  const int tb = 256;
  count_rank<<<(E + tb - 1) / tb, tb, 0, stream>>>(ei, E, cnt, rank);
  int nb = (N + 1023) / 1024;
  scan_reduce<<<nb, 256, 0, stream>>>(cnt, N, csum);
  scan_top<<<1, 256, 0, stream>>>(csum, nb, rowstart, N);
  scan_down<<<nb, 256, 0, stream>>>(cnt, N, csum, rowstart);
  scatter2<<<(E + tb - 1) / tb, tb, 0, stream>>>(ei, E, rowstart, rank, adj);

  pack_wt<<<128, Kpad0, 0, stream>>>(W0, Wt0, IN, Kpad0, flag);
  pack_wt<<<128, 128, 0, stream>>>(W1, Wt1, 128, 128, flag);
  convert_head<<<(hw_elems + 255) / 256, 256, 0, stream>>>(Wn, Wr, bn, br, Wc, bc, HW, IN, flag);

  int ggrid = (N + 63) / 64;
  int pgrid = (N + 127) / 128;
  int wgrid = ((N * 64) + 255) / 256;

  // Layer 0
  mfma_gemm<true><<<ggrid, 256, 0, stream>>>(x, Wt0, bufA, as2, ad2, aS0, aD0, N, IN, Kpad0, flag);
  gat_agg3<<<wgrid, 256, 0, stream>>>(bufA, as2, ad2, rowstart, adj, b0, bufB, N, flag);

  // Layer 1
  mfma_gemm<false><<<ggrid, 256, 0, stream>>>(bufB, Wt1, bufA, as2, ad2, aS1, aD1, N, 128, 128, flag);
  gat_agg3<<<wgrid, 256, 0, stream>>>(bufA, as2, ad2, rowstart, adj, b1, bufB, N, flag);

  // Head
  pool_kernel<<<pgrid, 256, 0, stream>>>(bufB, batch, pooled, N);
  head4_kernel<<<B, 512, 0, stream>>>(pooled, x, batch, HW, (void*)d_out, N, IN, flag);
}

// Round 8
// 356.917 us; speedup vs baseline: 2.1871x; 1.0187x over previous
//
#include <hip/hip_runtime.h>
#include <hip/hip_bf16.h>

typedef __hip_bfloat16 bf16;
typedef __attribute__((ext_vector_type(8))) __bf16 bf16x8;
typedef __attribute__((ext_vector_type(4))) float f32x4;

__device__ __forceinline__ float toF(bf16 v) { return __bfloat162float(v); }

// dual-dtype load: dt=1 -> underlying memory is fp32; dt=0 -> bf16
__device__ __forceinline__ float ldf(const void* p, size_t i, int dt) {
  return dt ? ((const float*)p)[i] : __bfloat162float(((const bf16*)p)[i]);
}
__device__ __forceinline__ ushort toBF(float f) {
  union { bf16 b; ushort u; } cv; cv.b = __float2bfloat16(f); return cv.u;
}

// ---------------- dtype detection ----------------
__global__ void detect_dtype(const void* x, int n, int* flag) {
  __shared__ int s;
  if (threadIdx.x == 0) s = 0;
  __syncthreads();
  const bf16* xb = (const bf16*)x;
  int bad = 0;
  for (int i = threadIdx.x; i < n; i += 256) {
    float v = __bfloat162float(xb[i]);
    if (!(fabsf(v) < 1e6f)) bad = 1;
  }
  if (bad) atomicOr(&s, 1);
  __syncthreads();
  if (threadIdx.x == 0) flag[0] = s;
}

// ---------------- CSR build (real edges only; self-loops analytic in agg) -------------
__global__ void count_rank(const int* __restrict__ ei, int E,
                           int* __restrict__ cnt, int* __restrict__ rank) {
  int e = blockIdx.x * blockDim.x + threadIdx.x;
  if (e >= E) return;
  int d = ei[E + e];
  rank[e] = atomicAdd(&cnt[d], 1);
}

__global__ __launch_bounds__(256) void scan_reduce(const int* __restrict__ cnt, int n, int* __restrict__ csum) {
  int base = blockIdx.x * 1024;
  int t = threadIdx.x;
  int s = 0;
#pragma unroll
  for (int j = 0; j < 4; j++) {
    int i = base + t * 4 + j;
    if (i < n) s += cnt[i];
  }
#pragma unroll
  for (int off = 32; off > 0; off >>= 1) s += __shfl_down(s, off, 64);
  __shared__ int ws[4];
  if ((t & 63) == 0) ws[t >> 6] = s;
  __syncthreads();
  if (t == 0) csum[blockIdx.x] = ws[0] + ws[1] + ws[2] + ws[3];
}

__global__ __launch_bounds__(256) void scan_top(int* __restrict__ csum, int nb, int* __restrict__ rowstart, int n) {
  __shared__ int sc[256];
  int t = threadIdx.x;
  int v0 = (t < nb) ? csum[t] : 0;
  sc[t] = v0;
  for (int off = 1; off < 256; off <<= 1) {
    __syncthreads();
    int v = (t >= off) ? sc[t - off] : 0;
    __syncthreads();
    sc[t] += v;
  }
  __syncthreads();
  if (t < nb) csum[t] = sc[t] - v0;  // exclusive
  if (t == 0) rowstart[n] = sc[255]; // total
}

__global__ __launch_bounds__(256) void scan_down(const int* __restrict__ cnt, int n,
                                                 const int* __restrict__ csum,
                                                 int* __restrict__ rowstart) {
  int base = blockIdx.x * 1024;
  int t = threadIdx.x, lane = t & 63, w = t >> 6;
  int v[4];
#pragma unroll
  for (int j = 0; j < 4; j++) {
    int i = base + t * 4 + j;
    v[j] = (i < n) ? cnt[i] : 0;
  }
  int s1 = v[0], s2 = s1 + v[1], s3 = s2 + v[2], s4 = s3 + v[3];
  int x = s4;
#pragma unroll
  for (int off = 1; off < 64; off <<= 1) {
    int y = __shfl_up(x, off, 64);
    if (lane >= off) x += y;
  }
  int texcl = x - s4;
  __shared__ int ws[4];
  if (lane == 63) ws[w] = x;
  __syncthreads();
  int woff = 0;
  for (int i = 0; i < 4; i++) if (i < w) woff += ws[i];
  int b0 = csum[blockIdx.x] + woff + texcl;
  int e0 = b0, e1 = b0 + s1, e2 = b0 + s2, e3 = b0 + s3;
  int i0 = base + t * 4;
  if (i0 + 0 < n) rowstart[i0 + 0] = e0;
  if (i0 + 1 < n) rowstart[i0 + 1] = e1;
  if (i0 + 2 < n) rowstart[i0 + 2] = e2;
  if (i0 + 3 < n) rowstart[i0 + 3] = e3;
}

__global__ void scatter2(const int* __restrict__ ei, int E,
                         const int* __restrict__ rowstart, const int* __restrict__ rank,
                         int* __restrict__ adj) {
  int e = blockIdx.x * blockDim.x + threadIdx.x;
  if (e >= E) return;
  int s = ei[e], d = ei[E + e];
  adj[rowstart[d] + rank[e]] = s;
}

// ---------------- W pack for direct MFMA frag loads: Wt2[k/8][col][k%8] ----------------
__global__ void pack_wt2(const void* __restrict__ W, ushort* __restrict__ Wt2, int K, int Kpad,
                         const int* __restrict__ dtflag) {
  int dt = dtflag[0];
  int c = blockIdx.x;           // 0..127
  int k = threadIdx.x;          // 0..Kpad-1
  if (k >= Kpad) return;
  float v = (k < K) ? ldf(W, (size_t)k * 128 + c, dt) : 0.f;
  Wt2[((size_t)(k >> 3) * 128 + c) * 8 + (k & 7)] = toBF(v);
}

// ---------------- x K-tail pack: xtail[n][32] = x[n][Kmain..K-1], zero-padded ----------
__global__ void pack_xtail(const void* __restrict__ x, ushort* __restrict__ xt,
                           int N, int K, int Kmain, const int* __restrict__ dtflag) {
  int dt = dtflag[0];
  int idx = blockIdx.x * blockDim.x + threadIdx.x;
  if (idx >= N * 32) return;
  int n = idx >> 5, j = idx & 31;
  int k = Kmain + j;
  float v = (k < K) ? ldf(x, (size_t)n * K + k, dt) : 0.f;
  xt[idx] = toBF(v);
}

// ---------------- head-weight fp32 pack: [Wn | Wr | bn | br | Wc | bc] ----------------
__global__ void convert_head(const void* Wn, const void* Wr, const void* bn, const void* br,
                             const void* Wc, const void* bc, float* __restrict__ dst, int IN,
                             const int* __restrict__ dtflag) {
  int dt = dtflag[0];
  int i = blockIdx.x * blockDim.x + threadIdx.x;
  int s0 = IN * 128, s1 = s0 + 128 * 128, s2 = s1 + 128, s3 = s2 + 128, s4 = s3 + 256, s5 = s4 + 1;
  if (i >= s5) return;
  float v;
  if (i < s0) v = ldf(Wn, i, dt);
  else if (i < s1) v = ldf(Wr, i - s0, dt);
  else if (i < s2) v = ldf(bn, i - s1, dt);
  else if (i < s3) v = ldf(br, i - s2, dt);
  else if (i < s4) v = ldf(Wc, i - s3, dt);
  else v = ldf(bc, 0, dt);
  dst[i] = v;
}

// ---------------- MFMA GEMM v2: LDS-free, barrier-free + fused attention logits -------
// C[nrows,128] = A[nrows,K] @ W[K,128]. Wt2 pre-packed for direct frag loads.
// 64 rows/block, 4 waves, wave=16 rows. Each lane loads its MFMA fragments straight
// from global (A: 16B/row-frag; W: 256B-contiguous per 16 lanes). TLP hides latency.
// DUALA: A = raw x input (dt-branched, dword loads, K arbitrary; tail via xtail).
// !DUALA: A = bf16 buffer, rows 16B-aligned, K%32==0, no tail.
template <bool DUALA>
__global__ __launch_bounds__(256) void mfma_gemm2(const void* __restrict__ A, const ushort* __restrict__ Wt2,
                                                  const ushort* __restrict__ xtail,
                                                  bf16* __restrict__ C,
                                                  float2* __restrict__ as2, float2* __restrict__ ad2,
                                                  const void* __restrict__ aS, const void* __restrict__ aD,
                                                  int nrows, int K, const int* __restrict__ dtflag) {
  int dtg = dtflag[0];
  int tid = threadIdx.x;
  int wave = tid >> 6, lane = tid & 63;
  int m = lane & 15, q = lane >> 4;
  int row0 = blockIdx.x * 64;
  int rowA = row0 + wave * 16 + m;
  int rA = rowA < nrows ? rowA : nrows - 1;   // clamp (stores are guarded)

  f32x4 acc[8];
#pragma unroll
  for (int ct = 0; ct < 8; ct++) acc[ct] = (f32x4){0.f, 0.f, 0.f, 0.f};

  const ushort* wq = Wt2 + (size_t)q * 1024 + (size_t)m * 8;
  int nmain = K >> 5;           // full 32-K iterations
  int Kmain = nmain << 5;

  if (!DUALA || dtg == 0) {
    // bf16 source. DUALA rows are only 4B-aligned (stride K*2) -> dword loads;
    // !DUALA rows 16B-aligned -> single dwordx4.
    const unsigned char* ab = (const unsigned char*)A + (size_t)rA * ((size_t)K * 2) + (size_t)q * 16;
    for (int it = 0; it < nmain; it++) {
      bf16x8 av;
      if (DUALA) {
        uint u[4];
#pragma unroll
        for (int j = 0; j < 4; j++) u[j] = *(const uint*)(ab + (size_t)it * 64 + j * 4);
        __builtin_memcpy(&av, u, 16);
      } else {
        av = *(const bf16x8*)(ab + (size_t)it * 64);
      }
      const ushort* wk = wq + (size_t)it * 4096;
      bf16x8 wv[8];
#pragma unroll
      for (int ct = 0; ct < 8; ct++) wv[ct] = *(const bf16x8*)(wk + ct * 128);
#pragma unroll
      for (int ct = 0; ct < 8; ct++)
        acc[ct] = __builtin_amdgcn_mfma_f32_16x16x32_bf16(av, wv[ct], acc[ct], 0, 0, 0);
    }
  } else {
    // fp32 source (DUALA, dt=1)
    const float* af = (const float*)A + (size_t)rA * K + q * 8;
    for (int it = 0; it < nmain; it++) {
      ushort u[8];
#pragma unroll
      for (int j = 0; j < 8; j++) u[j] = toBF(af[it * 32 + j]);
      bf16x8 av;
      __builtin_memcpy(&av, u, 16);
      const ushort* wk = wq + (size_t)it * 4096;
      bf16x8 wv[8];
#pragma unroll
      for (int ct = 0; ct < 8; ct++) wv[ct] = *(const bf16x8*)(wk + ct * 128);
#pragma unroll
      for (int ct = 0; ct < 8; ct++)
        acc[ct] = __builtin_amdgcn_mfma_f32_16x16x32_bf16(av, wv[ct], acc[ct], 0, 0, 0);
    }
  }
  if (DUALA && Kmain < K) {
    // tail: cols Kmain..K-1 from zero-padded xtail[n][32] (16B-aligned)
    bf16x8 av = *(const bf16x8*)(xtail + (size_t)rA * 32 + q * 8);
    const ushort* wk = wq + (size_t)nmain * 4096;
    bf16x8 wv[8];
#pragma unroll
    for (int ct = 0; ct < 8; ct++) wv[ct] = *(const bf16x8*)(wk + ct * 128);
#pragma unroll
    for (int ct = 0; ct < 8; ct++)
      acc[ct] = __builtin_amdgcn_mfma_f32_16x16x32_bf16(av, wv[ct], acc[ct], 0, 0, 0);
  }

  // ---- C writeback (C/D: col=lane&15, row=q*4+r) ----
#pragma unroll
  for (int ct = 0; ct < 8; ct++) {
#pragma unroll
    for (int r = 0; r < 4; r++) {
      int grow = row0 + wave * 16 + q * 4 + r;
      if (grow < nrows) C[(size_t)grow * 128 + ct * 16 + m] = __float2bfloat16(acc[ct][r]);
    }
  }

  // ---- fused attention logits ----
  float aSv[8], aDv[8];
#pragma unroll
  for (int ct = 0; ct < 8; ct++) {
    aSv[ct] = ldf(aS, ct * 16 + m, dtg);
    aDv[ct] = ldf(aD, ct * 16 + m, dtg);
  }
#pragma unroll
  for (int r = 0; r < 4; r++) {
    float s0 = 0.f, s1 = 0.f, d0 = 0.f, d1 = 0.f;
#pragma unroll
    for (int ct = 0; ct < 4; ct++) {
      float v = acc[ct][r];
      s0 += v * aSv[ct]; d0 += v * aDv[ct];
    }
#pragma unroll
    for (int ct = 4; ct < 8; ct++) {
      float v = acc[ct][r];
      s1 += v * aSv[ct]; d1 += v * aDv[ct];
    }
#pragma unroll
    for (int off = 1; off < 16; off <<= 1) {
      s0 += __shfl_xor(s0, off, 64);
      s1 += __shfl_xor(s1, off, 64);
      d0 += __shfl_xor(d0, off, 64);
      d1 += __shfl_xor(d1, off, 64);
    }
    int grow = row0 + wave * 16 + q * 4 + r;
    if (m == 0 && grow < nrows) {
      as2[grow] = make_float2(s0, s1);
      ad2[grow] = make_float2(d0, d1);
    }
  }
}

// ---------------- GAT aggregate v3: no max pass, analytic self-loop ----------------
#define GCAP 64
__global__ __launch_bounds__(256) void gat_agg3(const bf16* __restrict__ xw,
                                                const float2* __restrict__ as2, const float2* __restrict__ ad2,
                                                const int* __restrict__ rowstart, const int* __restrict__ adj,
                                                const void* __restrict__ bias, bf16* __restrict__ out, int N,
                                                const int* __restrict__ dtflag) {
  __shared__ float2 sW[4][GCAP];
  __shared__ int sS[4][GCAP];
  int dt = dtflag[0];
  int wslot = threadIdx.x >> 6;
  int lane = threadIdx.x & 63;
  int n = (blockIdx.x * blockDim.x + threadIdx.x) >> 6;
  bool act = n < N;
  int r0 = 0, r1 = 0;
  float2 adv = make_float2(0.f, 0.f), asn = make_float2(0.f, 0.f);
  if (act) { r0 = rowstart[n]; r1 = rowstart[n + 1]; adv = ad2[n]; asn = as2[n]; }
  int deg = r1 - r0;

  float es0 = asn.x + adv.x; es0 = es0 > 0.f ? es0 : 0.2f * es0;
  float es1 = asn.y + adv.y; es1 = es1 > 0.f ? es1 : 0.2f * es1;
  float ws0 = __expf(fminf(es0, 60.f)), ws1 = __expf(fminf(es1, 60.f));

  float den0, den1;
  {
    bool v = act && lane < deg;
    int s = v ? adj[r0 + lane] : 0;
    float w0 = 0.f, w1 = 0.f;
    if (v) {
      float2 asv = as2[s];
      float e0 = asv.x + adv.x; e0 = e0 > 0.f ? e0 : 0.2f * e0;
      float e1 = asv.y + adv.y; e1 = e1 > 0.f ? e1 : 0.2f * e1;
      w0 = __expf(fminf(e0, 60.f)); w1 = __expf(fminf(e1, 60.f));
    }
    sW[wslot][lane] = make_float2(w0, w1);
    sS[wslot][lane] = s;
    den0 = w0; den1 = w1;
  }
  for (int i = r0 + GCAP + lane; i < r1; i += 64) {
    int s = adj[i];
    float2 asv = as2[s];
    float e0 = asv.x + adv.x; e0 = e0 > 0.f ? e0 : 0.2f * e0;
    float e1 = asv.y + adv.y; e1 = e1 > 0.f ? e1 : 0.2f * e1;
    den0 += __expf(fminf(e0, 60.f)); den1 += __expf(fminf(e1, 60.f));
  }
#pragma unroll
  for (int off = 32; off > 0; off >>= 1) {
    den0 += __shfl_xor(den0, off, 64);
    den1 += __shfl_xor(den1, off, 64);
  }
  den0 += ws0; den1 += ws1;
  float inv0 = 1.f / (den0 + 1e-16f), inv1 = 1.f / (den1 + 1e-16f);

  const uint* xw32 = (const uint*)xw;
  float wsS = (lane < 32) ? ws0 : ws1;
  uint pvs = act ? xw32[((size_t)n << 6) + lane] : 0;
  float a0 = wsS * __uint_as_float(pvs << 16);
  float a1 = wsS * __uint_as_float(pvs & 0xffff0000u);
  int cap = deg < GCAP ? deg : GCAP;
#pragma unroll 4
  for (int i = 0; i < cap; i++) {
    float2 wv = sW[wslot][i];
    int s = sS[wslot][i];
    uint pv = xw32[((size_t)s << 6) + lane];
    float ws = (lane < 32) ? wv.x : wv.y;
    a0 += ws * __uint_as_float(pv << 16);
    a1 += ws * __uint_as_float(pv & 0xffff0000u);
  }
  for (int i = GCAP; i < deg; i++) {
    int s = adj[r0 + i];
    float2 asv = as2[s];
    float e0 = asv.x + adv.x; e0 = e0 > 0.f ? e0 : 0.2f * e0;
    float e1 = asv.y + adv.y; e1 = e1 > 0.f ? e1 : 0.2f * e1;
    float w0 = __expf(fminf(e0, 60.f)), w1 = __expf(fminf(e1, 60.f));
    uint pv = xw32[((size_t)s << 6) + lane];
    float ws = (lane < 32) ? w0 : w1;
    a0 += ws * __uint_as_float(pv << 16);
    a1 += ws * __uint_as_float(pv & 0xffff0000u);
  }
  if (act) {
    int c0 = 2 * lane;
    float invs = (lane < 32) ? inv0 : inv1;
    float o0 = a0 * invs + ldf(bias, c0, dt);
    float o1 = a1 * invs + ldf(bias, c0 + 1, dt);
    o0 = o0 > 0.f ? o0 : 0.f;
    o1 = o1 > 0.f ? o1 : 0.f;
    uint pk = (uint)toBF(o0) | ((uint)toBF(o1) << 16);
    ((uint*)out)[(size_t)n * 64 + lane] = pk;
  }
}

// ---------------- parallel mean-pool (unnormalized sums; contiguous batch) ----------------
__global__ __launch_bounds__(256) void pool_kernel(const bf16* __restrict__ h, const int* __restrict__ batch,
                                                   float* __restrict__ pooled, int N) {
  int n0 = blockIdx.x * 128;
  int nEnd = n0 + 128 < N ? n0 + 128 : N;
  int col = threadIdx.x & 127, half = threadIdx.x >> 7;
  float acc = 0.f;
  int cur = -1;
  for (int n = n0 + half; n < nEnd; n += 2) {
    int g = batch[n];
    if (g != cur) {
      if (cur >= 0) atomicAdd(&pooled[(size_t)cur * 128 + col], acc);
      acc = 0.f; cur = g;
    }
    acc += toF(h[(size_t)n * 128 + col]);
  }
  if (cur >= 0) atomicAdd(&pooled[(size_t)cur * 128 + col], acc);
}

// ---------------- head v4: fp32-packed weights, no per-load dtype branch ----------------
__global__ __launch_bounds__(512) void head4_kernel(
    const float* __restrict__ pooled, const void* __restrict__ x, const int* __restrict__ batch,
    const float* __restrict__ HW, void* __restrict__ out, int N, int IN,
    const int* __restrict__ dtflag) {
  const float* Wn_f = HW;
  const float* Wr_f = HW + (size_t)IN * 128;
  const float* bn_f = Wr_f + 128 * 128;
  const float* br_f = bn_f + 128;
  const float* Wc_f = br_f + 128;
  const float* bc_f = Wc_f + 256;
  int dt = dtflag[0];
  int b = blockIdx.x;
  int tid = threadIdx.x;
  int t = tid & 127, g = tid >> 7;
  __shared__ int sr0, sr1;
  __shared__ float xs[512];
  __shared__ float pl[128];
  __shared__ float pn[4][128];
  __shared__ float pg[4][128];
  __shared__ float red[128];
  if (tid == 0) {
    int lo = 0, hi = N;
    while (lo < hi) { int mid = (lo + hi) >> 1; if (batch[mid] < b) lo = mid + 1; else hi = mid; }
    sr0 = lo;
  }
  if (tid == 1) {
    int lo = 0, hi = N, b1 = b + 1;
    while (lo < hi) { int mid = (lo + hi) >> 1; if (batch[mid] < b1) lo = mid + 1; else hi = mid; }
    sr1 = lo;
  }
  __syncthreads();
  int r0 = sr0;
  float inv_cnt = 1.f / (float)(sr1 - r0);
  if (tid < 128) pl[tid] = pooled[(size_t)b * 128 + tid] * inv_cnt;
  if (dt) {
    const float* xf = (const float*)x + (size_t)r0 * IN;
    for (int k = tid; k < IN; k += 512) xs[k] = xf[k];
  } else {
    const bf16* xb = (const bf16*)x + (size_t)r0 * IN;
    for (int k = tid; k < IN; k += 512) xs[k] = toF(xb[k]);
  }
  __syncthreads();

  float n0 = 0.f, n1 = 0.f, n2 = 0.f, n3 = 0.f;
  {
    int k = g;
    for (; k + 12 < IN; k += 16) {
      n0 += xs[k]      * Wn_f[(size_t)k * 128 + t];
      n1 += xs[k + 4]  * Wn_f[(size_t)(k + 4) * 128 + t];
      n2 += xs[k + 8]  * Wn_f[(size_t)(k + 8) * 128 + t];
      n3 += xs[k + 12] * Wn_f[(size_t)(k + 12) * 128 + t];
    }
    for (; k < IN; k += 4) n0 += xs[k] * Wn_f[(size_t)k * 128 + t];
  }
  float g0 = 0.f, g1 = 0.f;
  {
    int k = g;
    for (; k + 4 < 128; k += 8) {
      g0 += pl[k]     * Wr_f[(size_t)k * 128 + t];
      g1 += pl[k + 4] * Wr_f[(size_t)(k + 4) * 128 + t];
    }
    for (; k < 128; k += 4) g0 += pl[k] * Wr_f[(size_t)k * 128 + t];
  }
  pn[g][t] = (n0 + n1) + (n2 + n3);
  pg[g][t] = g0 + g1;
  __syncthreads();
  if (tid < 128) {
    float nw = pn[0][t] + pn[1][t] + pn[2][t] + pn[3][t] + bn_f[t];
    nw = nw > 0.f ? nw : 0.f;
    float gg = pg[0][t] + pg[1][t] + pg[2][t] + pg[3][t] + br_f[t];
    gg = gg > 0.f ? gg : 0.f;
    red[t] = gg * Wc_f[t] + nw * Wc_f[128 + t];
  }
  __syncthreads();
  for (int s = 64; s > 0; s >>= 1) {
    if (tid < s) red[tid] += red[tid + s];
    __syncthreads();
  }
  if (tid == 0) {
    float z = red[0] + bc_f[0];
    float r = 1.f / (1.f + __expf(-z));
    if (dt) ((float*)out)[b] = r;
    else ((bf16*)out)[b] = __float2bfloat16(r);
  }
}

extern "C" void kernel_launch(void* const* d_in, const int* in_sizes, int n_in,
                              void* d_out, int out_size, void* d_ws, size_t ws_size,
                              hipStream_t stream) {
  const void* x   = d_in[0];
  const void* W0  = d_in[1];
  const void* aS0 = d_in[2];
  const void* aD0 = d_in[3];
  const void* b0  = d_in[4];
  const void* W1  = d_in[5];
  const void* aS1 = d_in[6];
  const void* aD1 = d_in[7];
  const void* b1  = d_in[8];
  const void* Wn  = d_in[9];
  const void* bn  = d_in[10];
  const void* Wr  = d_in[11];
  const void* br  = d_in[12];
  const void* Wc  = d_in[13];
  const void* bc  = d_in[14];
  const int* ei    = (const int*)d_in[15];
  const int* batch = (const int*)d_in[16];

  const int N = in_sizes[16];
  const int IN = in_sizes[0] / N;
  const int E = in_sizes[15] / 2;
  const int B = out_size;
  const int Kpad0 = (IN + 31) / 32 * 32;   // 320
  const int Kmain0 = (IN / 32) * 32;       // 288
  const int hw_elems = IN * 128 + 128 * 128 + 128 + 128 + 256 + 1;

  char* w = (char*)d_ws;
  size_t off = 0;
  auto alloc = [&](size_t bytes) { void* p = w + off; off += (bytes + 255) / 256 * 256; return p; };
  int* flag      = (int*)alloc(256);
  bf16* bufA     = (bf16*)alloc((size_t)N * 128 * 2);
  bf16* bufB     = (bf16*)alloc((size_t)N * 128 * 2);
  float2* as2    = (float2*)alloc((size_t)N * 8);
  float2* ad2    = (float2*)alloc((size_t)N * 8);
  int* cnt       = (int*)alloc((size_t)N * 4);
  int* rowstart  = (int*)alloc((size_t)(N + 1) * 4);
  int* rank      = (int*)alloc((size_t)E * 4);
  int* adj       = (int*)alloc((size_t)E * 4);
  int* csum      = (int*)alloc(1024);
  ushort* Wt0    = (ushort*)alloc((size_t)128 * Kpad0 * 2);
  ushort* Wt1    = (ushort*)alloc((size_t)128 * 128 * 2);
  float* pooled  = (float*)alloc((size_t)B * 128 * 4);
  float* HW      = (float*)alloc((size_t)hw_elems * 4);
  // xtail aliases bufB: only alive [pack_xtail .. gemm L0]; bufB first written by
  // gat_agg3 L0, which runs strictly after gemm L0. N*32*2 = 3.2MB << bufB 12.8MB.
  ushort* xtail  = (ushort*)bufB;

  int ndet = in_sizes[0] < 4096 ? in_sizes[0] : 4096;
  detect_dtype<<<1, 256, 0, stream>>>(x, ndet, flag);

  hipMemsetAsync(cnt, 0, sizeof(int) * N, stream);
  hipMemsetAsync(pooled, 0, sizeof(float) * (size_t)B * 128, stream);

  const int tb = 256;
  count_rank<<<(E + tb - 1) / tb, tb, 0, stream>>>(ei, E, cnt, rank);
  int nb = (N + 1023) / 1024;
  scan_reduce<<<nb, 256, 0, stream>>>(cnt, N, csum);
  scan_top<<<1, 256, 0, stream>>>(csum, nb, rowstart, N);
  scan_down<<<nb, 256, 0, stream>>>(cnt, N, csum, rowstart);
  scatter2<<<(E + tb - 1) / tb, tb, 0, stream>>>(ei, E, rowstart, rank, adj);

  pack_wt2<<<128, Kpad0, 0, stream>>>(W0, Wt0, IN, Kpad0, flag);
  pack_wt2<<<128, 128, 0, stream>>>(W1, Wt1, 128, 128, flag);
  pack_xtail<<<(N * 32 + 255) / 256, 256, 0, stream>>>(x, xtail, N, IN, Kmain0, flag);
  convert_head<<<(hw_elems + 255) / 256, 256, 0, stream>>>(Wn, Wr, bn, br, Wc, bc, HW, IN, flag);

  int ggrid = (N + 63) / 64;
  int pgrid = (N + 127) / 128;
  int wgrid = ((N * 64) + 255) / 256;

  // Layer 0
  mfma_gemm2<true><<<ggrid, 256, 0, stream>>>(x, Wt0, xtail, bufA, as2, ad2, aS0, aD0, N, IN, flag);
  gat_agg3<<<wgrid, 256, 0, stream>>>(bufA, as2, ad2, rowstart, adj, b0, bufB, N, flag);

  // Layer 1
  mfma_gemm2<false><<<ggrid, 256, 0, stream>>>(bufB, Wt1, nullptr, bufA, as2, ad2, aS1, aD1, N, 128, flag);
  gat_agg3<<<wgrid, 256, 0, stream>>>(bufA, as2, ad2, rowstart, adj, b1, bufB, N, flag);

  // Head
  pool_kernel<<<pgrid, 256, 0, stream>>>(bufB, batch, pooled, N);
  head4_kernel<<<B, 512, 0, stream>>>(pooled, x, batch, HW, (void*)d_out, N, IN, flag);
}

// Round 9
// 355.761 us; speedup vs baseline: 2.1942x; 1.0032x over previous
//
#include <hip/hip_runtime.h>
#include <hip/hip_bf16.h>

typedef __hip_bfloat16 bf16;
typedef __attribute__((ext_vector_type(8))) __bf16 bf16x8;
typedef __attribute__((ext_vector_type(4))) float f32x4;

__device__ __forceinline__ float toF(bf16 v) { return __bfloat162float(v); }

// dual-dtype load: dt=1 -> underlying memory is fp32; dt=0 -> bf16
__device__ __forceinline__ float ldf(const void* p, size_t i, int dt) {
  return dt ? ((const float*)p)[i] : __bfloat162float(((const bf16*)p)[i]);
}
__device__ __forceinline__ ushort toBF(float f) {
  union { bf16 b; ushort u; } cv; cv.b = __float2bfloat16(f); return cv.u;
}

// ---------------- dtype detection ----------------
__global__ void detect_dtype(const void* x, int n, int* flag) {
  __shared__ int s;
  if (threadIdx.x == 0) s = 0;
  __syncthreads();
  const bf16* xb = (const bf16*)x;
  int bad = 0;
  for (int i = threadIdx.x; i < n; i += 256) {
    float v = __bfloat162float(xb[i]);
    if (!(fabsf(v) < 1e6f)) bad = 1;
  }
  if (bad) atomicOr(&s, 1);
  __syncthreads();
  if (threadIdx.x == 0) flag[0] = s;
}

// ---------------- optional x -> bf16 repack (only runs when dt==1) ----------------
__global__ void pack_xp(const void* __restrict__ x, ushort* __restrict__ xp, size_t total,
                        const int* __restrict__ dtflag) {
  if (dtflag[0] == 0) return;
  const float* xf = (const float*)x;
  size_t stride = (size_t)gridDim.x * blockDim.x;
  for (size_t i = blockIdx.x * (size_t)blockDim.x + threadIdx.x; i < total; i += stride)
    xp[i] = toBF(xf[i]);
}

// ---------------- CSR build (real edges only; self-loops analytic in agg) -------------
__global__ void count_rank(const int* __restrict__ ei, int E,
                           int* __restrict__ cnt, int* __restrict__ rank) {
  int e = blockIdx.x * blockDim.x + threadIdx.x;
  if (e >= E) return;
  int d = ei[E + e];
  rank[e] = atomicAdd(&cnt[d], 1);
}

__global__ __launch_bounds__(256) void scan_reduce(const int* __restrict__ cnt, int n, int* __restrict__ csum) {
  int base = blockIdx.x * 1024;
  int t = threadIdx.x;
  int s = 0;
#pragma unroll
  for (int j = 0; j < 4; j++) {
    int i = base + t * 4 + j;
    if (i < n) s += cnt[i];
  }
#pragma unroll
  for (int off = 32; off > 0; off >>= 1) s += __shfl_down(s, off, 64);
  __shared__ int ws[4];
  if ((t & 63) == 0) ws[t >> 6] = s;
  __syncthreads();
  if (t == 0) csum[blockIdx.x] = ws[0] + ws[1] + ws[2] + ws[3];
}

__global__ __launch_bounds__(256) void scan_top(int* __restrict__ csum, int nb, int* __restrict__ rowstart, int n) {
  __shared__ int sc[256];
  int t = threadIdx.x;
  int v0 = (t < nb) ? csum[t] : 0;
  sc[t] = v0;
  for (int off = 1; off < 256; off <<= 1) {
    __syncthreads();
    int v = (t >= off) ? sc[t - off] : 0;
    __syncthreads();
    sc[t] += v;
  }
  __syncthreads();
  if (t < nb) csum[t] = sc[t] - v0;  // exclusive
  if (t == 0) rowstart[n] = sc[255]; // total
}

__global__ __launch_bounds__(256) void scan_down(const int* __restrict__ cnt, int n,
                                                 const int* __restrict__ csum,
                                                 int* __restrict__ rowstart) {
  int base = blockIdx.x * 1024;
  int t = threadIdx.x, lane = t & 63, w = t >> 6;
  int v[4];
#pragma unroll
  for (int j = 0; j < 4; j++) {
    int i = base + t * 4 + j;
    v[j] = (i < n) ? cnt[i] : 0;
  }
  int s1 = v[0], s2 = s1 + v[1], s3 = s2 + v[2], s4 = s3 + v[3];
  int x = s4;
#pragma unroll
  for (int off = 1; off < 64; off <<= 1) {
    int y = __shfl_up(x, off, 64);
    if (lane >= off) x += y;
  }
  int texcl = x - s4;
  __shared__ int ws[4];
  if (lane == 63) ws[w] = x;
  __syncthreads();
  int woff = 0;
  for (int i = 0; i < 4; i++) if (i < w) woff += ws[i];
  int b0 = csum[blockIdx.x] + woff + texcl;
  int e0 = b0, e1 = b0 + s1, e2 = b0 + s2, e3 = b0 + s3;
  int i0 = base + t * 4;
  if (i0 + 0 < n) rowstart[i0 + 0] = e0;
  if (i0 + 1 < n) rowstart[i0 + 1] = e1;
  if (i0 + 2 < n) rowstart[i0 + 2] = e2;
  if (i0 + 3 < n) rowstart[i0 + 3] = e3;
}

__global__ void scatter2(const int* __restrict__ ei, int E,
                         const int* __restrict__ rowstart, const int* __restrict__ rank,
                         int* __restrict__ adj) {
  int e = blockIdx.x * blockDim.x + threadIdx.x;
  if (e >= E) return;
  int s = ei[e], d = ei[E + e];
  adj[rowstart[d] + rank[e]] = s;
}

// ---------------- W pack for direct MFMA frag loads: Wt2[k/8][col][k%8] ----------------
// zero-padded for k in [K, Kpad) -> GEMM K-tail needs no A-side guards.
__global__ void pack_wt2(const void* __restrict__ W, ushort* __restrict__ Wt2, int K, int Kpad,
                         const int* __restrict__ dtflag) {
  int dt = dtflag[0];
  int c = blockIdx.x;           // 0..127
  int k = threadIdx.x;          // 0..Kpad-1
  if (k >= Kpad) return;
  float v = (k < K) ? ldf(W, (size_t)k * 128 + c, dt) : 0.f;
  Wt2[((size_t)(k >> 3) * 128 + c) * 8 + (k & 7)] = toBF(v);
}

// ---------------- head-weight fp32 pack: [Wn | Wr | bn | br | Wc | bc] ----------------
__global__ void convert_head(const void* Wn, const void* Wr, const void* bn, const void* br,
                             const void* Wc, const void* bc, float* __restrict__ dst, int IN,
                             const int* __restrict__ dtflag) {
  int dt = dtflag[0];
  int i = blockIdx.x * blockDim.x + threadIdx.x;
  int s0 = IN * 128, s1 = s0 + 128 * 128, s2 = s1 + 128, s3 = s2 + 128, s4 = s3 + 256, s5 = s4 + 1;
  if (i >= s5) return;
  float v;
  if (i < s0) v = ldf(Wn, i, dt);
  else if (i < s1) v = ldf(Wr, i - s0, dt);
  else if (i < s2) v = ldf(bn, i - s1, dt);
  else if (i < s3) v = ldf(br, i - s2, dt);
  else if (i < s4) v = ldf(Wc, i - s3, dt);
  else v = ldf(bc, 0, dt);
  dst[i] = v;
}

// ---------------- MFMA GEMM v3: LDS A-panel (coalesced contiguous stage), W from L2 ----
// C[nrows,128] = A[nrows,K] @ W[K,128], A bf16 row-major, row stride RB=K*2 bytes.
// Block = 64 rows (contiguous 64*RB bytes in global -> streamed into LDS with uint4).
// One barrier; K-loop reads A-frags from LDS (4B-aligned b32 or 16B b128), W frags
// direct from global (80KB table, L2-resident). Tail cols covered by Wt2 zero-pad.
// Asel: device-side source select (dt ? A1 : A0) so host never reads the flag.
template <int RB, bool ALIGN16>
__global__ __launch_bounds__(256) void mfma_gemm3(const void* __restrict__ A0, const void* __restrict__ A1,
                                                  const ushort* __restrict__ Wt2,
                                                  bf16* __restrict__ C,
                                                  float2* __restrict__ as2, float2* __restrict__ ad2,
                                                  const void* __restrict__ aS, const void* __restrict__ aD,
                                                  int nrows, int K, const int* __restrict__ dtflag) {
  __shared__ __align__(16) unsigned char panel[64 * RB + 64];  // +64 pad (zeroed) for tail reads
  int dtg = dtflag[0];
  const unsigned char* A = (const unsigned char*)((dtg && A1) ? A1 : A0);
  int tid = threadIdx.x;
  int row0 = blockIdx.x * 64;

  // ---- stage panel: contiguous global bytes, perfectly coalesced ----
  size_t gbase = (size_t)row0 * RB;
  size_t avail = (size_t)nrows * RB - gbase;
  size_t pbytes = avail < (size_t)(64 * RB) ? avail : (size_t)(64 * RB);
  int nchunk = (int)(pbytes >> 4);
  const uint4* gsrc = (const uint4*)(A + gbase);
  for (int c = tid; c < nchunk; c += 256)
    *(uint4*)&panel[(size_t)c << 4] = gsrc[c];
  // dword fixup for the (rare) non-16B-multiple end of the valid region
  for (int b = (nchunk << 4) + tid * 4; b < (int)pbytes; b += 1024)
    *(uint*)&panel[b] = *(const uint*)(A + gbase + b);
  // zero everything past the valid bytes (absent rows + 64B pad) -> no NaN garbage
  for (int b = (int)((pbytes + 3) & ~3ull) + tid * 4; b < 64 * RB + 64; b += 1024)
    *(uint*)&panel[b] = 0u;
  __syncthreads();

  int wave = tid >> 6, lane = tid & 63;
  int m = lane & 15, q = lane >> 4;
  int lrow = wave * 16 + m;
  const unsigned char* prow = &panel[(size_t)lrow * RB];

  f32x4 acc[8];
#pragma unroll
  for (int ct = 0; ct < 8; ct++) acc[ct] = (f32x4){0.f, 0.f, 0.f, 0.f};

  const ushort* wq = Wt2 + (size_t)q * 1024 + (size_t)m * 8;
  int niter = (K + 31) >> 5;
  for (int it = 0; it < niter; it++) {
    bf16x8 av;
    if (ALIGN16) {
      av = *(const bf16x8*)(prow + it * 64 + q * 16);
    } else {
      uint u[4];
#pragma unroll
      for (int j = 0; j < 4; j++) u[j] = *(const uint*)(prow + it * 64 + q * 16 + j * 4);
      __builtin_memcpy(&av, u, 16);
    }
    const ushort* wk = wq + (size_t)it * 4096;
    bf16x8 wv[8];
#pragma unroll
    for (int ct = 0; ct < 8; ct++) wv[ct] = *(const bf16x8*)(wk + ct * 128);
#pragma unroll
    for (int ct = 0; ct < 8; ct++)
      acc[ct] = __builtin_amdgcn_mfma_f32_16x16x32_bf16(av, wv[ct], acc[ct], 0, 0, 0);
  }

  // ---- C writeback (C/D: col=lane&15, row=q*4+r) ----
#pragma unroll
  for (int ct = 0; ct < 8; ct++) {
#pragma unroll
    for (int r = 0; r < 4; r++) {
      int grow = row0 + wave * 16 + q * 4 + r;
      if (grow < nrows) C[(size_t)grow * 128 + ct * 16 + m] = __float2bfloat16(acc[ct][r]);
    }
  }

  // ---- fused attention logits ----
  float aSv[8], aDv[8];
#pragma unroll
  for (int ct = 0; ct < 8; ct++) {
    aSv[ct] = ldf(aS, ct * 16 + m, dtg);
    aDv[ct] = ldf(aD, ct * 16 + m, dtg);
  }
#pragma unroll
  for (int r = 0; r < 4; r++) {
    float s0 = 0.f, s1 = 0.f, d0 = 0.f, d1 = 0.f;
#pragma unroll
    for (int ct = 0; ct < 4; ct++) {
      float v = acc[ct][r];
      s0 += v * aSv[ct]; d0 += v * aDv[ct];
    }
#pragma unroll
    for (int ct = 4; ct < 8; ct++) {
      float v = acc[ct][r];
      s1 += v * aSv[ct]; d1 += v * aDv[ct];
    }
#pragma unroll
    for (int off = 1; off < 16; off <<= 1) {
      s0 += __shfl_xor(s0, off, 64);
      s1 += __shfl_xor(s1, off, 64);
      d0 += __shfl_xor(d0, off, 64);
      d1 += __shfl_xor(d1, off, 64);
    }
    int grow = row0 + wave * 16 + q * 4 + r;
    if (m == 0 && grow < nrows) {
      as2[grow] = make_float2(s0, s1);
      ad2[grow] = make_float2(d0, d1);
    }
  }
}

// ---------------- generic fallback GEMM (any K / dtype), latency-tolerant enough -------
__global__ __launch_bounds__(256) void mfma_gemm_gen(const void* __restrict__ A, const ushort* __restrict__ Wt2,
                                                     bf16* __restrict__ C,
                                                     float2* __restrict__ as2, float2* __restrict__ ad2,
                                                     const void* __restrict__ aS, const void* __restrict__ aD,
                                                     int nrows, int K, const int* __restrict__ dtflag) {
  int dtg = dtflag[0];
  int tid = threadIdx.x;
  int wave = tid >> 6, lane = tid & 63;
  int m = lane & 15, q = lane >> 4;
  int row0 = blockIdx.x * 64;
  int rowA = row0 + wave * 16 + m;
  int rA = rowA < nrows ? rowA : nrows - 1;

  f32x4 acc[8];
#pragma unroll
  for (int ct = 0; ct < 8; ct++) acc[ct] = (f32x4){0.f, 0.f, 0.f, 0.f};

  const ushort* wq = Wt2 + (size_t)q * 1024 + (size_t)m * 8;
  int niter = (K + 31) >> 5;
  for (int it = 0; it < niter; it++) {
    ushort u[8];
#pragma unroll
    for (int j = 0; j < 8; j++) {
      int k = it * 32 + q * 8 + j;
      u[j] = (k < K) ? toBF(ldf(A, (size_t)rA * K + k, dtg)) : (ushort)0;
    }
    bf16x8 av;
    __builtin_memcpy(&av, u, 16);
    const ushort* wk = wq + (size_t)it * 4096;
    bf16x8 wv[8];
#pragma unroll
    for (int ct = 0; ct < 8; ct++) wv[ct] = *(const bf16x8*)(wk + ct * 128);
#pragma unroll
    for (int ct = 0; ct < 8; ct++)
      acc[ct] = __builtin_amdgcn_mfma_f32_16x16x32_bf16(av, wv[ct], acc[ct], 0, 0, 0);
  }
#pragma unroll
  for (int ct = 0; ct < 8; ct++) {
#pragma unroll
    for (int r = 0; r < 4; r++) {
      int grow = row0 + wave * 16 + q * 4 + r;
      if (grow < nrows) C[(size_t)grow * 128 + ct * 16 + m] = __float2bfloat16(acc[ct][r]);
    }
  }
  float aSv[8], aDv[8];
#pragma unroll
  for (int ct = 0; ct < 8; ct++) {
    aSv[ct] = ldf(aS, ct * 16 + m, dtg);
    aDv[ct] = ldf(aD, ct * 16 + m, dtg);
  }
#pragma unroll
  for (int r = 0; r < 4; r++) {
    float s0 = 0.f, s1 = 0.f, d0 = 0.f, d1 = 0.f;
#pragma unroll
    for (int ct = 0; ct < 4; ct++) { float v = acc[ct][r]; s0 += v * aSv[ct]; d0 += v * aDv[ct]; }
#pragma unroll
    for (int ct = 4; ct < 8; ct++) { float v = acc[ct][r]; s1 += v * aSv[ct]; d1 += v * aDv[ct]; }
#pragma unroll
    for (int off = 1; off < 16; off <<= 1) {
      s0 += __shfl_xor(s0, off, 64);
      s1 += __shfl_xor(s1, off, 64);
      d0 += __shfl_xor(d0, off, 64);
      d1 += __shfl_xor(d1, off, 64);
    }
    int grow = row0 + wave * 16 + q * 4 + r;
    if (m == 0 && grow < nrows) {
      as2[grow] = make_float2(s0, s1);
      ad2[grow] = make_float2(d0, d1);
    }
  }
}

// ---------------- GAT aggregate v3: no max pass, analytic self-loop ----------------
#define GCAP 64
__global__ __launch_bounds__(256) void gat_agg3(const bf16* __restrict__ xw,
                                                const float2* __restrict__ as2, const float2* __restrict__ ad2,
                                                const int* __restrict__ rowstart, const int* __restrict__ adj,
                                                const void* __restrict__ bias, bf16* __restrict__ out, int N,
                                                const int* __restrict__ dtflag) {
  __shared__ float2 sW[4][GCAP];
  __shared__ int sS[4][GCAP];
  int dt = dtflag[0];
  int wslot = threadIdx.x >> 6;
  int lane = threadIdx.x & 63;
  int n = (blockIdx.x * blockDim.x + threadIdx.x) >> 6;
  bool act = n < N;
  int r0 = 0, r1 = 0;
  float2 adv = make_float2(0.f, 0.f), asn = make_float2(0.f, 0.f);
  if (act) { r0 = rowstart[n]; r1 = rowstart[n + 1]; adv = ad2[n]; asn = as2[n]; }
  int deg = r1 - r0;

  float es0 = asn.x + adv.x; es0 = es0 > 0.f ? es0 : 0.2f * es0;
  float es1 = asn.y + adv.y; es1 = es1 > 0.f ? es1 : 0.2f * es1;
  float ws0 = __expf(fminf(es0, 60.f)), ws1 = __expf(fminf(es1, 60.f));

  float den0, den1;
  {
    bool v = act && lane < deg;
    int s = v ? adj[r0 + lane] : 0;
    float w0 = 0.f, w1 = 0.f;
    if (v) {
      float2 asv = as2[s];
      float e0 = asv.x + adv.x; e0 = e0 > 0.f ? e0 : 0.2f * e0;
      float e1 = asv.y + adv.y; e1 = e1 > 0.f ? e1 : 0.2f * e1;
      w0 = __expf(fminf(e0, 60.f)); w1 = __expf(fminf(e1, 60.f));
    }
    sW[wslot][lane] = make_float2(w0, w1);
    sS[wslot][lane] = s;
    den0 = w0; den1 = w1;
  }
  for (int i = r0 + GCAP + lane; i < r1; i += 64) {
    int s = adj[i];
    float2 asv = as2[s];
    float e0 = asv.x + adv.x; e0 = e0 > 0.f ? e0 : 0.2f * e0;
    float e1 = asv.y + adv.y; e1 = e1 > 0.f ? e1 : 0.2f * e1;
    den0 += __expf(fminf(e0, 60.f)); den1 += __expf(fminf(e1, 60.f));
  }
#pragma unroll
  for (int off = 32; off > 0; off >>= 1) {
    den0 += __shfl_xor(den0, off, 64);
    den1 += __shfl_xor(den1, off, 64);
  }
  den0 += ws0; den1 += ws1;
  float inv0 = 1.f / (den0 + 1e-16f), inv1 = 1.f / (den1 + 1e-16f);

  const uint* xw32 = (const uint*)xw;
  float wsS = (lane < 32) ? ws0 : ws1;
  uint pvs = act ? xw32[((size_t)n << 6) + lane] : 0;
  float a0 = wsS * __uint_as_float(pvs << 16);
  float a1 = wsS * __uint_as_float(pvs & 0xffff0000u);
  int cap = deg < GCAP ? deg : GCAP;
#pragma unroll 4
  for (int i = 0; i < cap; i++) {
    float2 wv = sW[wslot][i];
    int s = sS[wslot][i];
    uint pv = xw32[((size_t)s << 6) + lane];
    float ws = (lane < 32) ? wv.x : wv.y;
    a0 += ws * __uint_as_float(pv << 16);
    a1 += ws * __uint_as_float(pv & 0xffff0000u);
  }
  for (int i = GCAP; i < deg; i++) {
    int s = adj[r0 + i];
    float2 asv = as2[s];
    float e0 = asv.x + adv.x; e0 = e0 > 0.f ? e0 : 0.2f * e0;
    float e1 = asv.y + adv.y; e1 = e1 > 0.f ? e1 : 0.2f * e1;
    float w0 = __expf(fminf(e0, 60.f)), w1 = __expf(fminf(e1, 60.f));
    uint pv = xw32[((size_t)s << 6) + lane];
    float ws = (lane < 32) ? w0 : w1;
    a0 += ws * __uint_as_float(pv << 16);
    a1 += ws * __uint_as_float(pv & 0xffff0000u);
  }
  if (act) {
    int c0 = 2 * lane;
    float invs = (lane < 32) ? inv0 : inv1;
    float o0 = a0 * invs + ldf(bias, c0, dt);
    float o1 = a1 * invs + ldf(bias, c0 + 1, dt);
    o0 = o0 > 0.f ? o0 : 0.f;
    o1 = o1 > 0.f ? o1 : 0.f;
    uint pk = (uint)toBF(o0) | ((uint)toBF(o1) << 16);
    ((uint*)out)[(size_t)n * 64 + lane] = pk;
  }
}

// ---------------- parallel mean-pool (unnormalized sums; contiguous batch) ----------------
__global__ __launch_bounds__(256) void pool_kernel(const bf16* __restrict__ h, const int* __restrict__ batch,
                                                   float* __restrict__ pooled, int N) {
  int n0 = blockIdx.x * 128;
  int nEnd = n0 + 128 < N ? n0 + 128 : N;
  int col = threadIdx.x & 127, half = threadIdx.x >> 7;
  float acc = 0.f;
  int cur = -1;
  for (int n = n0 + half; n < nEnd; n += 2) {
    int g = batch[n];
    if (g != cur) {
      if (cur >= 0) atomicAdd(&pooled[(size_t)cur * 128 + col], acc);
      acc = 0.f; cur = g;
    }
    acc += toF(h[(size_t)n * 128 + col]);
  }
  if (cur >= 0) atomicAdd(&pooled[(size_t)cur * 128 + col], acc);
}

// ---------------- head v4: fp32-packed weights, no per-load dtype branch ----------------
__global__ __launch_bounds__(512) void head4_kernel(
    const float* __restrict__ pooled, const void* __restrict__ x, const int* __restrict__ batch,
    const float* __restrict__ HW, void* __restrict__ out, int N, int IN,
    const int* __restrict__ dtflag) {
  const float* Wn_f = HW;
  const float* Wr_f = HW + (size_t)IN * 128;
  const float* bn_f = Wr_f + 128 * 128;
  const float* br_f = bn_f + 128;
  const float* Wc_f = br_f + 128;
  const float* bc_f = Wc_f + 256;
  int dt = dtflag[0];
  int b = blockIdx.x;
  int tid = threadIdx.x;
  int t = tid & 127, g = tid >> 7;
  __shared__ int sr0, sr1;
  __shared__ float xs[512];
  __shared__ float pl[128];
  __shared__ float pn[4][128];
  __shared__ float pg[4][128];
  __shared__ float red[128];
  if (tid == 0) {
    int lo = 0, hi = N;
    while (lo < hi) { int mid = (lo + hi) >> 1; if (batch[mid] < b) lo = mid + 1; else hi = mid; }
    sr0 = lo;
  }
  if (tid == 1) {
    int lo = 0, hi = N, b1 = b + 1;
    while (lo < hi) { int mid = (lo + hi) >> 1; if (batch[mid] < b1) lo = mid + 1; else hi = mid; }
    sr1 = lo;
  }
  __syncthreads();
  int r0 = sr0;
  float inv_cnt = 1.f / (float)(sr1 - r0);
  if (tid < 128) pl[tid] = pooled[(size_t)b * 128 + tid] * inv_cnt;
  if (dt) {
    const float* xf = (const float*)x + (size_t)r0 * IN;
    for (int k = tid; k < IN; k += 512) xs[k] = xf[k];
  } else {
    const bf16* xb = (const bf16*)x + (size_t)r0 * IN;
    for (int k = tid; k < IN; k += 512) xs[k] = toF(xb[k]);
  }
  __syncthreads();

  float n0 = 0.f, n1 = 0.f, n2 = 0.f, n3 = 0.f;
  {
    int k = g;
    for (; k + 12 < IN; k += 16) {
      n0 += xs[k]      * Wn_f[(size_t)k * 128 + t];
      n1 += xs[k + 4]  * Wn_f[(size_t)(k + 4) * 128 + t];
      n2 += xs[k + 8]  * Wn_f[(size_t)(k + 8) * 128 + t];
      n3 += xs[k + 12] * Wn_f[(size_t)(k + 12) * 128 + t];
    }
    for (; k < IN; k += 4) n0 += xs[k] * Wn_f[(size_t)k * 128 + t];
  }
  float g0 = 0.f, g1 = 0.f;
  {
    int k = g;
    for (; k + 4 < 128; k += 8) {
      g0 += pl[k]     * Wr_f[(size_t)k * 128 + t];
      g1 += pl[k + 4] * Wr_f[(size_t)(k + 4) * 128 + t];
    }
    for (; k < 128; k += 4) g0 += pl[k] * Wr_f[(size_t)k * 128 + t];
  }
  pn[g][t] = (n0 + n1) + (n2 + n3);
  pg[g][t] = g0 + g1;
  __syncthreads();
  if (tid < 128) {
    float nw = pn[0][t] + pn[1][t] + pn[2][t] + pn[3][t] + bn_f[t];
    nw = nw > 0.f ? nw : 0.f;
    float gg = pg[0][t] + pg[1][t] + pg[2][t] + pg[3][t] + br_f[t];
    gg = gg > 0.f ? gg : 0.f;
    red[t] = gg * Wc_f[t] + nw * Wc_f[128 + t];
  }
  __syncthreads();
  for (int s = 64; s > 0; s >>= 1) {
    if (tid < s) red[tid] += red[tid + s];
    __syncthreads();
  }
  if (tid == 0) {
    float z = red[0] + bc_f[0];
    float r = 1.f / (1.f + __expf(-z));
    if (dt) ((float*)out)[b] = r;
    else ((bf16*)out)[b] = __float2bfloat16(r);
  }
}

extern "C" void kernel_launch(void* const* d_in, const int* in_sizes, int n_in,
                              void* d_out, int out_size, void* d_ws, size_t ws_size,
                              hipStream_t stream) {
  const void* x   = d_in[0];
  const void* W0  = d_in[1];
  const void* aS0 = d_in[2];
  const void* aD0 = d_in[3];
  const void* b0  = d_in[4];
  const void* W1  = d_in[5];
  const void* aS1 = d_in[6];
  const void* aD1 = d_in[7];
  const void* b1  = d_in[8];
  const void* Wn  = d_in[9];
  const void* bn  = d_in[10];
  const void* Wr  = d_in[11];
  const void* br  = d_in[12];
  const void* Wc  = d_in[13];
  const void* bc  = d_in[14];
  const int* ei    = (const int*)d_in[15];
  const int* batch = (const int*)d_in[16];

  const int N = in_sizes[16];
  const int IN = in_sizes[0] / N;
  const int E = in_sizes[15] / 2;
  const int B = out_size;
  const int Kpad0 = (IN + 31) / 32 * 32;   // 320
  const int hw_elems = IN * 128 + 128 * 128 + 128 + 128 + 256 + 1;

  char* w = (char*)d_ws;
  size_t off = 0;
  auto alloc = [&](size_t bytes) { void* p = w + off; off += (bytes + 255) / 256 * 256; return p; };
  int* flag      = (int*)alloc(256);
  bf16* bufA     = (bf16*)alloc((size_t)N * 128 * 2);
  bf16* bufB     = (bf16*)alloc((size_t)N * 128 * 2);
  float2* as2    = (float2*)alloc((size_t)N * 8);
  float2* ad2    = (float2*)alloc((size_t)N * 8);
  int* cnt       = (int*)alloc((size_t)N * 4);
  int* rowstart  = (int*)alloc((size_t)(N + 1) * 4);
  int* rank      = (int*)alloc((size_t)E * 4);
  int* adj       = (int*)alloc((size_t)E * 4);
  int* csum      = (int*)alloc(1024);
  ushort* Wt0    = (ushort*)alloc((size_t)128 * Kpad0 * 2);
  ushort* Wt1    = (ushort*)alloc((size_t)128 * 128 * 2);
  float* pooled  = (float*)alloc((size_t)B * 128 * 4);
  float* HW      = (float*)alloc((size_t)hw_elems * 4);
  ushort* xp     = (ushort*)alloc((size_t)N * IN * 2);   // bf16 repack of x (dt=1 only)

  int ndet = in_sizes[0] < 4096 ? in_sizes[0] : 4096;
  detect_dtype<<<1, 256, 0, stream>>>(x, ndet, flag);

  hipMemsetAsync(cnt, 0, sizeof(int) * N, stream);
  hipMemsetAsync(pooled, 0, sizeof(float) * (size_t)B * 128, stream);

  const int tb = 256;
  count_rank<<<(E + tb - 1) / tb, tb, 0, stream>>>(ei, E, cnt, rank);
  int nb = (N + 1023) / 1024;
  scan_reduce<<<nb, 256, 0, stream>>>(cnt, N, csum);
  scan_top<<<1, 256, 0, stream>>>(csum, nb, rowstart, N);
  scan_down<<<nb, 256, 0, stream>>>(cnt, N, csum, rowstart);
  scatter2<<<(E + tb - 1) / tb, tb, 0, stream>>>(ei, E, rowstart, rank, adj);

  pack_wt2<<<128, Kpad0, 0, stream>>>(W0, Wt0, IN, Kpad0, flag);
  pack_wt2<<<128, 128, 0, stream>>>(W1, Wt1, 128, 128, flag);
  pack_xp<<<2048, 256, 0, stream>>>(x, xp, (size_t)N * IN, flag);
  convert_head<<<(hw_elems + 255) / 256, 256, 0, stream>>>(Wn, Wr, bn, br, Wc, bc, HW, IN, flag);

  int ggrid = (N + 63) / 64;
  int pgrid = (N + 127) / 128;
  int wgrid = ((N * 64) + 255) / 256;

  // Layer 0: fast panel path for the known shape (IN=310); generic fallback otherwise
  if (IN == 310) {
    mfma_gemm3<620, false><<<ggrid, 256, 0, stream>>>(x, xp, Wt0, bufA, as2, ad2, aS0, aD0, N, IN, flag);
  } else {
    mfma_gemm_gen<<<ggrid, 256, 0, stream>>>(x, Wt0, bufA, as2, ad2, aS0, aD0, N, IN, flag);
  }
  gat_agg3<<<wgrid, 256, 0, stream>>>(bufA, as2, ad2, rowstart, adj, b0, bufB, N, flag);

  // Layer 1: bf16 buffer, 256B rows, 16B-aligned
  mfma_gemm3<256, true><<<ggrid, 256, 0, stream>>>(bufB, nullptr, Wt1, bufA, as2, ad2, aS1, aD1, N, 128, flag);
  gat_agg3<<<wgrid, 256, 0, stream>>>(bufA, as2, ad2, rowstart, adj, b1, bufB, N, flag);

  // Head
  pool_kernel<<<pgrid, 256, 0, stream>>>(bufB, batch, pooled, N);
  head4_kernel<<<B, 512, 0, stream>>>(pooled, x, batch, HW, (void*)d_out, N, IN, flag);
}